// Round 1
// baseline (2292.194 us; speedup 1.0000x reference)
//
#include <hip/hip_runtime.h>
#include <hip/hip_bf16.h>
#include <math.h>

// ---------------------------------------------------------------------------
// RGCN forward: conv1(add) -> LN+ReLU -> conv2(max) -> LN+ReLU+0.2*res ->
//               [Lin->LN->GELU] x2 -> Lin -> log_softmax
// All f32. Transform-then-gather per relation, atomics for aggregation.
// ---------------------------------------------------------------------------

// ============================ GEMM  M x 128 @ 128 x 128 ====================
// 32 rows/block, 256 threads, thread computes 4 rows x 4 cols.
// W staged in LDS in two K-halves to stay under 64KB static LDS (48KB total).
__global__ __launch_bounds__(256) void gemm128(const float* __restrict__ X,
                                               const float* __restrict__ W,
                                               const float* __restrict__ bias,
                                               float* __restrict__ Y, int M) {
    __shared__ float Ws[64 * 128];   // one K-half of W: 32KB
    __shared__ float Xs[32 * 128];   // 16KB
    const int tid = threadIdx.x;
    const int row0 = blockIdx.x * 32;

    // load X tile (32 rows x 128) as float4
    const float4* X4 = (const float4*)X;
    float4* Xs4 = (float4*)Xs;
#pragma unroll
    for (int j = 0; j < 4; ++j) {
        int idx = tid + j * 256;          // 0..1023 float4 slots
        int r = idx >> 5, c = idx & 31;   // 32 float4 per row
        float4 v = make_float4(0.f, 0.f, 0.f, 0.f);
        if (row0 + r < M) v = X4[(size_t)(row0 + r) * 32 + c];
        Xs4[idx] = v;
    }

    const int ty = tid >> 5, tx = tid & 31;
    float acc[4][4];
#pragma unroll
    for (int i = 0; i < 4; ++i)
#pragma unroll
        for (int j = 0; j < 4; ++j) acc[i][j] = 0.f;

    const float4* W4 = (const float4*)W;
    float4* Ws4 = (float4*)Ws;

    for (int kb = 0; kb < 128; kb += 64) {
        __syncthreads();
        // load W[kb..kb+63][0..127] : 2048 float4 / 256 threads = 8 each
#pragma unroll
        for (int j = 0; j < 8; ++j) {
            int idx = tid + j * 256;              // local float4 slot
            Ws4[idx] = W4[(size_t)kb * 32 + idx]; // contiguous rows
        }
        __syncthreads();
#pragma unroll 8
        for (int kk = 0; kk < 64; ++kk) {
            float4 wv = Ws4[kk * 32 + tx];
            int k = kb + kk;
#pragma unroll
            for (int i = 0; i < 4; ++i) {
                float xv = Xs[(ty + 8 * i) * 128 + k];
                acc[i][0] = fmaf(xv, wv.x, acc[i][0]);
                acc[i][1] = fmaf(xv, wv.y, acc[i][1]);
                acc[i][2] = fmaf(xv, wv.z, acc[i][2]);
                acc[i][3] = fmaf(xv, wv.w, acc[i][3]);
            }
        }
    }

    float4 bv = make_float4(0.f, 0.f, 0.f, 0.f);
    if (bias) bv = ((const float4*)bias)[tx];
#pragma unroll
    for (int i = 0; i < 4; ++i) {
        int r = row0 + ty + 8 * i;
        if (r < M) {
            float4 o;
            o.x = acc[i][0] + bv.x; o.y = acc[i][1] + bv.y;
            o.z = acc[i][2] + bv.z; o.w = acc[i][3] + bv.w;
            ((float4*)Y)[(size_t)r * 32 + tx] = o;
        }
    }
}

// ===================== small GEMM  M x K @ K x N  (K,N <= 128) =============
template <int K, int N>
__global__ __launch_bounds__(256) void gemm_small(const float* __restrict__ X,
                                                  const float* __restrict__ W,
                                                  const float* __restrict__ bias,
                                                  float* __restrict__ Y, int M) {
    __shared__ float Ws[K * N];
    __shared__ float Xs[8 * K];
    const int tid = threadIdx.x;
    const int row0 = blockIdx.x * 8;
    for (int i = tid; i < K * N; i += 256) Ws[i] = W[i];
    for (int i = tid; i < 8 * K; i += 256) {
        int r = i / K, c = i % K;
        Xs[i] = (row0 + r < M) ? X[(size_t)(row0 + r) * K + c] : 0.f;
    }
    __syncthreads();
    const int r = tid >> 5, tx = tid & 31;
    constexpr int NJ = (N + 31) / 32;
    float acc[NJ];
#pragma unroll
    for (int j = 0; j < NJ; ++j) acc[j] = 0.f;
    for (int k = 0; k < K; ++k) {
        float xv = Xs[r * K + k];
#pragma unroll
        for (int j = 0; j < NJ; ++j) {
            int n = tx + 32 * j;
            if (n < N) acc[j] = fmaf(xv, Ws[k * N + n], acc[j]);
        }
    }
    int grow = row0 + r;
    if (grow < M) {
#pragma unroll
        for (int j = 0; j < NJ; ++j) {
            int n = tx + 32 * j;
            if (n < N) Y[(size_t)grow * N + n] = acc[j] + (bias ? bias[n] : 0.f);
        }
    }
}

// ========================== scatter add (aggr='add') =======================
// 32 lanes per edge, float4 per lane (128 cols).
__global__ __launch_bounds__(256) void scatter_add_kernel(
    const float* __restrict__ H, const int* __restrict__ esrc,
    const int* __restrict__ edst, const int* __restrict__ etype,
    int rel, int E, float* __restrict__ out) {
    int gt = blockIdx.x * 256 + threadIdx.x;
    int e = gt >> 5;
    if (e >= E) return;
    if (etype[e] != rel) return;
    int lane = gt & 31;
    int s = esrc[e], d = edst[e];
    float4 v = ((const float4*)H)[(size_t)s * 32 + lane];
    float* o = out + (size_t)d * 128 + lane * 4;
    unsafeAtomicAdd(o + 0, v.x);
    unsafeAtomicAdd(o + 1, v.y);
    unsafeAtomicAdd(o + 2, v.z);
    unsafeAtomicAdd(o + 3, v.w);
}

// ========================== scatter max (aggr='max') =======================
// monotonic float->uint encoding; 0 == "empty" (no finite msg maps to 0).
__device__ __forceinline__ unsigned enc_f(float f) {
    unsigned u = __float_as_uint(f);
    return (f >= 0.f) ? (u | 0x80000000u) : ~u;
}
__device__ __forceinline__ float dec_f(unsigned u) {
    return (u & 0x80000000u) ? __uint_as_float(u & 0x7FFFFFFFu)
                             : __uint_as_float(~u);
}

__global__ __launch_bounds__(256) void scatter_max_kernel(
    const float* __restrict__ H, const int* __restrict__ esrc,
    const int* __restrict__ edst, const int* __restrict__ etype,
    int rel, int E, unsigned* __restrict__ maxbuf) {
    int gt = blockIdx.x * 256 + threadIdx.x;
    int e = gt >> 5;
    if (e >= E) return;
    if (etype[e] != rel) return;
    int lane = gt & 31;
    int s = esrc[e], d = edst[e];
    float4 v = ((const float4*)H)[(size_t)s * 32 + lane];
    unsigned* o = maxbuf + (size_t)d * 128 + lane * 4;
    atomicMax(o + 0, enc_f(v.x));
    atomicMax(o + 1, enc_f(v.y));
    atomicMax(o + 2, enc_f(v.z));
    atomicMax(o + 3, enc_f(v.w));
}

__global__ __launch_bounds__(256) void merge_max_kernel(
    const unsigned* __restrict__ maxbuf, float* __restrict__ out, int n) {
    int i = blockIdx.x * 256 + threadIdx.x;
    if (i < n) {
        unsigned u = maxbuf[i];
        if (u) out[i] += dec_f(u);
    }
}

// ===================== LayerNorm (+ReLU / +ReLU+res / +GELU) ===============
// MODE: 0 = relu, 1 = relu + 0.2*resid, 2 = exact gelu
template <int D, int MODE>
__global__ __launch_bounds__(256) void ln_kernel(const float* __restrict__ in,
                                                 const float* __restrict__ g,
                                                 const float* __restrict__ b,
                                                 const float* __restrict__ resid,
                                                 float* __restrict__ out, int M) {
    int row = blockIdx.x * 4 + (threadIdx.x >> 6);
    int lane = threadIdx.x & 63;
    if (row >= M) return;
    constexpr int EPL = D / 64;
    float v[EPL];
    const float* ip = in + (size_t)row * D;
#pragma unroll
    for (int j = 0; j < EPL; ++j) v[j] = ip[lane * EPL + j];
    float s = 0.f, sq = 0.f;
#pragma unroll
    for (int j = 0; j < EPL; ++j) { s += v[j]; sq += v[j] * v[j]; }
#pragma unroll
    for (int off = 32; off; off >>= 1) {
        s += __shfl_xor(s, off, 64);
        sq += __shfl_xor(sq, off, 64);
    }
    float mu = s * (1.f / D);
    float var = sq * (1.f / D) - mu * mu;
    float rs = rsqrtf(var + 1e-5f);
#pragma unroll
    for (int j = 0; j < EPL; ++j) {
        int c = lane * EPL + j;
        float y = (v[j] - mu) * rs * g[c] + b[c];
        if (MODE == 0) {
            y = fmaxf(y, 0.f);
        } else if (MODE == 1) {
            y = fmaxf(y, 0.f) + 0.2f * resid[(size_t)row * D + c];
        } else {
            y = 0.5f * y * (1.f + erff(y * 0.70710678118654752f));
        }
        out[(size_t)row * D + c] = y;
    }
}

// ============================ log_softmax (rows of 40) =====================
__global__ __launch_bounds__(256) void lsm_kernel(const float* __restrict__ in,
                                                  float* __restrict__ out, int M) {
    int row = blockIdx.x * 4 + (threadIdx.x >> 6);
    int lane = threadIdx.x & 63;
    if (row >= M) return;
    float v = (lane < 40) ? in[(size_t)row * 40 + lane] : -INFINITY;
    float mx = v;
#pragma unroll
    for (int off = 32; off; off >>= 1) mx = fmaxf(mx, __shfl_xor(mx, off, 64));
    float e = (lane < 40) ? __expf(v - mx) : 0.f;
    float sum = e;
#pragma unroll
    for (int off = 32; off; off >>= 1) sum += __shfl_xor(sum, off, 64);
    float ls = logf(sum);
    if (lane < 40) out[(size_t)row * 40 + lane] = v - mx - ls;
}

// ===========================================================================
extern "C" void kernel_launch(void* const* d_in, const int* in_sizes, int n_in,
                              void* d_out, int out_size, void* d_ws, size_t ws_size,
                              hipStream_t stream) {
    const float* x       = (const float*)d_in[0];
    const int*   eidx    = (const int*)d_in[1];
    const int*   etype   = (const int*)d_in[2];
    const float* w1_rel  = (const float*)d_in[3];
    const float* w1_root = (const float*)d_in[4];
    const float* b1      = (const float*)d_in[5];
    const float* ln1_g   = (const float*)d_in[6];
    const float* ln1_b   = (const float*)d_in[7];
    const float* w2_rel  = (const float*)d_in[8];
    const float* w2_root = (const float*)d_in[9];
    const float* b2      = (const float*)d_in[10];
    const float* ln2_g   = (const float*)d_in[11];
    const float* ln2_b   = (const float*)d_in[12];
    const float* cw1     = (const float*)d_in[13];
    const float* cb1     = (const float*)d_in[14];
    const float* cln1_g  = (const float*)d_in[15];
    const float* cln1_b  = (const float*)d_in[16];
    const float* cw2     = (const float*)d_in[17];
    const float* cb2     = (const float*)d_in[18];
    const float* cln2_g  = (const float*)d_in[19];
    const float* cln2_b  = (const float*)d_in[20];
    const float* cw3     = (const float*)d_in[21];
    const float* cb3     = (const float*)d_in[22];

    const int N = in_sizes[0] / 128;   // 50000
    const int E = in_sizes[1] / 2;     // 600000
    const int* esrc = eidx;
    const int* edst = eidx + E;

    const size_t NF = (size_t)N * 128;
    float*    B_h    = (float*)d_ws;          // [N,128] transformed feats
    float*    B_out  = B_h + NF;              // [N,128] conv accumulator
    float*    B_x1   = B_out + NF;            // [N,128] saved activation
    float*    B_maxf = B_x1 + NF;             // [N,128] max agg (uint enc)
    unsigned* B_max  = (unsigned*)B_maxf;

    const dim3 blk(256);
    const int gGemm  = (N + 31) / 32;
    const int gSmall = (N + 7) / 8;
    const int gRow   = (N + 3) / 4;
    const int gScat  = (int)(((size_t)E * 32 + 255) / 256);
    const int gElem  = (int)((NF + 255) / 256);

    // ---------------- conv1 (add) ----------------
    gemm128<<<gGemm, blk, 0, stream>>>(x, w1_root, b1, B_out, N);
    for (int r = 0; r < 3; ++r) {
        gemm128<<<gGemm, blk, 0, stream>>>(x, w1_rel + (size_t)r * 128 * 128,
                                           nullptr, B_h, N);
        scatter_add_kernel<<<gScat, blk, 0, stream>>>(B_h, esrc, edst, etype, r,
                                                      E, B_out);
    }
    ln_kernel<128, 0><<<gRow, blk, 0, stream>>>(B_out, ln1_g, ln1_b, nullptr,
                                                B_x1, N);

    // ---------------- conv2 (max) ----------------
    gemm128<<<gGemm, blk, 0, stream>>>(B_x1, w2_root, b2, B_out, N);
    for (int r = 0; r < 3; ++r) {
        gemm128<<<gGemm, blk, 0, stream>>>(B_x1, w2_rel + (size_t)r * 128 * 128,
                                           nullptr, B_h, N);
        hipMemsetAsync(B_max, 0, NF * sizeof(unsigned), stream);
        scatter_max_kernel<<<gScat, blk, 0, stream>>>(B_h, esrc, edst, etype, r,
                                                      E, B_max);
        merge_max_kernel<<<gElem, blk, 0, stream>>>(B_max, B_out, (int)NF);
    }
    // h = relu(LN(out)) + 0.2*x1  -> B_h
    ln_kernel<128, 1><<<gRow, blk, 0, stream>>>(B_out, ln2_g, ln2_b, B_x1, B_h, N);

    // ---------------- classifier ----------------
    gemm128<<<gGemm, blk, 0, stream>>>(B_h, cw1, cb1, B_out, N);
    ln_kernel<128, 2><<<gRow, blk, 0, stream>>>(B_out, cln1_g, cln1_b, nullptr,
                                                B_x1, N);
    gemm_small<128, 64><<<gSmall, blk, 0, stream>>>(B_x1, cw2, cb2, B_h, N);
    ln_kernel<64, 2><<<gRow, blk, 0, stream>>>(B_h, cln2_g, cln2_b, nullptr,
                                               B_maxf, N);
    gemm_small<64, 40><<<gSmall, blk, 0, stream>>>(B_maxf, cw3, cb3, B_out, N);
    lsm_kernel<<<gRow, blk, 0, stream>>>(B_out, (float*)d_out, N);
}

// Round 2
// 765.967 us; speedup vs baseline: 2.9926x; 2.9926x over previous
//
#include <hip/hip_runtime.h>
#include <hip/hip_bf16.h>
#include <math.h>

// ---------------------------------------------------------------------------
// RGCN forward, CSR pull-based aggregation (no feature atomics).
//   conv1(add) -> LN+ReLU -> conv2(max) -> LN+ReLU+0.2*res ->
//   [Lin->LN->GELU] x2 -> Lin -> log_softmax.   All f32.
// ws layout: B0=H, B1=acc, B2=CSR(+scratch), B3=x1  (4 x [N,128] = 102.4MB)
// ---------------------------------------------------------------------------

// ============================ GEMM  M x 128 @ 128 x 128 ====================
__global__ __launch_bounds__(256) void gemm128(const float* __restrict__ X,
                                               const float* __restrict__ W,
                                               const float* __restrict__ bias,
                                               float* __restrict__ Y, int M) {
    __shared__ float Ws[64 * 128];   // one K-half of W: 32KB
    __shared__ float Xs[32 * 128];   // 16KB
    const int tid = threadIdx.x;
    const int row0 = blockIdx.x * 32;

    const float4* X4 = (const float4*)X;
    float4* Xs4 = (float4*)Xs;
#pragma unroll
    for (int j = 0; j < 4; ++j) {
        int idx = tid + j * 256;
        int r = idx >> 5, c = idx & 31;
        float4 v = make_float4(0.f, 0.f, 0.f, 0.f);
        if (row0 + r < M) v = X4[(size_t)(row0 + r) * 32 + c];
        Xs4[idx] = v;
    }

    const int ty = tid >> 5, tx = tid & 31;
    float acc[4][4];
#pragma unroll
    for (int i = 0; i < 4; ++i)
#pragma unroll
        for (int j = 0; j < 4; ++j) acc[i][j] = 0.f;

    const float4* W4 = (const float4*)W;
    float4* Ws4 = (float4*)Ws;

    for (int kb = 0; kb < 128; kb += 64) {
        __syncthreads();
#pragma unroll
        for (int j = 0; j < 8; ++j) {
            int idx = tid + j * 256;
            Ws4[idx] = W4[(size_t)kb * 32 + idx];
        }
        __syncthreads();
#pragma unroll 8
        for (int kk = 0; kk < 64; ++kk) {
            float4 wv = Ws4[kk * 32 + tx];
            int k = kb + kk;
#pragma unroll
            for (int i = 0; i < 4; ++i) {
                float xv = Xs[(ty + 8 * i) * 128 + k];
                acc[i][0] = fmaf(xv, wv.x, acc[i][0]);
                acc[i][1] = fmaf(xv, wv.y, acc[i][1]);
                acc[i][2] = fmaf(xv, wv.z, acc[i][2]);
                acc[i][3] = fmaf(xv, wv.w, acc[i][3]);
            }
        }
    }

    float4 bv = make_float4(0.f, 0.f, 0.f, 0.f);
    if (bias) bv = ((const float4*)bias)[tx];
#pragma unroll
    for (int i = 0; i < 4; ++i) {
        int r = row0 + ty + 8 * i;
        if (r < M) {
            float4 o;
            o.x = acc[i][0] + bv.x; o.y = acc[i][1] + bv.y;
            o.z = acc[i][2] + bv.z; o.w = acc[i][3] + bv.w;
            ((float4*)Y)[(size_t)r * 32 + tx] = o;
        }
    }
}

// ===================== small GEMM  M x K @ K x N  (K,N <= 128) =============
template <int K, int N>
__global__ __launch_bounds__(256) void gemm_small(const float* __restrict__ X,
                                                  const float* __restrict__ W,
                                                  const float* __restrict__ bias,
                                                  float* __restrict__ Y, int M) {
    __shared__ float Ws[K * N];
    __shared__ float Xs[8 * K];
    const int tid = threadIdx.x;
    const int row0 = blockIdx.x * 8;
    for (int i = tid; i < K * N; i += 256) Ws[i] = W[i];
    for (int i = tid; i < 8 * K; i += 256) {
        int r = i / K, c = i % K;
        Xs[i] = (row0 + r < M) ? X[(size_t)(row0 + r) * K + c] : 0.f;
    }
    __syncthreads();
    const int r = tid >> 5, tx = tid & 31;
    constexpr int NJ = (N + 31) / 32;
    float acc[NJ];
#pragma unroll
    for (int j = 0; j < NJ; ++j) acc[j] = 0.f;
    for (int k = 0; k < K; ++k) {
        float xv = Xs[r * K + k];
#pragma unroll
        for (int j = 0; j < NJ; ++j) {
            int n = tx + 32 * j;
            if (n < N) acc[j] = fmaf(xv, Ws[k * N + n], acc[j]);
        }
    }
    int grow = row0 + r;
    if (grow < M) {
#pragma unroll
        for (int j = 0; j < NJ; ++j) {
            int n = tx + 32 * j;
            if (n < N) Y[(size_t)grow * N + n] = acc[j] + (bias ? bias[n] : 0.f);
        }
    }
}

// ============================== CSR build ==================================
__global__ __launch_bounds__(256) void hist_kernel(const int* __restrict__ edst,
                                                   int* __restrict__ deg, int E) {
    int e = blockIdx.x * 256 + threadIdx.x;
    if (e < E) atomicAdd(&deg[edst[e]], 1);
}

// 256-element exclusive block scan (Hillis-Steele); sums!=null -> block totals
__global__ __launch_bounds__(256) void scan_block(const int* __restrict__ in,
                                                  int* __restrict__ out,
                                                  int* __restrict__ sums, int n) {
    __shared__ int s[256];
    int g = blockIdx.x * 256 + threadIdx.x;
    int v = (g < n) ? in[g] : 0;
    s[threadIdx.x] = v;
    __syncthreads();
    int acc = v;
    for (int off = 1; off < 256; off <<= 1) {
        int t = (threadIdx.x >= off) ? s[threadIdx.x - off] : 0;
        __syncthreads();
        acc += t;
        s[threadIdx.x] = acc;
        __syncthreads();
    }
    if (g < n) out[g] = acc - v;          // exclusive
    if (threadIdx.x == 255 && sums) sums[blockIdx.x] = acc;
}

__global__ __launch_bounds__(256) void scan_add(int* __restrict__ out,
                                                const int* __restrict__ topex,
                                                int n, int total) {
    int g = blockIdx.x * 256 + threadIdx.x;
    if (g < n) out[g] += topex[blockIdx.x];
    if (g == 0) out[n] = total;           // rowptr[N] = E
}

__global__ __launch_bounds__(256) void copy_int(const int* __restrict__ in,
                                                int* __restrict__ out, int n) {
    int g = blockIdx.x * 256 + threadIdx.x;
    if (g < n) out[g] = in[g];
}

__global__ __launch_bounds__(256) void fill_kernel(
    const int* __restrict__ esrc, const int* __restrict__ edst,
    const int* __restrict__ etype, int* __restrict__ cursor,
    unsigned* __restrict__ colidx, int E) {
    int e = blockIdx.x * 256 + threadIdx.x;
    if (e >= E) return;
    int d = edst[e];
    int pos = atomicAdd(&cursor[d], 1);
    colidx[pos] = ((unsigned)etype[e] << 24) | (unsigned)esrc[e];
}

// ======================= pull aggregation (per relation) ===================
// One wave (64 lanes) per node; lane holds float2 (128 cols). AGGR: 0=add 1=max
template <int AGGR>
__global__ __launch_bounds__(256) void agg_pass(
    const float* __restrict__ H, const int* __restrict__ rowptr,
    const unsigned* __restrict__ colidx, int rel,
    float* __restrict__ acc, int N) {
    int node = blockIdx.x * 4 + (threadIdx.x >> 6);
    int lane = threadIdx.x & 63;
    if (node >= N) return;
    int beg = rowptr[node], end = rowptr[node + 1];
    float ax, ay;
    if (AGGR == 0) { ax = 0.f; ay = 0.f; }
    else { ax = -INFINITY; ay = -INFINITY; }
    bool any = false;
    for (int e = beg; e < end; ++e) {
        unsigned p = colidx[e];
        if ((int)(p >> 24) != rel) continue;
        const float2 v = *(const float2*)(H + ((size_t)(p & 0xFFFFFFu)) * 128 +
                                          lane * 2);
        if (AGGR == 0) { ax += v.x; ay += v.y; }
        else { ax = fmaxf(ax, v.x); ay = fmaxf(ay, v.y); }
        any = true;
    }
    if (any) {
        float2* ap = (float2*)(acc + (size_t)node * 128) + lane;
        float2 cur = *ap;
        cur.x += ax; cur.y += ay;
        *ap = cur;
    }
}

// ===================== LayerNorm (+ReLU / +ReLU+res / +GELU) ===============
template <int D, int MODE>
__global__ __launch_bounds__(256) void ln_kernel(const float* __restrict__ in,
                                                 const float* __restrict__ g,
                                                 const float* __restrict__ b,
                                                 const float* __restrict__ resid,
                                                 float* __restrict__ out, int M) {
    int row = blockIdx.x * 4 + (threadIdx.x >> 6);
    int lane = threadIdx.x & 63;
    if (row >= M) return;
    constexpr int EPL = D / 64;
    float v[EPL];
    const float* ip = in + (size_t)row * D;
#pragma unroll
    for (int j = 0; j < EPL; ++j) v[j] = ip[lane * EPL + j];
    float s = 0.f, sq = 0.f;
#pragma unroll
    for (int j = 0; j < EPL; ++j) { s += v[j]; sq += v[j] * v[j]; }
#pragma unroll
    for (int off = 32; off; off >>= 1) {
        s += __shfl_xor(s, off, 64);
        sq += __shfl_xor(sq, off, 64);
    }
    float mu = s * (1.f / D);
    float var = sq * (1.f / D) - mu * mu;
    float rs = rsqrtf(var + 1e-5f);
#pragma unroll
    for (int j = 0; j < EPL; ++j) {
        int c = lane * EPL + j;
        float y = (v[j] - mu) * rs * g[c] + b[c];
        if (MODE == 0) {
            y = fmaxf(y, 0.f);
        } else if (MODE == 1) {
            y = fmaxf(y, 0.f) + 0.2f * resid[(size_t)row * D + c];
        } else {
            y = 0.5f * y * (1.f + erff(y * 0.70710678118654752f));
        }
        out[(size_t)row * D + c] = y;
    }
}

// ============================ log_softmax (rows of 40) =====================
__global__ __launch_bounds__(256) void lsm_kernel(const float* __restrict__ in,
                                                  float* __restrict__ out, int M) {
    int row = blockIdx.x * 4 + (threadIdx.x >> 6);
    int lane = threadIdx.x & 63;
    if (row >= M) return;
    float v = (lane < 40) ? in[(size_t)row * 40 + lane] : -INFINITY;
    float mx = v;
#pragma unroll
    for (int off = 32; off; off >>= 1) mx = fmaxf(mx, __shfl_xor(mx, off, 64));
    float e = (lane < 40) ? __expf(v - mx) : 0.f;
    float sum = e;
#pragma unroll
    for (int off = 32; off; off >>= 1) sum += __shfl_xor(sum, off, 64);
    float ls = logf(sum);
    if (lane < 40) out[(size_t)row * 40 + lane] = v - mx - ls;
}

// ===========================================================================
extern "C" void kernel_launch(void* const* d_in, const int* in_sizes, int n_in,
                              void* d_out, int out_size, void* d_ws, size_t ws_size,
                              hipStream_t stream) {
    const float* x       = (const float*)d_in[0];
    const int*   eidx    = (const int*)d_in[1];
    const int*   etype   = (const int*)d_in[2];
    const float* w1_rel  = (const float*)d_in[3];
    const float* w1_root = (const float*)d_in[4];
    const float* b1      = (const float*)d_in[5];
    const float* ln1_g   = (const float*)d_in[6];
    const float* ln1_b   = (const float*)d_in[7];
    const float* w2_rel  = (const float*)d_in[8];
    const float* w2_root = (const float*)d_in[9];
    const float* b2      = (const float*)d_in[10];
    const float* ln2_g   = (const float*)d_in[11];
    const float* ln2_b   = (const float*)d_in[12];
    const float* cw1     = (const float*)d_in[13];
    const float* cb1     = (const float*)d_in[14];
    const float* cln1_g  = (const float*)d_in[15];
    const float* cln1_b  = (const float*)d_in[16];
    const float* cw2     = (const float*)d_in[17];
    const float* cb2     = (const float*)d_in[18];
    const float* cln2_g  = (const float*)d_in[19];
    const float* cln2_b  = (const float*)d_in[20];
    const float* cw3     = (const float*)d_in[21];
    const float* cb3     = (const float*)d_in[22];

    const int N = in_sizes[0] / 128;   // 50000
    const int E = in_sizes[1] / 2;     // 600000
    const int* esrc = eidx;
    const int* edst = eidx + E;

    const size_t NF = (size_t)N * 128;
    float* B0 = (float*)d_ws;          // H (per-relation transformed feats)
    float* B1 = B0 + NF;               // acc (conv out), classifier temps
    float* B2 = B1 + NF;               // CSR + scan scratch
    float* B3 = B2 + NF;               // x1

    // CSR layout inside B2
    int*      rowptr  = (int*)B2;                    // [N+1]
    int*      cursor  = rowptr + (N + 1);            // [N]
    int*      deg     = cursor + N;                  // [N]  (scan input)
    int*      bsums   = deg + N;                     // [256]
    int*      btop    = bsums + 256;                 // [256]
    unsigned* colidx  = (unsigned*)(btop + 256);     // [E]

    const dim3 blk(256);
    const int gGemm  = (N + 31) / 32;
    const int gSmall = (N + 7) / 8;
    const int gRow   = (N + 3) / 4;
    const int gEdge  = (E + 255) / 256;
    const int gNode  = (N + 255) / 256;
    const int nScanB = (N + 255) / 256;   // 196

    // ---------------- CSR build (once, reused by both convs) ----------------
    hipMemsetAsync(deg, 0, (size_t)N * sizeof(int), stream);
    hist_kernel<<<gEdge, blk, 0, stream>>>(edst, deg, E);
    scan_block<<<nScanB, blk, 0, stream>>>(deg, rowptr, bsums, N);
    scan_block<<<1, blk, 0, stream>>>(bsums, btop, nullptr, nScanB);
    scan_add<<<nScanB, blk, 0, stream>>>(rowptr, btop, N, E);
    copy_int<<<gNode, blk, 0, stream>>>(rowptr, cursor, N);
    fill_kernel<<<gEdge, blk, 0, stream>>>(esrc, edst, etype, cursor, colidx, E);

    // ---------------- conv1 (add) ----------------
    gemm128<<<gGemm, blk, 0, stream>>>(x, w1_root, b1, B1, N);
    for (int r = 0; r < 3; ++r) {
        gemm128<<<gGemm, blk, 0, stream>>>(x, w1_rel + (size_t)r * 128 * 128,
                                           nullptr, B0, N);
        agg_pass<0><<<gRow, blk, 0, stream>>>(B0, rowptr, colidx, r, B1, N);
    }
    ln_kernel<128, 0><<<gRow, blk, 0, stream>>>(B1, ln1_g, ln1_b, nullptr, B3, N);

    // ---------------- conv2 (max) ----------------
    gemm128<<<gGemm, blk, 0, stream>>>(B3, w2_root, b2, B1, N);
    for (int r = 0; r < 3; ++r) {
        gemm128<<<gGemm, blk, 0, stream>>>(B3, w2_rel + (size_t)r * 128 * 128,
                                           nullptr, B0, N);
        agg_pass<1><<<gRow, blk, 0, stream>>>(B0, rowptr, colidx, r, B1, N);
    }
    // h2 = relu(LN(B1)) + 0.2*x1  -> B0
    ln_kernel<128, 1><<<gRow, blk, 0, stream>>>(B1, ln2_g, ln2_b, B3, B0, N);

    // ---------------- classifier ----------------
    gemm128<<<gGemm, blk, 0, stream>>>(B0, cw1, cb1, B1, N);
    ln_kernel<128, 2><<<gRow, blk, 0, stream>>>(B1, cln1_g, cln1_b, nullptr, B3, N);
    gemm_small<128, 64><<<gSmall, blk, 0, stream>>>(B3, cw2, cb2, B0, N);
    ln_kernel<64, 2><<<gRow, blk, 0, stream>>>(B0, cln2_g, cln2_b, nullptr, B1, N);
    gemm_small<64, 40><<<gSmall, blk, 0, stream>>>(B1, cw3, cb3, B0, N);
    lsm_kernel<<<gRow, blk, 0, stream>>>(B0, (float*)d_out, N);
}

// Round 3
// 682.898 us; speedup vs baseline: 3.3566x; 1.1216x over previous
//
#include <hip/hip_runtime.h>
#include <hip/hip_bf16.h>
#include <math.h>

// ---------------------------------------------------------------------------
// RGCN forward. CSR (dst,rel)-sorted pull aggregation + split-bf16 MFMA GEMM.
// ws: B0=H/temps, B1=acc/temps, B2=CSR + W-bf16 scratch, B3=x1/temps.
// ---------------------------------------------------------------------------

typedef __attribute__((ext_vector_type(8))) short bf16x8;
typedef __attribute__((ext_vector_type(4))) float f32x4;

// split f32 into bf16 hi + bf16 lo (v ~= hi + lo, residual ~2^-17 |v|)
__device__ __forceinline__ void split_bf16(float v, unsigned short& h,
                                           unsigned short& l) {
    unsigned uv = __float_as_uint(v);
    unsigned rh = uv + 0x7FFFu + ((uv >> 16) & 1u);   // RNE to bf16
    unsigned short hu = (unsigned short)(rh >> 16);
    float hf = __uint_as_float((unsigned)hu << 16);
    float lo = v - hf;                                // exact
    unsigned ul = __float_as_uint(lo);
    unsigned rl = ul + 0x7FFFu + ((ul >> 16) & 1u);
    h = hu;
    l = (unsigned short)(rl >> 16);
}

// W[128][128] f32 -> transposed bf16 hi/lo Wt[col][k]
__global__ __launch_bounds__(256) void convert_w(const float* __restrict__ W,
                                                 unsigned short* __restrict__ wtH,
                                                 unsigned short* __restrict__ wtL) {
    int idx = blockIdx.x * 256 + threadIdx.x;   // 16384
    int k = idx >> 7, col = idx & 127;
    unsigned short h, l;
    split_bf16(W[idx], h, l);
    wtH[col * 128 + k] = h;
    wtL[col * 128 + k] = l;
}

// ================= MFMA GEMM  Y[M,128] = X[M,128] @ W[128,128] (+bias) =====
// 256 thr / 4 waves, 64 rows per block, wave w -> cols [w*32, w*32+32).
// Split-bf16: 3 MFMA per (m,n,k-step). LDS XOR-swizzled (G4).
__global__ __launch_bounds__(256) void gemm128_mfma(
    const float* __restrict__ X, const unsigned short* __restrict__ WtHi,
    const unsigned short* __restrict__ WtLo, const float* __restrict__ bias,
    float* __restrict__ Y, int M) {
    __shared__ __align__(16) unsigned short Xhi[64 * 64], Xlo[64 * 64];
    __shared__ __align__(16) unsigned short Whi[128 * 64], Wlo[128 * 64];
    const int tid = threadIdx.x;
    const int row0 = blockIdx.x * 64;
    const int wv = tid >> 6, lane = tid & 63;
    const int l15 = lane & 15, lg = lane >> 4;
    const int wcol = wv * 32;

    const f32x4 zero = {0.f, 0.f, 0.f, 0.f};
    f32x4 acc[4][2];
#pragma unroll
    for (int m = 0; m < 4; ++m)
#pragma unroll
        for (int n = 0; n < 2; ++n) acc[m][n] = zero;

    for (int kc = 0; kc < 128; kc += 64) {
        __syncthreads();
        // ---- stage X chunk [64 rows][64 k], f32 -> bf16 hi/lo, swizzled ----
#pragma unroll
        for (int i = 0; i < 16; ++i) {
            int idx = tid + i * 256;
            int r = idx >> 6, k = idx & 63;
            int gr = row0 + r;
            float v = (gr < M) ? X[(size_t)gr * 128 + kc + k] : 0.f;
            unsigned short h, l;
            split_bf16(v, h, l);
            int byte = (r * 128 + k * 2) ^ ((r & 7) << 4);
            *(unsigned short*)((char*)Xhi + byte) = h;
            *(unsigned short*)((char*)Xlo + byte) = l;
        }
        // ---- stage W chunk (pre-transposed bf16 Wt[col][128]) --------------
#pragma unroll
        for (int i = 0; i < 16; ++i) {
            int idx = tid + i * 256;            // 4096 uint slots
            int col = idx >> 5, kp = idx & 31;  // kp: pair of k
            unsigned vh = *(const unsigned*)(WtHi + col * 128 + kc + kp * 2);
            unsigned vl = *(const unsigned*)(WtLo + col * 128 + kc + kp * 2);
            int byte = (col * 128 + kp * 4) ^ ((col & 7) << 4);
            *(unsigned*)((char*)Whi + byte) = vh;
            *(unsigned*)((char*)Wlo + byte) = vl;
        }
        __syncthreads();

#pragma unroll
        for (int kk = 0; kk < 64; kk += 32) {
            bf16x8 ah[4], al[4], bh[2], bl[2];
#pragma unroll
            for (int m = 0; m < 4; ++m) {
                int row = m * 16 + l15;
                int byte = (row * 128 + kk * 2 + (lg << 4)) ^ ((row & 7) << 4);
                ah[m] = *(const bf16x8*)((const char*)Xhi + byte);
                al[m] = *(const bf16x8*)((const char*)Xlo + byte);
            }
#pragma unroll
            for (int n = 0; n < 2; ++n) {
                int col = wcol + n * 16 + l15;
                int byte = (col * 128 + kk * 2 + (lg << 4)) ^ ((col & 7) << 4);
                bh[n] = *(const bf16x8*)((const char*)Whi + byte);
                bl[n] = *(const bf16x8*)((const char*)Wlo + byte);
            }
#pragma unroll
            for (int m = 0; m < 4; ++m)
#pragma unroll
                for (int n = 0; n < 2; ++n) {
                    acc[m][n] = __builtin_amdgcn_mfma_f32_16x16x32_bf16(
                        ah[m], bh[n], acc[m][n], 0, 0, 0);
                    acc[m][n] = __builtin_amdgcn_mfma_f32_16x16x32_bf16(
                        al[m], bh[n], acc[m][n], 0, 0, 0);
                    acc[m][n] = __builtin_amdgcn_mfma_f32_16x16x32_bf16(
                        ah[m], bl[n], acc[m][n], 0, 0, 0);
                }
        }
    }

    // epilogue: C/D layout col=lane&15, row=(lane>>4)*4+i  [verified m89/m91]
#pragma unroll
    for (int n = 0; n < 2; ++n) {
        int col = wcol + n * 16 + l15;
        float bv = bias ? bias[col] : 0.f;
#pragma unroll
        for (int m = 0; m < 4; ++m)
#pragma unroll
            for (int i = 0; i < 4; ++i) {
                int row = row0 + m * 16 + lg * 4 + i;
                if (row < M) Y[(size_t)row * 128 + col] = acc[m][n][i] + bv;
            }
    }
}

// ===================== small GEMM  M x K @ K x N  (f32) ====================
template <int K, int N>
__global__ __launch_bounds__(256) void gemm_small(const float* __restrict__ X,
                                                  const float* __restrict__ W,
                                                  const float* __restrict__ bias,
                                                  float* __restrict__ Y, int M) {
    __shared__ float Ws[K * N];
    __shared__ float Xs[8 * K];
    const int tid = threadIdx.x;
    const int row0 = blockIdx.x * 8;
    for (int i = tid; i < K * N; i += 256) Ws[i] = W[i];
    for (int i = tid; i < 8 * K; i += 256) {
        int r = i / K, c = i % K;
        Xs[i] = (row0 + r < M) ? X[(size_t)(row0 + r) * K + c] : 0.f;
    }
    __syncthreads();
    const int r = tid >> 5, tx = tid & 31;
    constexpr int NJ = (N + 31) / 32;
    float acc[NJ];
#pragma unroll
    for (int j = 0; j < NJ; ++j) acc[j] = 0.f;
    for (int k = 0; k < K; ++k) {
        float xv = Xs[r * K + k];
#pragma unroll
        for (int j = 0; j < NJ; ++j) {
            int n = tx + 32 * j;
            if (n < N) acc[j] = fmaf(xv, Ws[k * N + n], acc[j]);
        }
    }
    int grow = row0 + r;
    if (grow < M) {
#pragma unroll
        for (int j = 0; j < NJ; ++j) {
            int n = tx + 32 * j;
            if (n < N) Y[(size_t)grow * N + n] = acc[j] + (bias ? bias[n] : 0.f);
        }
    }
}

// ============================== CSR build ((dst,rel)-sorted) ===============
__global__ __launch_bounds__(256) void hist3_kernel(const int* __restrict__ edst,
                                                    const int* __restrict__ etype,
                                                    int* __restrict__ deg3, int E) {
    int e = blockIdx.x * 256 + threadIdx.x;
    if (e < E) atomicAdd(&deg3[edst[e] * 3 + etype[e]], 1);
}

__global__ __launch_bounds__(256) void degtot_kernel(const int* __restrict__ deg3,
                                                     int* __restrict__ degtot, int N) {
    int n = blockIdx.x * 256 + threadIdx.x;
    if (n < N) degtot[n] = deg3[n * 3] + deg3[n * 3 + 1] + deg3[n * 3 + 2];
}

__global__ __launch_bounds__(256) void scan_block(const int* __restrict__ in,
                                                  int* __restrict__ out,
                                                  int* __restrict__ sums, int n) {
    __shared__ int s[256];
    int g = blockIdx.x * 256 + threadIdx.x;
    int v = (g < n) ? in[g] : 0;
    s[threadIdx.x] = v;
    __syncthreads();
    int acc = v;
    for (int off = 1; off < 256; off <<= 1) {
        int t = (threadIdx.x >= off) ? s[threadIdx.x - off] : 0;
        __syncthreads();
        acc += t;
        s[threadIdx.x] = acc;
        __syncthreads();
    }
    if (g < n) out[g] = acc - v;
    if (threadIdx.x == 255 && sums) sums[blockIdx.x] = acc;
}

__global__ __launch_bounds__(256) void scan_add(int* __restrict__ out,
                                                const int* __restrict__ topex,
                                                int n, int total) {
    int g = blockIdx.x * 256 + threadIdx.x;
    if (g < n) out[g] += topex[blockIdx.x];
    if (g == 0) out[n] = total;
}

__global__ __launch_bounds__(256) void ranges_kernel(
    const int* __restrict__ rowptr, const int* __restrict__ deg3,
    int4* __restrict__ ranges, int* __restrict__ cursor3, int N) {
    int n = blockIdx.x * 256 + threadIdx.x;
    if (n >= N) return;
    int b = rowptr[n];
    int d0 = deg3[n * 3], d1 = deg3[n * 3 + 1];
    int4 r;
    r.x = b; r.y = b + d0; r.z = b + d0 + d1; r.w = rowptr[n + 1];
    ranges[n] = r;
    cursor3[n * 3] = r.x; cursor3[n * 3 + 1] = r.y; cursor3[n * 3 + 2] = r.z;
}

__global__ __launch_bounds__(256) void fill3_kernel(
    const int* __restrict__ esrc, const int* __restrict__ edst,
    const int* __restrict__ etype, int* __restrict__ cursor3,
    int* __restrict__ colidx, int E) {
    int e = blockIdx.x * 256 + threadIdx.x;
    if (e >= E) return;
    int pos = atomicAdd(&cursor3[edst[e] * 3 + etype[e]], 1);
    colidx[pos] = esrc[e];
}

// ======================= pull aggregation (per relation) ===================
// wave per node, float2/lane, 4-deep unrolled gathers. AGGR: 0=add 1=max
template <int AGGR>
__global__ __launch_bounds__(256) void agg_pass(
    const float* __restrict__ H, const int4* __restrict__ ranges,
    const int* __restrict__ colidx, int rel, float* __restrict__ acc, int N) {
    int node = blockIdx.x * 4 + (threadIdx.x >> 6);
    int lane = threadIdx.x & 63;
    if (node >= N) return;
    int4 rg = ranges[node];
    int beg, end;
    if (rel == 0) { beg = rg.x; end = rg.y; }
    else if (rel == 1) { beg = rg.y; end = rg.z; }
    else { beg = rg.z; end = rg.w; }
    if (beg >= end) return;
    const float2* H2 = (const float2*)H;
    float ax, ay;
    if (AGGR == 0) { ax = 0.f; ay = 0.f; }
    else { ax = -INFINITY; ay = -INFINITY; }
    int e = beg;
    for (; e + 4 <= end; e += 4) {
        int s0 = colidx[e], s1 = colidx[e + 1], s2 = colidx[e + 2], s3 = colidx[e + 3];
        float2 v0 = H2[(size_t)s0 * 64 + lane];
        float2 v1 = H2[(size_t)s1 * 64 + lane];
        float2 v2 = H2[(size_t)s2 * 64 + lane];
        float2 v3 = H2[(size_t)s3 * 64 + lane];
        if (AGGR == 0) {
            ax += (v0.x + v1.x) + (v2.x + v3.x);
            ay += (v0.y + v1.y) + (v2.y + v3.y);
        } else {
            ax = fmaxf(ax, fmaxf(fmaxf(v0.x, v1.x), fmaxf(v2.x, v3.x)));
            ay = fmaxf(ay, fmaxf(fmaxf(v0.y, v1.y), fmaxf(v2.y, v3.y)));
        }
    }
    for (; e < end; ++e) {
        float2 v = H2[(size_t)colidx[e] * 64 + lane];
        if (AGGR == 0) { ax += v.x; ay += v.y; }
        else { ax = fmaxf(ax, v.x); ay = fmaxf(ay, v.y); }
    }
    float2* ap = (float2*)(acc + (size_t)node * 128) + lane;
    float2 cur = *ap;
    cur.x += ax; cur.y += ay;
    *ap = cur;
}

// ===================== LayerNorm (+ReLU / +ReLU+res / +GELU) ===============
template <int D, int MODE>
__global__ __launch_bounds__(256) void ln_kernel(const float* __restrict__ in,
                                                 const float* __restrict__ g,
                                                 const float* __restrict__ b,
                                                 const float* __restrict__ resid,
                                                 float* __restrict__ out, int M) {
    int row = blockIdx.x * 4 + (threadIdx.x >> 6);
    int lane = threadIdx.x & 63;
    if (row >= M) return;
    constexpr int EPL = D / 64;
    float v[EPL];
    const float* ip = in + (size_t)row * D;
#pragma unroll
    for (int j = 0; j < EPL; ++j) v[j] = ip[lane * EPL + j];
    float s = 0.f, sq = 0.f;
#pragma unroll
    for (int j = 0; j < EPL; ++j) { s += v[j]; sq += v[j] * v[j]; }
#pragma unroll
    for (int off = 32; off; off >>= 1) {
        s += __shfl_xor(s, off, 64);
        sq += __shfl_xor(sq, off, 64);
    }
    float mu = s * (1.f / D);
    float var = sq * (1.f / D) - mu * mu;
    float rs = rsqrtf(var + 1e-5f);
#pragma unroll
    for (int j = 0; j < EPL; ++j) {
        int c = lane * EPL + j;
        float y = (v[j] - mu) * rs * g[c] + b[c];
        if (MODE == 0) {
            y = fmaxf(y, 0.f);
        } else if (MODE == 1) {
            y = fmaxf(y, 0.f) + 0.2f * resid[(size_t)row * D + c];
        } else {
            y = 0.5f * y * (1.f + erff(y * 0.70710678118654752f));
        }
        out[(size_t)row * D + c] = y;
    }
}

// ============================ log_softmax (rows of 40) =====================
__global__ __launch_bounds__(256) void lsm_kernel(const float* __restrict__ in,
                                                  float* __restrict__ out, int M) {
    int row = blockIdx.x * 4 + (threadIdx.x >> 6);
    int lane = threadIdx.x & 63;
    if (row >= M) return;
    float v = (lane < 40) ? in[(size_t)row * 40 + lane] : -INFINITY;
    float mx = v;
#pragma unroll
    for (int off = 32; off; off >>= 1) mx = fmaxf(mx, __shfl_xor(mx, off, 64));
    float e = (lane < 40) ? __expf(v - mx) : 0.f;
    float sum = e;
#pragma unroll
    for (int off = 32; off; off >>= 1) sum += __shfl_xor(sum, off, 64);
    float ls = logf(sum);
    if (lane < 40) out[(size_t)row * 40 + lane] = v - mx - ls;
}

// ===========================================================================
extern "C" void kernel_launch(void* const* d_in, const int* in_sizes, int n_in,
                              void* d_out, int out_size, void* d_ws, size_t ws_size,
                              hipStream_t stream) {
    const float* x       = (const float*)d_in[0];
    const int*   eidx    = (const int*)d_in[1];
    const int*   etype   = (const int*)d_in[2];
    const float* w1_rel  = (const float*)d_in[3];
    const float* w1_root = (const float*)d_in[4];
    const float* b1      = (const float*)d_in[5];
    const float* ln1_g   = (const float*)d_in[6];
    const float* ln1_b   = (const float*)d_in[7];
    const float* w2_rel  = (const float*)d_in[8];
    const float* w2_root = (const float*)d_in[9];
    const float* b2      = (const float*)d_in[10];
    const float* ln2_g   = (const float*)d_in[11];
    const float* ln2_b   = (const float*)d_in[12];
    const float* cw1     = (const float*)d_in[13];
    const float* cb1     = (const float*)d_in[14];
    const float* cln1_g  = (const float*)d_in[15];
    const float* cln1_b  = (const float*)d_in[16];
    const float* cw2     = (const float*)d_in[17];
    const float* cb2     = (const float*)d_in[18];
    const float* cln2_g  = (const float*)d_in[19];
    const float* cln2_b  = (const float*)d_in[20];
    const float* cw3     = (const float*)d_in[21];
    const float* cb3     = (const float*)d_in[22];

    const int N = in_sizes[0] / 128;   // 50000
    const int E = in_sizes[1] / 2;     // 600000
    const int* esrc = eidx;
    const int* edst = eidx + E;

    const size_t NF = (size_t)N * 128;
    float* B0 = (float*)d_ws;
    float* B1 = B0 + NF;
    float* B2 = B1 + NF;
    float* B3 = B2 + NF;

    // CSR + scratch inside B2 (~5MB of 25.6MB)
    int* rowptr  = (int*)B2;                      // N+1
    int* degtot  = rowptr + (N + 1);              // N
    int* deg3    = degtot + N;                    // 3N
    int* cursor3 = deg3 + 3 * N;                  // 3N
    int* bsums   = cursor3 + 3 * N;               // 256
    int* btop    = bsums + 256;                   // 256
    int4* ranges = (int4*)(((uintptr_t)(btop + 256) + 15) & ~(uintptr_t)15);
    int* colidx  = (int*)(ranges + N);            // E
    // W bf16 scratch at B2 + 16MB
    unsigned short* WtHi = (unsigned short*)((char*)B2 + 16u * 1024 * 1024);
    unsigned short* WtLo = WtHi + 128 * 128;

    const dim3 blk(256);
    const int gGemm  = (N + 63) / 64;
    const int gSmall = (N + 7) / 8;
    const int gRow   = (N + 3) / 4;
    const int gEdge  = (E + 255) / 256;
    const int gNode  = (N + 255) / 256;
    const int nScanB = (N + 255) / 256;   // 196 <= 256

    // ---------------- CSR build ----------------
    hipMemsetAsync(deg3, 0, (size_t)3 * N * sizeof(int), stream);
    hist3_kernel<<<gEdge, blk, 0, stream>>>(edst, etype, deg3, E);
    degtot_kernel<<<gNode, blk, 0, stream>>>(deg3, degtot, N);
    scan_block<<<nScanB, blk, 0, stream>>>(degtot, rowptr, bsums, N);
    scan_block<<<1, blk, 0, stream>>>(bsums, btop, nullptr, nScanB);
    scan_add<<<nScanB, blk, 0, stream>>>(rowptr, btop, N, E);
    ranges_kernel<<<gNode, blk, 0, stream>>>(rowptr, deg3, ranges, cursor3, N);
    fill3_kernel<<<gEdge, blk, 0, stream>>>(esrc, edst, etype, cursor3, colidx, E);

    // ---------------- conv1 (add) ----------------
    convert_w<<<64, blk, 0, stream>>>(w1_root, WtHi, WtLo);
    gemm128_mfma<<<gGemm, blk, 0, stream>>>(x, WtHi, WtLo, b1, B1, N);
    for (int r = 0; r < 3; ++r) {
        convert_w<<<64, blk, 0, stream>>>(w1_rel + (size_t)r * 128 * 128, WtHi, WtLo);
        gemm128_mfma<<<gGemm, blk, 0, stream>>>(x, WtHi, WtLo, nullptr, B0, N);
        agg_pass<0><<<gRow, blk, 0, stream>>>(B0, ranges, colidx, r, B1, N);
    }
    ln_kernel<128, 0><<<gRow, blk, 0, stream>>>(B1, ln1_g, ln1_b, nullptr, B3, N);

    // ---------------- conv2 (max) ----------------
    convert_w<<<64, blk, 0, stream>>>(w2_root, WtHi, WtLo);
    gemm128_mfma<<<gGemm, blk, 0, stream>>>(B3, WtHi, WtLo, b2, B1, N);
    for (int r = 0; r < 3; ++r) {
        convert_w<<<64, blk, 0, stream>>>(w2_rel + (size_t)r * 128 * 128, WtHi, WtLo);
        gemm128_mfma<<<gGemm, blk, 0, stream>>>(B3, WtHi, WtLo, nullptr, B0, N);
        agg_pass<1><<<gRow, blk, 0, stream>>>(B0, ranges, colidx, r, B1, N);
    }
    ln_kernel<128, 1><<<gRow, blk, 0, stream>>>(B1, ln2_g, ln2_b, B3, B0, N);

    // ---------------- classifier ----------------
    convert_w<<<64, blk, 0, stream>>>(cw1, WtHi, WtLo);
    gemm128_mfma<<<gGemm, blk, 0, stream>>>(B0, WtHi, WtLo, cb1, B1, N);
    ln_kernel<128, 2><<<gRow, blk, 0, stream>>>(B1, cln1_g, cln1_b, nullptr, B3, N);
    gemm_small<128, 64><<<gSmall, blk, 0, stream>>>(B3, cw2, cb2, B0, N);
    ln_kernel<64, 2><<<gRow, blk, 0, stream>>>(B0, cln2_g, cln2_b, nullptr, B1, N);
    gemm_small<64, 40><<<gSmall, blk, 0, stream>>>(B1, cw3, cb3, B0, N);
    lsm_kernel<<<gRow, blk, 0, stream>>>(B0, (float*)d_out, N);
}

// Round 4
// 472.262 us; speedup vs baseline: 4.8536x; 1.4460x over previous
//
#include <hip/hip_runtime.h>
#include <hip/hip_bf16.h>
#include <math.h>

// ---------------------------------------------------------------------------
// RGCN forward.
// conv1 (add, linear): aggregate-then-transform: S_r = A_r x (one fused gather
//   pass, write-only), then ONE K=512 split-bf16 MFMA GEMM (x,S0,S1,S2).
// conv2 (max): transform-then-gather: root + 3x (H-gemm + fused max RMW).
// classifier: MFMA 128x128, MFMA 128x64, f32 64x40, log_softmax.
// ws: B0,B1,B2 data [N,128]; B3 = CSR + converted weights.  Peak = 4*NF.
// ---------------------------------------------------------------------------

typedef __attribute__((ext_vector_type(8))) short bf16x8;
typedef __attribute__((ext_vector_type(4))) float f32x4;
typedef unsigned short ushort_t;

__device__ __forceinline__ void split_bf16(float v, ushort_t& h, ushort_t& l) {
    unsigned uv = __float_as_uint(v);
    unsigned rh = uv + 0x7FFFu + ((uv >> 16) & 1u);   // RNE to bf16
    ushort_t hu = (ushort_t)(rh >> 16);
    float hf = __uint_as_float((unsigned)hu << 16);
    float lo = v - hf;                                // exact
    unsigned ul = __float_as_uint(lo);
    unsigned rl = ul + 0x7FFFu + ((ul >> 16) & 1u);
    h = hu;
    l = (ushort_t)(rl >> 16);
}

__device__ __forceinline__ void split4(float4 v, uint2& h, uint2& l) {
    ushort_t h0, h1, h2, h3, l0, l1, l2, l3;
    split_bf16(v.x, h0, l0); split_bf16(v.y, h1, l1);
    split_bf16(v.z, h2, l2); split_bf16(v.w, h3, l3);
    h.x = (unsigned)h0 | ((unsigned)h1 << 16);
    h.y = (unsigned)h2 | ((unsigned)h3 << 16);
    l.x = (unsigned)l0 | ((unsigned)l1 << 16);
    l.y = (unsigned)l2 | ((unsigned)l3 << 16);
}

// W[128][NCOL] f32 -> transposed bf16 hi/lo planes [NCOL][128]
__global__ __launch_bounds__(256) void convert_w(const float* __restrict__ W,
                                                 ushort_t* __restrict__ wtH,
                                                 ushort_t* __restrict__ wtL,
                                                 int colshift) {
    int idx = blockIdx.x * 256 + threadIdx.x;   // 128*NCOL
    int k = idx >> colshift, col = idx & ((1 << colshift) - 1);
    ushort_t h, l;
    split_bf16(W[idx], h, l);
    wtH[col * 128 + k] = h;
    wtL[col * 128 + k] = l;
}

// ================= MFMA GEMM  Y[M,NCOL] = sum_s A_s[M,128] @ W_s + bias =====
// 256 thr / 4 waves, 64 rows x NCOL cols per block, 2x2 wave grid.
// Split-bf16 triple MFMA.  wt planes: [NSEG][NCOL][128].
template <int NCOL, int NSEG>
__global__ __launch_bounds__(256, 3) void gemm_mfma(
    const float* __restrict__ A0, const float* __restrict__ A1,
    const float* __restrict__ A2, const float* __restrict__ A3,
    const ushort_t* __restrict__ wtHi, const ushort_t* __restrict__ wtLo,
    const float* __restrict__ bias, float* __restrict__ Y, int M) {
    __shared__ __align__(16) ushort_t Xhi[64 * 64], Xlo[64 * 64];
    __shared__ __align__(16) ushort_t Whi[NCOL * 64], Wlo[NCOL * 64];
    const int tid = threadIdx.x;
    const int row0 = blockIdx.x * 64;
    const int wv = tid >> 6, lane = tid & 63;
    const int l15 = lane & 15, lg = lane >> 4;
    constexpr int WCOLS = NCOL / 2;
    constexpr int NFR = WCOLS / 16;
    const int wrow = (wv >> 1) * 32;
    const int wcol = (wv & 1) * WCOLS;

    f32x4 acc[2][NFR];
#pragma unroll
    for (int m = 0; m < 2; ++m)
#pragma unroll
        for (int n = 0; n < NFR; ++n) acc[m][n] = (f32x4){0.f, 0.f, 0.f, 0.f};

    const float* As[4] = {A0, A1, A2, A3};

    for (int ch = 0; ch < 2 * NSEG; ++ch) {
        const float* __restrict__ A = As[ch >> 1];
        const int kc = (ch & 1) * 64;
        __syncthreads();
        // ---- stage X [64 rows][64 k]: float4 load, split, ds_write_b64 ----
#pragma unroll
        for (int i = 0; i < 4; ++i) {
            int slot = tid + i * 256;          // 1024 float4 slots
            int r = slot >> 4, c4 = slot & 15;
            int gr = row0 + r;
            float4 v = make_float4(0.f, 0.f, 0.f, 0.f);
            if (gr < M) v = *(const float4*)(A + (size_t)gr * 128 + kc + c4 * 4);
            uint2 hh, ll;
            split4(v, hh, ll);
            int byte = (r * 128 + c4 * 8) ^ ((r & 7) << 4);
            *(uint2*)((char*)Xhi + byte) = hh;
            *(uint2*)((char*)Xlo + byte) = ll;
        }
        // ---- stage W chunk [NCOL][64 k] from pre-converted planes ---------
        const ushort_t* __restrict__ wh = wtHi + (ch >> 1) * (NCOL * 128);
        const ushort_t* __restrict__ wl = wtLo + (ch >> 1) * (NCOL * 128);
#pragma unroll
        for (int i = 0; i < NCOL / 16; ++i) {
            int slot = tid + i * 256;          // NCOL*16 8B-chunks
            int col = slot >> 4, c8 = slot & 15;
            int go = col * 128 + kc + c8 * 4;
            uint2 vh = *(const uint2*)(wh + go);
            uint2 vl = *(const uint2*)(wl + go);
            int byte = (col * 128 + c8 * 8) ^ ((col & 7) << 4);
            *(uint2*)((char*)Whi + byte) = vh;
            *(uint2*)((char*)Wlo + byte) = vl;
        }
        __syncthreads();

#pragma unroll
        for (int kk = 0; kk < 2; ++kk) {
            bf16x8 ah[2], al[2], bh[NFR], bl[NFR];
#pragma unroll
            for (int m = 0; m < 2; ++m) {
                int row = wrow + m * 16 + l15;
                int byte = (row * 128 + kk * 64 + lg * 16) ^ ((row & 7) << 4);
                ah[m] = *(const bf16x8*)((const char*)Xhi + byte);
                al[m] = *(const bf16x8*)((const char*)Xlo + byte);
            }
#pragma unroll
            for (int n = 0; n < NFR; ++n) {
                int col = wcol + n * 16 + l15;
                int byte = (col * 128 + kk * 64 + lg * 16) ^ ((col & 7) << 4);
                bh[n] = *(const bf16x8*)((const char*)Whi + byte);
                bl[n] = *(const bf16x8*)((const char*)Wlo + byte);
            }
#pragma unroll
            for (int m = 0; m < 2; ++m)
#pragma unroll
                for (int n = 0; n < NFR; ++n) {
                    acc[m][n] = __builtin_amdgcn_mfma_f32_16x16x32_bf16(
                        ah[m], bh[n], acc[m][n], 0, 0, 0);
                    acc[m][n] = __builtin_amdgcn_mfma_f32_16x16x32_bf16(
                        al[m], bh[n], acc[m][n], 0, 0, 0);
                    acc[m][n] = __builtin_amdgcn_mfma_f32_16x16x32_bf16(
                        ah[m], bl[n], acc[m][n], 0, 0, 0);
                }
        }
    }

    // epilogue: C/D layout col=lane&15, row=(lane>>4)*4+i
#pragma unroll
    for (int n = 0; n < NFR; ++n) {
        int col = wcol + n * 16 + l15;
        float bv = bias ? bias[col] : 0.f;
#pragma unroll
        for (int m = 0; m < 2; ++m)
#pragma unroll
            for (int i = 0; i < 4; ++i) {
                int row = row0 + wrow + m * 16 + lg * 4 + i;
                if (row < M) Y[(size_t)row * NCOL + col] = acc[m][n][i] + bv;
            }
    }
}

// ============================== CSR build ((dst,rel)-sorted) ===============
__global__ __launch_bounds__(256) void hist3_kernel(const int* __restrict__ edst,
                                                    const int* __restrict__ etype,
                                                    int* __restrict__ deg3, int E) {
    int e = blockIdx.x * 256 + threadIdx.x;
    if (e < E) atomicAdd(&deg3[edst[e] * 3 + etype[e]], 1);
}

__global__ __launch_bounds__(256) void degtot_kernel(const int* __restrict__ deg3,
                                                     int* __restrict__ degtot, int N) {
    int n = blockIdx.x * 256 + threadIdx.x;
    if (n < N) degtot[n] = deg3[n * 3] + deg3[n * 3 + 1] + deg3[n * 3 + 2];
}

__global__ __launch_bounds__(256) void scan_block(const int* __restrict__ in,
                                                  int* __restrict__ out,
                                                  int* __restrict__ sums, int n) {
    __shared__ int s[256];
    int g = blockIdx.x * 256 + threadIdx.x;
    int v = (g < n) ? in[g] : 0;
    s[threadIdx.x] = v;
    __syncthreads();
    int acc = v;
    for (int off = 1; off < 256; off <<= 1) {
        int t = (threadIdx.x >= off) ? s[threadIdx.x - off] : 0;
        __syncthreads();
        acc += t;
        s[threadIdx.x] = acc;
        __syncthreads();
    }
    if (g < n) out[g] = acc - v;
    if (threadIdx.x == 255 && sums) sums[blockIdx.x] = acc;
}

__global__ __launch_bounds__(256) void scan_add(int* __restrict__ out,
                                                const int* __restrict__ topex,
                                                int n, int total) {
    int g = blockIdx.x * 256 + threadIdx.x;
    if (g < n) out[g] += topex[blockIdx.x];
    if (g == 0) out[n] = total;
}

__global__ __launch_bounds__(256) void ranges_kernel(
    const int* __restrict__ rowptr, const int* __restrict__ deg3,
    int4* __restrict__ ranges, int* __restrict__ cursor3, int N) {
    int n = blockIdx.x * 256 + threadIdx.x;
    if (n >= N) return;
    int b = rowptr[n];
    int d0 = deg3[n * 3], d1 = deg3[n * 3 + 1];
    int4 r;
    r.x = b; r.y = b + d0; r.z = b + d0 + d1; r.w = rowptr[n + 1];
    ranges[n] = r;
    cursor3[n * 3] = r.x; cursor3[n * 3 + 1] = r.y; cursor3[n * 3 + 2] = r.z;
}

__global__ __launch_bounds__(256) void fill3_kernel(
    const int* __restrict__ esrc, const int* __restrict__ edst,
    const int* __restrict__ etype, int* __restrict__ cursor3,
    int* __restrict__ colidx, int E) {
    int e = blockIdx.x * 256 + threadIdx.x;
    if (e >= E) return;
    int pos = atomicAdd(&cursor3[edst[e] * 3 + etype[e]], 1);
    colidx[pos] = esrc[e];
}

// ===================== fused add-gather: S_r = A_r x  (write-only) =========
// 32 lanes per node (float4/lane), 8 nodes per block.
__device__ __forceinline__ float4 gather_sum(const float4* __restrict__ X4,
                                             const int* __restrict__ colidx,
                                             int beg, int end, int l) {
    float4 a = make_float4(0.f, 0.f, 0.f, 0.f);
    int e = beg;
    for (; e + 4 <= end; e += 4) {
        int s0 = colidx[e], s1 = colidx[e + 1];
        int s2 = colidx[e + 2], s3 = colidx[e + 3];
        float4 v0 = X4[(size_t)s0 * 32 + l];
        float4 v1 = X4[(size_t)s1 * 32 + l];
        float4 v2 = X4[(size_t)s2 * 32 + l];
        float4 v3 = X4[(size_t)s3 * 32 + l];
        a.x += (v0.x + v1.x) + (v2.x + v3.x);
        a.y += (v0.y + v1.y) + (v2.y + v3.y);
        a.z += (v0.z + v1.z) + (v2.z + v3.z);
        a.w += (v0.w + v1.w) + (v2.w + v3.w);
    }
    for (; e < end; ++e) {
        float4 v = X4[(size_t)colidx[e] * 32 + l];
        a.x += v.x; a.y += v.y; a.z += v.z; a.w += v.w;
    }
    return a;
}

__global__ __launch_bounds__(256) void agg3_add(
    const float* __restrict__ x, const int4* __restrict__ ranges,
    const int* __restrict__ colidx, float* __restrict__ S0,
    float* __restrict__ S1, float* __restrict__ S2, int N) {
    int node = blockIdx.x * 8 + (threadIdx.x >> 5);
    int l = threadIdx.x & 31;
    if (node >= N) return;
    int4 rg = ranges[node];
    const float4* X4 = (const float4*)x;
    float4 a0 = gather_sum(X4, colidx, rg.x, rg.y, l);
    float4 a1 = gather_sum(X4, colidx, rg.y, rg.z, l);
    float4 a2 = gather_sum(X4, colidx, rg.z, rg.w, l);
    ((float4*)S0)[(size_t)node * 32 + l] = a0;
    ((float4*)S1)[(size_t)node * 32 + l] = a1;
    ((float4*)S2)[(size_t)node * 32 + l] = a2;
}

// ===================== max-gather RMW: acc += max_r(H[src])  ===============
__global__ __launch_bounds__(256) void maxagg(
    const float* __restrict__ H, const int4* __restrict__ ranges,
    const int* __restrict__ colidx, int rel, float* __restrict__ acc, int N) {
    int node = blockIdx.x * 8 + (threadIdx.x >> 5);
    int l = threadIdx.x & 31;
    if (node >= N) return;
    int4 rg = ranges[node];
    int beg = (rel == 0) ? rg.x : ((rel == 1) ? rg.y : rg.z);
    int end = (rel == 0) ? rg.y : ((rel == 1) ? rg.z : rg.w);
    if (beg >= end) return;
    const float4* H4 = (const float4*)H;
    float4 m = make_float4(-INFINITY, -INFINITY, -INFINITY, -INFINITY);
    int e = beg;
    for (; e + 4 <= end; e += 4) {
        int s0 = colidx[e], s1 = colidx[e + 1];
        int s2 = colidx[e + 2], s3 = colidx[e + 3];
        float4 v0 = H4[(size_t)s0 * 32 + l];
        float4 v1 = H4[(size_t)s1 * 32 + l];
        float4 v2 = H4[(size_t)s2 * 32 + l];
        float4 v3 = H4[(size_t)s3 * 32 + l];
        m.x = fmaxf(m.x, fmaxf(fmaxf(v0.x, v1.x), fmaxf(v2.x, v3.x)));
        m.y = fmaxf(m.y, fmaxf(fmaxf(v0.y, v1.y), fmaxf(v2.y, v3.y)));
        m.z = fmaxf(m.z, fmaxf(fmaxf(v0.z, v1.z), fmaxf(v2.z, v3.z)));
        m.w = fmaxf(m.w, fmaxf(fmaxf(v0.w, v1.w), fmaxf(v2.w, v3.w)));
    }
    for (; e < end; ++e) {
        float4 v = H4[(size_t)colidx[e] * 32 + l];
        m.x = fmaxf(m.x, v.x); m.y = fmaxf(m.y, v.y);
        m.z = fmaxf(m.z, v.z); m.w = fmaxf(m.w, v.w);
    }
    float4* ap = (float4*)acc + (size_t)node * 32 + l;
    float4 c = *ap;
    c.x += m.x; c.y += m.y; c.z += m.z; c.w += m.w;
    *ap = c;
}

// ===================== LayerNorm (+ReLU / +ReLU+res / +GELU) ===============
template <int D, int MODE>
__global__ __launch_bounds__(256) void ln_kernel(const float* __restrict__ in,
                                                 const float* __restrict__ g,
                                                 const float* __restrict__ b,
                                                 const float* __restrict__ resid,
                                                 float* __restrict__ out, int M) {
    int row = blockIdx.x * 4 + (threadIdx.x >> 6);
    int lane = threadIdx.x & 63;
    if (row >= M) return;
    constexpr int EPL = D / 64;
    float v[EPL];
    const float* ip = in + (size_t)row * D;
#pragma unroll
    for (int j = 0; j < EPL; ++j) v[j] = ip[lane * EPL + j];
    float s = 0.f, sq = 0.f;
#pragma unroll
    for (int j = 0; j < EPL; ++j) { s += v[j]; sq += v[j] * v[j]; }
#pragma unroll
    for (int off = 32; off; off >>= 1) {
        s += __shfl_xor(s, off, 64);
        sq += __shfl_xor(sq, off, 64);
    }
    float mu = s * (1.f / D);
    float var = sq * (1.f / D) - mu * mu;
    float rs = rsqrtf(var + 1e-5f);
#pragma unroll
    for (int j = 0; j < EPL; ++j) {
        int c = lane * EPL + j;
        float y = (v[j] - mu) * rs * g[c] + b[c];
        if (MODE == 0) {
            y = fmaxf(y, 0.f);
        } else if (MODE == 1) {
            y = fmaxf(y, 0.f) + 0.2f * resid[(size_t)row * D + c];
        } else {
            y = 0.5f * y * (1.f + erff(y * 0.70710678118654752f));
        }
        out[(size_t)row * D + c] = y;
    }
}

// =================== f32 GEMM  M x 64 @ 64 x 40  (classifier out) ==========
__global__ __launch_bounds__(256) void gemm_40(const float* __restrict__ X,
                                               const float* __restrict__ W,
                                               const float* __restrict__ bias,
                                               float* __restrict__ Y, int M) {
    __shared__ float Xs[64][65];
    __shared__ float Ws[64 * 40];
    const int tid = threadIdx.x;
    const int row0 = blockIdx.x * 64;
    for (int i = tid; i < 64 * 40; i += 256) Ws[i] = W[i];
#pragma unroll
    for (int i = 0; i < 4; ++i) {
        int slot = tid + i * 256;
        int r = slot >> 4, c4 = slot & 15;
        float4 v = make_float4(0.f, 0.f, 0.f, 0.f);
        if (row0 + r < M) v = *(const float4*)(X + (size_t)(row0 + r) * 64 + c4 * 4);
        Xs[r][c4 * 4 + 0] = v.x; Xs[r][c4 * 4 + 1] = v.y;
        Xs[r][c4 * 4 + 2] = v.z; Xs[r][c4 * 4 + 3] = v.w;
    }
    __syncthreads();
    const int row = tid >> 2, cg = (tid & 3) * 10;
    float acc[10];
#pragma unroll
    for (int j = 0; j < 10; ++j) acc[j] = 0.f;
#pragma unroll 8
    for (int k = 0; k < 64; ++k) {
        float xv = Xs[row][k];
#pragma unroll
        for (int j = 0; j < 10; ++j) acc[j] = fmaf(xv, Ws[k * 40 + cg + j], acc[j]);
    }
    int grow = row0 + row;
    if (grow < M) {
#pragma unroll
        for (int j = 0; j < 10; ++j)
            Y[(size_t)grow * 40 + cg + j] = acc[j] + bias[cg + j];
    }
}

// ============================ log_softmax (rows of 40) =====================
__global__ __launch_bounds__(256) void lsm_kernel(const float* __restrict__ in,
                                                  float* __restrict__ out, int M) {
    int row = blockIdx.x * 4 + (threadIdx.x >> 6);
    int lane = threadIdx.x & 63;
    if (row >= M) return;
    float v = (lane < 40) ? in[(size_t)row * 40 + lane] : -INFINITY;
    float mx = v;
#pragma unroll
    for (int off = 32; off; off >>= 1) mx = fmaxf(mx, __shfl_xor(mx, off, 64));
    float e = (lane < 40) ? __expf(v - mx) : 0.f;
    float sum = e;
#pragma unroll
    for (int off = 32; off; off >>= 1) sum += __shfl_xor(sum, off, 64);
    float ls = logf(sum);
    if (lane < 40) out[(size_t)row * 40 + lane] = v - mx - ls;
}

// ===========================================================================
extern "C" void kernel_launch(void* const* d_in, const int* in_sizes, int n_in,
                              void* d_out, int out_size, void* d_ws, size_t ws_size,
                              hipStream_t stream) {
    const float* x       = (const float*)d_in[0];
    const int*   eidx    = (const int*)d_in[1];
    const int*   etype   = (const int*)d_in[2];
    const float* w1_rel  = (const float*)d_in[3];
    const float* w1_root = (const float*)d_in[4];
    const float* b1      = (const float*)d_in[5];
    const float* ln1_g   = (const float*)d_in[6];
    const float* ln1_b   = (const float*)d_in[7];
    const float* w2_rel  = (const float*)d_in[8];
    const float* w2_root = (const float*)d_in[9];
    const float* b2      = (const float*)d_in[10];
    const float* ln2_g   = (const float*)d_in[11];
    const float* ln2_b   = (const float*)d_in[12];
    const float* cw1     = (const float*)d_in[13];
    const float* cb1     = (const float*)d_in[14];
    const float* cln1_g  = (const float*)d_in[15];
    const float* cln1_b  = (const float*)d_in[16];
    const float* cw2     = (const float*)d_in[17];
    const float* cb2     = (const float*)d_in[18];
    const float* cln2_g  = (const float*)d_in[19];
    const float* cln2_b  = (const float*)d_in[20];
    const float* cw3     = (const float*)d_in[21];
    const float* cb3     = (const float*)d_in[22];

    const int N = in_sizes[0] / 128;   // 50000
    const int E = in_sizes[1] / 2;     // 600000
    const int* esrc = eidx;
    const int* edst = eidx + E;

    const size_t NF = (size_t)N * 128;
    float* B0 = (float*)d_ws;
    float* B1 = B0 + NF;
    float* B2 = B1 + NF;
    float* B3 = B2 + NF;   // CSR + converted weights

    // ---- B3 layout ----
    int* rowptr  = (int*)B3;                      // N+1
    int* degtot  = rowptr + (N + 1);              // N
    int* deg3    = degtot + N;                    // 3N
    int* cursor3 = deg3 + 3 * N;                  // 3N
    int* bsums   = cursor3 + 3 * N;               // 256
    int* btop    = bsums + 256;                   // 256
    int4* ranges = (int4*)(((uintptr_t)(btop + 256) + 15) & ~(uintptr_t)15);
    int* colidx  = (int*)(ranges + N);            // E
    // 10 weight slots (hi plane array, lo plane array), slot stride 16384
    ushort_t* wtHi = (ushort_t*)(((uintptr_t)(colidx + E) + 15) & ~(uintptr_t)15);
    ushort_t* wtLo = wtHi + 10 * 16384;
    // slots: 0=w1_root 1..3=w1_rel[r] 4=w2_root 5..7=w2_rel[r] 8=cw1 9=cw2

    const dim3 blk(256);
    const int gGemm = (N + 63) / 64;
    const int gAgg  = (N + 7) / 8;
    const int gRow  = (N + 3) / 4;
    const int gEdge = (E + 255) / 256;
    const int gNode = (N + 255) / 256;
    const int nScanB = (N + 255) / 256;

    // ---------------- CSR build ----------------
    hipMemsetAsync(deg3, 0, (size_t)3 * N * sizeof(int), stream);
    hist3_kernel<<<gEdge, blk, 0, stream>>>(edst, etype, deg3, E);
    degtot_kernel<<<gNode, blk, 0, stream>>>(deg3, degtot, N);
    scan_block<<<nScanB, blk, 0, stream>>>(degtot, rowptr, bsums, N);
    scan_block<<<1, blk, 0, stream>>>(bsums, btop, nullptr, nScanB);
    scan_add<<<nScanB, blk, 0, stream>>>(rowptr, btop, N, E);
    ranges_kernel<<<gNode, blk, 0, stream>>>(rowptr, deg3, ranges, cursor3, N);
    fill3_kernel<<<gEdge, blk, 0, stream>>>(esrc, edst, etype, cursor3, colidx, E);

    // ---------------- convert all weights ----------------
    convert_w<<<64, blk, 0, stream>>>(w1_root, wtHi, wtLo, 7);
    for (int r = 0; r < 3; ++r)
        convert_w<<<64, blk, 0, stream>>>(w1_rel + (size_t)r * 16384,
                                          wtHi + (1 + r) * 16384,
                                          wtLo + (1 + r) * 16384, 7);
    convert_w<<<64, blk, 0, stream>>>(w2_root, wtHi + 4 * 16384, wtLo + 4 * 16384, 7);
    for (int r = 0; r < 3; ++r)
        convert_w<<<64, blk, 0, stream>>>(w2_rel + (size_t)r * 16384,
                                          wtHi + (5 + r) * 16384,
                                          wtLo + (5 + r) * 16384, 7);
    convert_w<<<64, blk, 0, stream>>>(cw1, wtHi + 8 * 16384, wtLo + 8 * 16384, 7);
    convert_w<<<32, blk, 0, stream>>>(cw2, wtHi + 9 * 16384, wtLo + 9 * 16384, 6);

    // ---------------- conv1 (add): aggregate-then-transform ----------------
    // S0->B0 S1->B1 S2->B2, then K=512 fused gemm -> acc in B0 (in-place safe)
    agg3_add<<<gAgg, blk, 0, stream>>>(x, ranges, colidx, B0, B1, B2, N);
    gemm_mfma<128, 4><<<gGemm, blk, 0, stream>>>(x, B0, B1, B2, wtHi, wtLo,
                                                 b1, B0, N);
    // x1 = relu(LN(acc)) -> B1
    ln_kernel<128, 0><<<gRow, blk, 0, stream>>>(B0, ln1_g, ln1_b, nullptr, B1, N);

    // ---------------- conv2 (max): transform-then-gather -------------------
    gemm_mfma<128, 1><<<gGemm, blk, 0, stream>>>(B1, B1, B1, B1,
                                                 wtHi + 4 * 16384,
                                                 wtLo + 4 * 16384, b2, B0, N);
    for (int r = 0; r < 3; ++r) {
        gemm_mfma<128, 1><<<gGemm, blk, 0, stream>>>(B1, B1, B1, B1,
                                                     wtHi + (5 + r) * 16384,
                                                     wtLo + (5 + r) * 16384,
                                                     nullptr, B2, N);
        maxagg<<<gAgg, blk, 0, stream>>>(B2, ranges, colidx, r, B0, N);
    }
    // h2 = relu(LN(acc)) + 0.2*x1 -> B2
    ln_kernel<128, 1><<<gRow, blk, 0, stream>>>(B0, ln2_g, ln2_b, B1, B2, N);

    // ---------------- classifier ----------------
    gemm_mfma<128, 1><<<gGemm, blk, 0, stream>>>(B2, B2, B2, B2,
                                                 wtHi + 8 * 16384,
                                                 wtLo + 8 * 16384, cb1, B0, N);
    ln_kernel<128, 2><<<gRow, blk, 0, stream>>>(B0, cln1_g, cln1_b, nullptr, B1, N);
    gemm_mfma<64, 1><<<gGemm, blk, 0, stream>>>(B1, B1, B1, B1,
                                                wtHi + 9 * 16384,
                                                wtLo + 9 * 16384, cb2, B2, N);
    ln_kernel<64, 2><<<gRow, blk, 0, stream>>>(B2, cln2_g, cln2_b, nullptr, B0, N);
    gemm_40<<<gGemm, blk, 0, stream>>>(B0, cw3, cb3, B1, N);
    lsm_kernel<<<gRow, blk, 0, stream>>>(B1, (float*)d_out, N);
}

// Round 5
// 415.756 us; speedup vs baseline: 5.5133x; 1.1359x over previous
//
#include <hip/hip_runtime.h>
#include <hip/hip_bf16.h>
#include <math.h>

// ---------------------------------------------------------------------------
// RGCN forward. Activations carried as bf16 hi/lo "plane rows":
//   row r = [hi[128] ushort][lo[128] ushort] = 512B (same footprint as f32).
// GEMMs: split-bf16 triple MFMA, swapped operands (a=W,b=X) so the epilogue
// is float4 row-major stores. W pre-converted to MFMA-fragment order in
// global (register-direct loads). X staged via double-buffered LDS.
// conv1 (add): aggregate-then-transform, one fused K=512 GEMM.
// conv2 (max): transform-then-gather with f32 H + RMW max.
// ---------------------------------------------------------------------------

typedef __attribute__((ext_vector_type(8))) short bf16x8;
typedef __attribute__((ext_vector_type(4))) float f32x4;
typedef unsigned short ushort_t;

__device__ __forceinline__ void split_bf16(float v, ushort_t& h, ushort_t& l) {
    unsigned uv = __float_as_uint(v);
    unsigned rh = uv + 0x7FFFu + ((uv >> 16) & 1u);   // RNE to bf16
    ushort_t hu = (ushort_t)(rh >> 16);
    float hf = __uint_as_float((unsigned)hu << 16);
    float lo = v - hf;                                // exact
    unsigned ul = __float_as_uint(lo);
    unsigned rl = ul + 0x7FFFu + ((ul >> 16) & 1u);
    h = hu;
    l = (ushort_t)(rl >> 16);
}

__device__ __forceinline__ void split4(float4 v, uint2& h, uint2& l) {
    ushort_t h0, h1, h2, h3, l0, l1, l2, l3;
    split_bf16(v.x, h0, l0); split_bf16(v.y, h1, l1);
    split_bf16(v.z, h2, l2); split_bf16(v.w, h3, l3);
    h.x = (unsigned)h0 | ((unsigned)h1 << 16);
    h.y = (unsigned)h2 | ((unsigned)h3 << 16);
    l.x = (unsigned)l0 | ((unsigned)l1 << 16);
    l.y = (unsigned)l2 | ((unsigned)l3 << 16);
}

__device__ __forceinline__ float bf2f(ushort_t u) {
    return __uint_as_float((unsigned)u << 16);
}

// ============ W[128][NCOL] f32 -> fragment-ordered bf16 hi/lo ==============
// layout (ushort): [plane][ks 0..3][cf 0..NCF-1][lane 0..63][8]
template <int NCOL>
__global__ __launch_bounds__(256) void convert_wfrag(const float* __restrict__ W,
                                                     ushort_t* __restrict__ out) {
    constexpr int NCF = NCOL / 16;
    constexpr int CSH = (NCF == 8) ? 3 : 2;
    constexpr size_t PST = (size_t)4 * NCF * 512;   // plane stride (ushorts)
    int idx = blockIdx.x * 256 + threadIdx.x;
    if (idx >= 4 * NCF * 64) return;
    int l = idx & 63;
    int cf = (idx >> 6) & (NCF - 1);
    int ks = idx >> (6 + CSH);
    int col = cf * 16 + (l & 15);
    int k0 = ks * 32 + (l >> 4) * 8;
    size_t base = (((size_t)ks * NCF + cf) * 64 + l) * 8;
#pragma unroll
    for (int j = 0; j < 8; ++j) {
        ushort_t h, lo_;
        split_bf16(W[(size_t)(k0 + j) * NCOL + col], h, lo_);
        out[base + j] = h;
        out[PST + base + j] = lo_;
    }
}

// ================= GEMM  Y[M,NCOL] = sum_s A_s[M,128] @ W_s + bias =========
// 256 thr / 4 waves (2 rowgrp x 2 colgrp), 64 rows/block.
// A_s: plane rows (or f32 rows for seg 0 if SPLIT0). wfrag: [NSEG] matrices.
template <int NCOL, int NSEG, bool SPLIT0>
__global__ __launch_bounds__(256, 3) void gemm_planes(
    const char* __restrict__ A0, const char* __restrict__ A1,
    const char* __restrict__ A2, const char* __restrict__ A3,
    const ushort_t* __restrict__ wfrag, const float* __restrict__ bias,
    float* __restrict__ Y, int M) {
    constexpr int NCF = NCOL / 16;
    constexpr int WF = NCOL / 32;               // n-frags per wave
    constexpr int PST = 4 * NCF * 512;          // plane stride in wfrag
    constexpr int WSEG = 2 * PST;               // per-segment stride
    __shared__ __align__(16) char lds[2][16384];   // [buf][2 planes x 64r x 128B]
    const int tid = threadIdx.x;
    const int wv = tid >> 6, lane = tid & 63, l15 = lane & 15, lg = lane >> 4;
    const int rowgrp = wv >> 1, colgrp = wv & 1;
    const int row0 = blockIdx.x * 64;
    const char* As[4] = {A0, A1, A2, A3};

    f32x4 acc[2][WF];
#pragma unroll
    for (int xf = 0; xf < 2; ++xf)
#pragma unroll
        for (int wf = 0; wf < WF; ++wf) acc[xf][wf] = (f32x4){0.f, 0.f, 0.f, 0.f};

    uint4 regs[4];

    auto LOADSTAGE = [&](int ch) {
        int seg = ch >> 1, kc = (ch & 1) * 64;
        const char* __restrict__ A = As[seg];
        if (SPLIT0 && seg == 0) {
#pragma unroll
            for (int i = 0; i < 4; ++i) {
                int s = tid + i * 256;             // 1024: 64r x 16 c4
                int r = s >> 4, c4 = s & 15;
                int gr = row0 + r;
                float4 v = make_float4(0.f, 0.f, 0.f, 0.f);
                if (gr < M) v = *(const float4*)(A + (size_t)gr * 512 + kc * 4 + c4 * 16);
                regs[i] = *(uint4*)&v;
            }
        } else {
#pragma unroll
            for (int i = 0; i < 4; ++i) {
                int s = tid + i * 256;             // 1024: 2p x 64r x 8 c16
                int p = s >> 9, r = (s >> 3) & 63, c16 = s & 7;
                int gr = row0 + r;
                uint4 v = make_uint4(0u, 0u, 0u, 0u);
                if (gr < M)
                    v = *(const uint4*)(A + (size_t)gr * 512 + p * 256 + kc * 2 + c16 * 16);
                regs[i] = v;
            }
        }
    };

    auto WRITESTAGE = [&](int ch, int buf) {
        char* L = lds[buf];
        if (SPLIT0 && (ch >> 1) == 0) {
#pragma unroll
            for (int i = 0; i < 4; ++i) {
                int s = tid + i * 256;
                int r = s >> 4, c4 = s & 15;
                uint2 hh, ll;
                float4 v = *(float4*)&regs[i];
                split4(v, hh, ll);
                int byte = (r * 128 + c4 * 8) ^ ((r & 7) << 4);
                *(uint2*)(L + byte) = hh;
                *(uint2*)(L + 8192 + byte) = ll;
            }
        } else {
#pragma unroll
            for (int i = 0; i < 4; ++i) {
                int s = tid + i * 256;
                int p = s >> 9, r = (s >> 3) & 63, c16 = s & 7;
                int byte = p * 8192 + ((r * 128 + c16 * 16) ^ ((r & 7) << 4));
                *(uint4*)(L + byte) = regs[i];
            }
        }
    };

    auto COMPUTE = [&](int ch, int buf) {
        int seg = ch >> 1, half = ch & 1;
        const ushort_t* __restrict__ ws = wfrag + (size_t)seg * WSEG;
        const char* L = lds[buf];
#pragma unroll
        for (int kk = 0; kk < 2; ++kk) {
            int ks = half * 2 + kk;
            bf16x8 xh[2], xl[2];
#pragma unroll
            for (int xf = 0; xf < 2; ++xf) {
                int r = rowgrp * 32 + xf * 16 + l15;
                int byte = (r * 128 + kk * 64 + lg * 16) ^ ((r & 7) << 4);
                xh[xf] = *(const bf16x8*)(L + byte);
                xl[xf] = *(const bf16x8*)(L + 8192 + byte);
            }
            bf16x8 wh[WF], wl[WF];
#pragma unroll
            for (int wf = 0; wf < WF; ++wf) {
                size_t off = (((size_t)ks * NCF + colgrp * WF + wf) * 64 + lane) * 8;
                wh[wf] = *(const bf16x8*)(ws + off);
                wl[wf] = *(const bf16x8*)(ws + PST + off);
            }
#pragma unroll
            for (int xf = 0; xf < 2; ++xf)
#pragma unroll
                for (int wf = 0; wf < WF; ++wf) {
                    acc[xf][wf] = __builtin_amdgcn_mfma_f32_16x16x32_bf16(
                        wh[wf], xh[xf], acc[xf][wf], 0, 0, 0);
                    acc[xf][wf] = __builtin_amdgcn_mfma_f32_16x16x32_bf16(
                        wl[wf], xh[xf], acc[xf][wf], 0, 0, 0);
                    acc[xf][wf] = __builtin_amdgcn_mfma_f32_16x16x32_bf16(
                        wh[wf], xl[xf], acc[xf][wf], 0, 0, 0);
                }
        }
    };

    constexpr int CH = 2 * NSEG;
    LOADSTAGE(0);
    WRITESTAGE(0, 0);
    __syncthreads();
    for (int ch = 0; ch < CH; ++ch) {
        if (ch + 1 < CH) LOADSTAGE(ch + 1);
        COMPUTE(ch, ch & 1);
        __syncthreads();
        if (ch + 1 < CH) WRITESTAGE(ch + 1, (ch + 1) & 1);
        __syncthreads();
    }

    // epilogue: lane holds Y[row = l15-based][4 consecutive cols at 4*lg+i]
#pragma unroll
    for (int xf = 0; xf < 2; ++xf) {
        int row = row0 + rowgrp * 32 + xf * 16 + l15;
        if (row < M) {
#pragma unroll
            for (int wf = 0; wf < WF; ++wf) {
                int col = colgrp * (NCOL / 2) + wf * 16 + lg * 4;
                float4 bv = make_float4(0.f, 0.f, 0.f, 0.f);
                if (bias) bv = *(const float4*)(bias + col);
                float4 o;
                o.x = acc[xf][wf][0] + bv.x;
                o.y = acc[xf][wf][1] + bv.y;
                o.z = acc[xf][wf][2] + bv.z;
                o.w = acc[xf][wf][3] + bv.w;
                *(float4*)(Y + (size_t)row * NCOL + col) = o;
            }
        }
    }
}

// ============================== CSR build ((dst,rel)-sorted) ===============
__global__ __launch_bounds__(256) void hist3_kernel(const int* __restrict__ edst,
                                                    const int* __restrict__ etype,
                                                    int* __restrict__ deg3, int E) {
    int e = blockIdx.x * 256 + threadIdx.x;
    if (e < E) atomicAdd(&deg3[edst[e] * 3 + etype[e]], 1);
}

__global__ __launch_bounds__(256) void degtot_kernel(const int* __restrict__ deg3,
                                                     int* __restrict__ degtot, int N) {
    int n = blockIdx.x * 256 + threadIdx.x;
    if (n < N) degtot[n] = deg3[n * 3] + deg3[n * 3 + 1] + deg3[n * 3 + 2];
}

__global__ __launch_bounds__(256) void scan_block(const int* __restrict__ in,
                                                  int* __restrict__ out,
                                                  int* __restrict__ sums, int n) {
    __shared__ int s[256];
    int g = blockIdx.x * 256 + threadIdx.x;
    int v = (g < n) ? in[g] : 0;
    s[threadIdx.x] = v;
    __syncthreads();
    int acc = v;
    for (int off = 1; off < 256; off <<= 1) {
        int t = (threadIdx.x >= off) ? s[threadIdx.x - off] : 0;
        __syncthreads();
        acc += t;
        s[threadIdx.x] = acc;
        __syncthreads();
    }
    if (g < n) out[g] = acc - v;
    if (threadIdx.x == 255 && sums) sums[blockIdx.x] = acc;
}

__global__ __launch_bounds__(256) void scan_add(int* __restrict__ out,
                                                const int* __restrict__ topex,
                                                int n, int total) {
    int g = blockIdx.x * 256 + threadIdx.x;
    if (g < n) out[g] += topex[blockIdx.x];
    if (g == 0) out[n] = total;
}

__global__ __launch_bounds__(256) void ranges_kernel(
    const int* __restrict__ rowptr, const int* __restrict__ deg3,
    int4* __restrict__ ranges, int* __restrict__ cursor3, int N) {
    int n = blockIdx.x * 256 + threadIdx.x;
    if (n >= N) return;
    int b = rowptr[n];
    int d0 = deg3[n * 3], d1 = deg3[n * 3 + 1];
    int4 r;
    r.x = b; r.y = b + d0; r.z = b + d0 + d1; r.w = rowptr[n + 1];
    ranges[n] = r;
    cursor3[n * 3] = r.x; cursor3[n * 3 + 1] = r.y; cursor3[n * 3 + 2] = r.z;
}

__global__ __launch_bounds__(256) void fill3_kernel(
    const int* __restrict__ esrc, const int* __restrict__ edst,
    const int* __restrict__ etype, int* __restrict__ cursor3,
    int* __restrict__ colidx, int E) {
    int e = blockIdx.x * 256 + threadIdx.x;
    if (e >= E) return;
    int pos = atomicAdd(&cursor3[edst[e] * 3 + etype[e]], 1);
    colidx[pos] = esrc[e];
}

// ===================== fused add-gather: S_r = A_r x -> planes =============
__device__ __forceinline__ float4 gather_sum(const float4* __restrict__ X4,
                                             const int* __restrict__ colidx,
                                             int beg, int end, int l) {
    float4 a = make_float4(0.f, 0.f, 0.f, 0.f);
    int e = beg;
    for (; e + 4 <= end; e += 4) {
        int s0 = colidx[e], s1 = colidx[e + 1];
        int s2 = colidx[e + 2], s3 = colidx[e + 3];
        float4 v0 = X4[(size_t)s0 * 32 + l];
        float4 v1 = X4[(size_t)s1 * 32 + l];
        float4 v2 = X4[(size_t)s2 * 32 + l];
        float4 v3 = X4[(size_t)s3 * 32 + l];
        a.x += (v0.x + v1.x) + (v2.x + v3.x);
        a.y += (v0.y + v1.y) + (v2.y + v3.y);
        a.z += (v0.z + v1.z) + (v2.z + v3.z);
        a.w += (v0.w + v1.w) + (v2.w + v3.w);
    }
    for (; e < end; ++e) {
        float4 v = X4[(size_t)colidx[e] * 32 + l];
        a.x += v.x; a.y += v.y; a.z += v.z; a.w += v.w;
    }
    return a;
}

__device__ __forceinline__ void store_plane4(char* rowbase, int l, float4 a) {
    uint2 h, lo;
    split4(a, h, lo);
    *(uint2*)(rowbase + 8 * l) = h;
    *(uint2*)(rowbase + 256 + 8 * l) = lo;
}

__global__ __launch_bounds__(256) void agg3_add(
    const float* __restrict__ x, const int4* __restrict__ ranges,
    const int* __restrict__ colidx, char* __restrict__ S0,
    char* __restrict__ S1, char* __restrict__ S2, int N) {
    int node = blockIdx.x * 8 + (threadIdx.x >> 5);
    int l = threadIdx.x & 31;
    if (node >= N) return;
    int4 rg = ranges[node];
    const float4* X4 = (const float4*)x;
    float4 a0 = gather_sum(X4, colidx, rg.x, rg.y, l);
    float4 a1 = gather_sum(X4, colidx, rg.y, rg.z, l);
    float4 a2 = gather_sum(X4, colidx, rg.z, rg.w, l);
    store_plane4(S0 + (size_t)node * 512, l, a0);
    store_plane4(S1 + (size_t)node * 512, l, a1);
    store_plane4(S2 + (size_t)node * 512, l, a2);
}

// ===================== max-gather RMW: acc += max_r(H[src])  ===============
__global__ __launch_bounds__(256) void maxagg(
    const float* __restrict__ H, const int4* __restrict__ ranges,
    const int* __restrict__ colidx, int rel, float* __restrict__ acc, int N) {
    int node = blockIdx.x * 8 + (threadIdx.x >> 5);
    int l = threadIdx.x & 31;
    if (node >= N) return;
    int4 rg = ranges[node];
    int beg = (rel == 0) ? rg.x : ((rel == 1) ? rg.y : rg.z);
    int end = (rel == 0) ? rg.y : ((rel == 1) ? rg.z : rg.w);
    if (beg >= end) return;
    const float4* H4 = (const float4*)H;
    float4 m = make_float4(-INFINITY, -INFINITY, -INFINITY, -INFINITY);
    int e = beg;
    for (; e + 4 <= end; e += 4) {
        int s0 = colidx[e], s1 = colidx[e + 1];
        int s2 = colidx[e + 2], s3 = colidx[e + 3];
        float4 v0 = H4[(size_t)s0 * 32 + l];
        float4 v1 = H4[(size_t)s1 * 32 + l];
        float4 v2 = H4[(size_t)s2 * 32 + l];
        float4 v3 = H4[(size_t)s3 * 32 + l];
        m.x = fmaxf(m.x, fmaxf(fmaxf(v0.x, v1.x), fmaxf(v2.x, v3.x)));
        m.y = fmaxf(m.y, fmaxf(fmaxf(v0.y, v1.y), fmaxf(v2.y, v3.y)));
        m.z = fmaxf(m.z, fmaxf(fmaxf(v0.z, v1.z), fmaxf(v2.z, v3.z)));
        m.w = fmaxf(m.w, fmaxf(fmaxf(v0.w, v1.w), fmaxf(v2.w, v3.w)));
    }
    for (; e < end; ++e) {
        float4 v = H4[(size_t)colidx[e] * 32 + l];
        m.x = fmaxf(m.x, v.x); m.y = fmaxf(m.y, v.y);
        m.z = fmaxf(m.z, v.z); m.w = fmaxf(m.w, v.w);
    }
    float4* ap = (float4*)acc + (size_t)node * 32 + l;
    float4 c = *ap;
    c.x += m.x; c.y += m.y; c.z += m.z; c.w += m.w;
    *ap = c;
}

// ===================== LayerNorm =====================
// MODE: 0=relu, 1=relu+0.2*resid(planes), 2=exact gelu
// OUT:  0=f32 rows, 1=plane rows (D must be 128)
template <int D, int MODE, int OUT>
__global__ __launch_bounds__(256) void ln_kernel(const float* __restrict__ in,
                                                 const float* __restrict__ g,
                                                 const float* __restrict__ b,
                                                 const char* __restrict__ residP,
                                                 void* __restrict__ outv, int M) {
    int row = blockIdx.x * 4 + (threadIdx.x >> 6);
    int lane = threadIdx.x & 63;
    if (row >= M) return;
    constexpr int EPL = D / 64;
    float v[EPL];
    const float* ip = in + (size_t)row * D;
#pragma unroll
    for (int j = 0; j < EPL; ++j) v[j] = ip[lane * EPL + j];
    float s = 0.f, sq = 0.f;
#pragma unroll
    for (int j = 0; j < EPL; ++j) { s += v[j]; sq += v[j] * v[j]; }
#pragma unroll
    for (int off = 32; off; off >>= 1) {
        s += __shfl_xor(s, off, 64);
        sq += __shfl_xor(sq, off, 64);
    }
    float mu = s * (1.f / D);
    float var = sq * (1.f / D) - mu * mu;
    float rs = rsqrtf(var + 1e-5f);
    float y[EPL];
#pragma unroll
    for (int j = 0; j < EPL; ++j) {
        int c = lane * EPL + j;
        float t = (v[j] - mu) * rs * g[c] + b[c];
        if (MODE == 0) {
            t = fmaxf(t, 0.f);
        } else if (MODE == 1) {
            const char* rb = residP + (size_t)row * 512;
            float rf = bf2f(*(const ushort_t*)(rb + 2 * c)) +
                       bf2f(*(const ushort_t*)(rb + 256 + 2 * c));
            t = fmaxf(t, 0.f) + 0.2f * rf;
        } else {
            t = 0.5f * t * (1.f + erff(t * 0.70710678118654752f));
        }
        y[j] = t;
    }
    if (OUT == 0) {
        float* out = (float*)outv;
#pragma unroll
        for (int j = 0; j < EPL; ++j) out[(size_t)row * D + lane * EPL + j] = y[j];
    } else {
        // D==128, EPL==2: pack two bf16 per plane word
        char* ob = (char*)outv + (size_t)row * 512;
        ushort_t h0, l0, h1, l1;
        split_bf16(y[0], h0, l0);
        split_bf16(y[1], h1, l1);
        *(unsigned*)(ob + 4 * lane) = (unsigned)h0 | ((unsigned)h1 << 16);
        *(unsigned*)(ob + 256 + 4 * lane) = (unsigned)l0 | ((unsigned)l1 << 16);
    }
}

// =================== f32 GEMM  M x 64 @ 64 x 40  (classifier out) ==========
__global__ __launch_bounds__(256) void gemm_40(const float* __restrict__ X,
                                               const float* __restrict__ W,
                                               const float* __restrict__ bias,
                                               float* __restrict__ Y, int M) {
    __shared__ float Xs[64][65];
    __shared__ float Ws[64 * 40];
    const int tid = threadIdx.x;
    const int row0 = blockIdx.x * 64;
    for (int i = tid; i < 64 * 40; i += 256) Ws[i] = W[i];
#pragma unroll
    for (int i = 0; i < 4; ++i) {
        int slot = tid + i * 256;
        int r = slot >> 4, c4 = slot & 15;
        float4 v = make_float4(0.f, 0.f, 0.f, 0.f);
        if (row0 + r < M) v = *(const float4*)(X + (size_t)(row0 + r) * 64 + c4 * 4);
        Xs[r][c4 * 4 + 0] = v.x; Xs[r][c4 * 4 + 1] = v.y;
        Xs[r][c4 * 4 + 2] = v.z; Xs[r][c4 * 4 + 3] = v.w;
    }
    __syncthreads();
    const int row = tid >> 2, cg = (tid & 3) * 10;
    float acc[10];
#pragma unroll
    for (int j = 0; j < 10; ++j) acc[j] = 0.f;
#pragma unroll 8
    for (int k = 0; k < 64; ++k) {
        float xv = Xs[row][k];
#pragma unroll
        for (int j = 0; j < 10; ++j) acc[j] = fmaf(xv, Ws[k * 40 + cg + j], acc[j]);
    }
    int grow = row0 + row;
    if (grow < M) {
#pragma unroll
        for (int j = 0; j < 10; ++j)
            Y[(size_t)grow * 40 + cg + j] = acc[j] + bias[cg + j];
    }
}

// ============================ log_softmax (rows of 40) =====================
__global__ __launch_bounds__(256) void lsm_kernel(const float* __restrict__ in,
                                                  float* __restrict__ out, int M) {
    int row = blockIdx.x * 4 + (threadIdx.x >> 6);
    int lane = threadIdx.x & 63;
    if (row >= M) return;
    float v = (lane < 40) ? in[(size_t)row * 40 + lane] : -INFINITY;
    float mx = v;
#pragma unroll
    for (int off = 32; off; off >>= 1) mx = fmaxf(mx, __shfl_xor(mx, off, 64));
    float e = (lane < 40) ? __expf(v - mx) : 0.f;
    float sum = e;
#pragma unroll
    for (int off = 32; off; off >>= 1) sum += __shfl_xor(sum, off, 64);
    float ls = logf(sum);
    if (lane < 40) out[(size_t)row * 40 + lane] = v - mx - ls;
}

// ===========================================================================
extern "C" void kernel_launch(void* const* d_in, const int* in_sizes, int n_in,
                              void* d_out, int out_size, void* d_ws, size_t ws_size,
                              hipStream_t stream) {
    const float* x       = (const float*)d_in[0];
    const int*   eidx    = (const int*)d_in[1];
    const int*   etype   = (const int*)d_in[2];
    const float* w1_rel  = (const float*)d_in[3];
    const float* w1_root = (const float*)d_in[4];
    const float* b1      = (const float*)d_in[5];
    const float* ln1_g   = (const float*)d_in[6];
    const float* ln1_b   = (const float*)d_in[7];
    const float* w2_rel  = (const float*)d_in[8];
    const float* w2_root = (const float*)d_in[9];
    const float* b2      = (const float*)d_in[10];
    const float* ln2_g   = (const float*)d_in[11];
    const float* ln2_b   = (const float*)d_in[12];
    const float* cw1     = (const float*)d_in[13];
    const float* cb1     = (const float*)d_in[14];
    const float* cln1_g  = (const float*)d_in[15];
    const float* cln1_b  = (const float*)d_in[16];
    const float* cw2     = (const float*)d_in[17];
    const float* cb2     = (const float*)d_in[18];
    const float* cln2_g  = (const float*)d_in[19];
    const float* cln2_b  = (const float*)d_in[20];
    const float* cw3     = (const float*)d_in[21];
    const float* cb3     = (const float*)d_in[22];

    const int N = in_sizes[0] / 128;   // 50000
    const int E = in_sizes[1] / 2;     // 600000
    const int* esrc = eidx;
    const int* edst = eidx + E;

    const size_t NFB = (size_t)N * 512;     // one [N,128]-f32-equivalent, bytes
    char* B0 = (char*)d_ws;
    char* B1 = B0 + NFB;
    char* B2 = B1 + NFB;
    char* B3 = B2 + NFB;   // META: CSR + wfrag

    int* rowptr  = (int*)B3;                      // N+1
    int* degtot  = rowptr + (N + 1);              // N
    int* deg3    = degtot + N;                    // 3N
    int* cursor3 = deg3 + 3 * N;                  // 3N
    int* bsums   = cursor3 + 3 * N;               // 256
    int* btop    = bsums + 256;                   // 256
    int4* ranges = (int4*)(((uintptr_t)(btop + 256) + 15) & ~(uintptr_t)15);
    int* colidx  = (int*)(ranges + N);            // E
    ushort_t* wfb = (ushort_t*)(((uintptr_t)(colidx + E) + 255) & ~(uintptr_t)255);
    // 10 slots x 32768 ushorts (64KB): 0-3 conv1 (root, rel0-2), 4 w2_root,
    // 5-7 w2_rel, 8 cw1, 9 cw2(64col)
    auto WSLOT = [&](int i) { return wfb + (size_t)i * 32768; };

    const dim3 blk(256);
    const dim3 blk512(256);
    const int gGemm = (N + 63) / 64;
    const int gAgg  = (N + 7) / 8;
    const int gRow  = (N + 3) / 4;
    const int gEdge = (E + 255) / 256;
    const int gNode = (N + 255) / 256;
    const int nScanB = (N + 255) / 256;

    // ---------------- CSR build ----------------
    hipMemsetAsync(deg3, 0, (size_t)3 * N * sizeof(int), stream);
    hist3_kernel<<<gEdge, blk, 0, stream>>>(edst, etype, deg3, E);
    degtot_kernel<<<gNode, blk, 0, stream>>>(deg3, degtot, N);
    scan_block<<<nScanB, blk, 0, stream>>>(degtot, rowptr, bsums, N);
    scan_block<<<1, blk, 0, stream>>>(bsums, btop, nullptr, nScanB);
    scan_add<<<nScanB, blk, 0, stream>>>(rowptr, btop, N, E);
    ranges_kernel<<<gNode, blk, 0, stream>>>(rowptr, deg3, ranges, cursor3, N);
    fill3_kernel<<<gEdge, blk, 0, stream>>>(esrc, edst, etype, cursor3, colidx, E);

    // ---------------- convert weights to fragment order ----------------
    convert_wfrag<128><<<8, blk, 0, stream>>>(w1_root, WSLOT(0));
    for (int r = 0; r < 3; ++r)
        convert_wfrag<128><<<8, blk, 0, stream>>>(w1_rel + (size_t)r * 16384, WSLOT(1 + r));
    convert_wfrag<128><<<8, blk, 0, stream>>>(w2_root, WSLOT(4));
    for (int r = 0; r < 3; ++r)
        convert_wfrag<128><<<8, blk, 0, stream>>>(w2_rel + (size_t)r * 16384, WSLOT(5 + r));
    convert_wfrag<128><<<8, blk, 0, stream>>>(cw1, WSLOT(8));
    convert_wfrag<64><<<4, blk, 0, stream>>>(cw2, WSLOT(9));

    // ---------------- conv1 (add): aggregate-then-transform ----------------
    // S planes -> B0,B1,B2; fused K=512 gemm (x f32 + 3 plane segs) -> f32 B0
    agg3_add<<<gAgg, blk, 0, stream>>>(x, ranges, colidx, B0, B1, B2, N);
    gemm_planes<128, 4, true><<<gGemm, blk512, 0, stream>>>(
        (const char*)x, B0, B1, B2, WSLOT(0), b1, (float*)B0, N);
    // x1 planes -> B1
    ln_kernel<128, 0, 1><<<gRow, blk, 0, stream>>>((float*)B0, ln1_g, ln1_b,
                                                   nullptr, B1, N);

    // ---------------- conv2 (max) ----------------
    gemm_planes<128, 1, false><<<gGemm, blk512, 0, stream>>>(
        B1, B1, B1, B1, WSLOT(4), b2, (float*)B2, N);           // acc2 f32 -> B2
    for (int r = 0; r < 3; ++r) {
        gemm_planes<128, 1, false><<<gGemm, blk512, 0, stream>>>(
            B1, B1, B1, B1, WSLOT(5 + r), nullptr, (float*)B0, N);  // H f32 -> B0
        maxagg<<<gAgg, blk, 0, stream>>>((float*)B0, ranges, colidx, r,
                                         (float*)B2, N);
    }
    // h2 planes -> B0 (resid = x1 planes in B1)
    ln_kernel<128, 1, 1><<<gRow, blk, 0, stream>>>((float*)B2, ln2_g, ln2_b,
                                                   B1, B0, N);

    // ---------------- classifier ----------------
    gemm_planes<128, 1, false><<<gGemm, blk512, 0, stream>>>(
        B0, B0, B0, B0, WSLOT(8), cb1, (float*)B1, N);          // c1pre f32 -> B1
    ln_kernel<128, 2, 1><<<gRow, blk, 0, stream>>>((float*)B1, cln1_g, cln1_b,
                                                   nullptr, B2, N);  // planes -> B2
    gemm_planes<64, 1, false><<<gGemm, blk512, 0, stream>>>(
        B2, B2, B2, B2, WSLOT(9), cb2, (float*)B0, N);          // f32 [N,64] -> B0
    ln_kernel<64, 2, 0><<<gRow, blk, 0, stream>>>((float*)B0, cln2_g, cln2_b,
                                                  nullptr, B1, N);   // f32 -> B1
    gemm_40<<<gGemm, blk, 0, stream>>>((float*)B1, cw3, cb3, (float*)B2, N);
    lsm_kernel<<<gRow, blk, 0, stream>>>((float*)B2, (float*)d_out, N);
}

// Round 6
// 406.135 us; speedup vs baseline: 5.6439x; 1.0237x over previous
//
#include <hip/hip_runtime.h>
#include <hip/hip_bf16.h>
#include <math.h>

// ---------------------------------------------------------------------------
// RGCN forward. Activations as bf16 hi/lo "plane rows" (512B/row).
// GEMM: split-bf16 triple MFMA, swapped operands; W pre-converted to
// fragment order in global; X via double-buffered LDS; epilogue goes
// through LDS for full-line stores and optional fused LN+activation.
// conv1 (add): aggregate-then-transform (one K=512 GEMM, fused LN1+relu).
// conv2 (max): transform-then-gather, f32 H + RMW max.
// ---------------------------------------------------------------------------

typedef __attribute__((ext_vector_type(8))) short bf16x8;
typedef __attribute__((ext_vector_type(4))) float f32x4;
typedef unsigned short ushort_t;

__device__ __forceinline__ void split_bf16(float v, ushort_t& h, ushort_t& l) {
    unsigned uv = __float_as_uint(v);
    unsigned rh = uv + 0x7FFFu + ((uv >> 16) & 1u);   // RNE to bf16
    ushort_t hu = (ushort_t)(rh >> 16);
    float hf = __uint_as_float((unsigned)hu << 16);
    float lo = v - hf;                                // exact
    unsigned ul = __float_as_uint(lo);
    unsigned rl = ul + 0x7FFFu + ((ul >> 16) & 1u);
    h = hu;
    l = (ushort_t)(rl >> 16);
}

__device__ __forceinline__ void split4(float4 v, uint2& h, uint2& l) {
    ushort_t h0, h1, h2, h3, l0, l1, l2, l3;
    split_bf16(v.x, h0, l0); split_bf16(v.y, h1, l1);
    split_bf16(v.z, h2, l2); split_bf16(v.w, h3, l3);
    h.x = (unsigned)h0 | ((unsigned)h1 << 16);
    h.y = (unsigned)h2 | ((unsigned)h3 << 16);
    l.x = (unsigned)l0 | ((unsigned)l1 << 16);
    l.y = (unsigned)l2 | ((unsigned)l3 << 16);
}

__device__ __forceinline__ float bf2f(ushort_t u) {
    return __uint_as_float((unsigned)u << 16);
}

// ============ W[128][NCOL] f32 -> fragment-ordered bf16 hi/lo ==============
// layout (ushort): [plane][ks 0..3][cf 0..NCF-1][lane 0..63][8]
template <int NCOL>
__global__ __launch_bounds__(256) void convert_wfrag(const float* __restrict__ W,
                                                     ushort_t* __restrict__ out) {
    constexpr int NCF = NCOL / 16;
    constexpr int CSH = (NCF == 8) ? 3 : 2;
    constexpr size_t PST = (size_t)4 * NCF * 512;   // plane stride (ushorts)
    int idx = blockIdx.x * 256 + threadIdx.x;
    if (idx >= 4 * NCF * 64) return;
    int l = idx & 63;
    int cf = (idx >> 6) & (NCF - 1);
    int ks = idx >> (6 + CSH);
    int col = cf * 16 + (l & 15);
    int k0 = ks * 32 + (l >> 4) * 8;
    size_t base = (((size_t)ks * NCF + cf) * 64 + l) * 8;
#pragma unroll
    for (int j = 0; j < 8; ++j) {
        ushort_t h, lo_;
        split_bf16(W[(size_t)(k0 + j) * NCOL + col], h, lo_);
        out[base + j] = h;
        out[PST + base + j] = lo_;
    }
}

// ================= GEMM  Y[M,NCOL] = sum_s A_s[M,128] @ W_s + bias =========
// 256 thr / 4 waves (2 rowgrp x 2 colgrp), 64 rows/block.
// FUSE: 0 = bias only, f32 rows out
//       1 = bias + LN + relu -> plane rows out
//       2 = bias + LN + gelu -> plane rows out
//       3 = bias + LN + gelu -> f32 rows out
template <int NCOL, int NSEG, bool SPLIT0, int FUSE>
__global__ __launch_bounds__(256, 3) void gemm_planes(
    const char* __restrict__ A0, const char* __restrict__ A1,
    const char* __restrict__ A2, const char* __restrict__ A3,
    const ushort_t* __restrict__ wfrag, const float* __restrict__ bias,
    const float* __restrict__ lng, const float* __restrict__ lnb,
    void* __restrict__ Yv, int M) {
    constexpr int NCF = NCOL / 16;
    constexpr int WF = NCOL / 32;               // n-frags per wave
    constexpr int PST = 4 * NCF * 512;          // plane stride in wfrag
    constexpr int WSEG = 2 * PST;               // per-segment stride
    constexpr int RS = NCOL * 4 + 16;           // epilogue LDS row stride
    constexpr int EPB = 64 * RS;
    constexpr int SMEM_BYTES = (EPB > 32768) ? EPB : 32768;
    __shared__ __align__(16) char smem[SMEM_BYTES];
    char (*lds)[16384] = (char(*)[16384])smem;

    const int tid = threadIdx.x;
    const int wv = tid >> 6, lane = tid & 63, l15 = lane & 15, lg = lane >> 4;
    const int rowgrp = wv >> 1, colgrp = wv & 1;
    const int row0 = blockIdx.x * 64;
    const char* As[4] = {A0, A1, A2, A3};

    f32x4 acc[2][WF];
#pragma unroll
    for (int xf = 0; xf < 2; ++xf)
#pragma unroll
        for (int wf = 0; wf < WF; ++wf) acc[xf][wf] = (f32x4){0.f, 0.f, 0.f, 0.f};

    uint4 regs[4];

    auto LOADSTAGE = [&](int ch) {
        int seg = ch >> 1, kc = (ch & 1) * 64;
        const char* __restrict__ A = As[seg];
        if (SPLIT0 && seg == 0) {
#pragma unroll
            for (int i = 0; i < 4; ++i) {
                int s = tid + i * 256;             // 1024: 64r x 16 c4
                int r = s >> 4, c4 = s & 15;
                int gr = row0 + r;
                float4 v = make_float4(0.f, 0.f, 0.f, 0.f);
                if (gr < M) v = *(const float4*)(A + (size_t)gr * 512 + kc * 4 + c4 * 16);
                regs[i] = *(uint4*)&v;
            }
        } else {
#pragma unroll
            for (int i = 0; i < 4; ++i) {
                int s = tid + i * 256;             // 1024: 2p x 64r x 8 c16
                int p = s >> 9, r = (s >> 3) & 63, c16 = s & 7;
                int gr = row0 + r;
                uint4 v = make_uint4(0u, 0u, 0u, 0u);
                if (gr < M)
                    v = *(const uint4*)(A + (size_t)gr * 512 + p * 256 + kc * 2 + c16 * 16);
                regs[i] = v;
            }
        }
    };

    auto WRITESTAGE = [&](int ch, int buf) {
        char* L = lds[buf];
        if (SPLIT0 && (ch >> 1) == 0) {
#pragma unroll
            for (int i = 0; i < 4; ++i) {
                int s = tid + i * 256;
                int r = s >> 4, c4 = s & 15;
                uint2 hh, ll;
                float4 v = *(float4*)&regs[i];
                split4(v, hh, ll);
                int byte = (r * 128 + c4 * 8) ^ ((r & 7) << 4);
                *(uint2*)(L + byte) = hh;
                *(uint2*)(L + 8192 + byte) = ll;
            }
        } else {
#pragma unroll
            for (int i = 0; i < 4; ++i) {
                int s = tid + i * 256;
                int p = s >> 9, r = (s >> 3) & 63, c16 = s & 7;
                int byte = p * 8192 + ((r * 128 + c16 * 16) ^ ((r & 7) << 4));
                *(uint4*)(L + byte) = regs[i];
            }
        }
    };

    auto COMPUTE = [&](int ch, int buf) {
        int seg = ch >> 1, half = ch & 1;
        const ushort_t* __restrict__ ws = wfrag + (size_t)seg * WSEG;
        const char* L = lds[buf];
#pragma unroll
        for (int kk = 0; kk < 2; ++kk) {
            int ks = half * 2 + kk;
            bf16x8 xh[2], xl[2];
#pragma unroll
            for (int xf = 0; xf < 2; ++xf) {
                int r = rowgrp * 32 + xf * 16 + l15;
                int byte = (r * 128 + kk * 64 + lg * 16) ^ ((r & 7) << 4);
                xh[xf] = *(const bf16x8*)(L + byte);
                xl[xf] = *(const bf16x8*)(L + 8192 + byte);
            }
            bf16x8 wh[WF], wl[WF];
#pragma unroll
            for (int wf = 0; wf < WF; ++wf) {
                size_t off = (((size_t)ks * NCF + colgrp * WF + wf) * 64 + lane) * 8;
                wh[wf] = *(const bf16x8*)(ws + off);
                wl[wf] = *(const bf16x8*)(ws + PST + off);
            }
#pragma unroll
            for (int xf = 0; xf < 2; ++xf)
#pragma unroll
                for (int wf = 0; wf < WF; ++wf) {
                    acc[xf][wf] = __builtin_amdgcn_mfma_f32_16x16x32_bf16(
                        wh[wf], xh[xf], acc[xf][wf], 0, 0, 0);
                    acc[xf][wf] = __builtin_amdgcn_mfma_f32_16x16x32_bf16(
                        wl[wf], xh[xf], acc[xf][wf], 0, 0, 0);
                    acc[xf][wf] = __builtin_amdgcn_mfma_f32_16x16x32_bf16(
                        wh[wf], xl[xf], acc[xf][wf], 0, 0, 0);
                }
        }
    };

    constexpr int CH = 2 * NSEG;
    LOADSTAGE(0);
    WRITESTAGE(0, 0);
    __syncthreads();
    for (int ch = 0; ch < CH; ++ch) {
        if (ch + 1 < CH) LOADSTAGE(ch + 1);
        COMPUTE(ch, ch & 1);
        __syncthreads();
        if (ch + 1 < CH) WRITESTAGE(ch + 1, (ch + 1) & 1);
        __syncthreads();
    }
    // after final __syncthreads the staging LDS is dead -> reuse as epilogue

    // ---- stage acc tile (+bias) into LDS as full f32 rows ----
    {
        float4 bv[WF];
#pragma unroll
        for (int wf = 0; wf < WF; ++wf) {
            int col = colgrp * (NCOL / 2) + wf * 16 + lg * 4;
            bv[wf] = bias ? *(const float4*)(bias + col)
                          : make_float4(0.f, 0.f, 0.f, 0.f);
        }
#pragma unroll
        for (int xf = 0; xf < 2; ++xf) {
            int r = rowgrp * 32 + xf * 16 + l15;
#pragma unroll
            for (int wf = 0; wf < WF; ++wf) {
                int col = colgrp * (NCOL / 2) + wf * 16 + lg * 4;
                float4 o;
                o.x = acc[xf][wf][0] + bv[wf].x;
                o.y = acc[xf][wf][1] + bv[wf].y;
                o.z = acc[xf][wf][2] + bv[wf].z;
                o.w = acc[xf][wf][3] + bv[wf].w;
                *(float4*)(smem + r * RS + col * 4) = o;
            }
        }
    }
    __syncthreads();

    if (FUSE == 0) {
        float* Y = (float*)Yv;
        constexpr int NF4 = 64 * NCOL / 4;
#pragma unroll
        for (int i = 0; i < NF4 / 256; ++i) {
            int slot = tid + i * 256;
            int r = slot / (NCOL / 4), c4 = slot % (NCOL / 4);
            int gr = row0 + r;
            if (gr < M)
                *(float4*)(Y + (size_t)gr * NCOL + c4 * 4) =
                    *(const float4*)(smem + r * RS + c4 * 16);
        }
    } else {
        constexpr int CPT = NCOL / 4;          // cols per thread
        int r = tid >> 2, seg = tid & 3;
        const char* rp = smem + r * RS + seg * CPT * 4;
        float s = 0.f, sq = 0.f;
#pragma unroll
        for (int j = 0; j < CPT / 4; ++j) {
            float4 v = *(const float4*)(rp + j * 16);
            s += (v.x + v.y) + (v.z + v.w);
            sq += (v.x * v.x + v.y * v.y) + (v.z * v.z + v.w * v.w);
        }
        s += __shfl_xor(s, 1, 64); sq += __shfl_xor(sq, 1, 64);
        s += __shfl_xor(s, 2, 64); sq += __shfl_xor(sq, 2, 64);
        float mu = s * (1.f / NCOL);
        float var = sq * (1.f / NCOL) - mu * mu;
        float rstd = rsqrtf(var + 1e-5f);
        int gr = row0 + r;
        if (gr < M) {
#pragma unroll
            for (int j = 0; j < CPT / 4; ++j) {
                int c0 = seg * CPT + j * 4;
                float4 v = *(const float4*)(rp + j * 16);
                float4 gg = *(const float4*)(lng + c0);
                float4 bb = *(const float4*)(lnb + c0);
                float y0 = (v.x - mu) * rstd * gg.x + bb.x;
                float y1 = (v.y - mu) * rstd * gg.y + bb.y;
                float y2 = (v.z - mu) * rstd * gg.z + bb.z;
                float y3 = (v.w - mu) * rstd * gg.w + bb.w;
                if (FUSE == 1) {
                    y0 = fmaxf(y0, 0.f); y1 = fmaxf(y1, 0.f);
                    y2 = fmaxf(y2, 0.f); y3 = fmaxf(y3, 0.f);
                } else {
                    y0 = 0.5f * y0 * (1.f + erff(y0 * 0.70710678118654752f));
                    y1 = 0.5f * y1 * (1.f + erff(y1 * 0.70710678118654752f));
                    y2 = 0.5f * y2 * (1.f + erff(y2 * 0.70710678118654752f));
                    y3 = 0.5f * y3 * (1.f + erff(y3 * 0.70710678118654752f));
                }
                if (FUSE == 3) {
                    float4 o = make_float4(y0, y1, y2, y3);
                    *(float4*)((float*)Yv + (size_t)gr * NCOL + c0) = o;
                } else {
                    char* ob = (char*)Yv + (size_t)gr * 512;
                    ushort_t h0, l0, h1, l1, h2, l2, h3, l3;
                    split_bf16(y0, h0, l0); split_bf16(y1, h1, l1);
                    split_bf16(y2, h2, l2); split_bf16(y3, h3, l3);
                    uint2 hw, lw;
                    hw.x = (unsigned)h0 | ((unsigned)h1 << 16);
                    hw.y = (unsigned)h2 | ((unsigned)h3 << 16);
                    lw.x = (unsigned)l0 | ((unsigned)l1 << 16);
                    lw.y = (unsigned)l2 | ((unsigned)l3 << 16);
                    *(uint2*)(ob + 2 * c0) = hw;
                    *(uint2*)(ob + 256 + 2 * c0) = lw;
                }
            }
        }
    }
}

// ============================== CSR build ((dst,rel)-sorted) ===============
__global__ __launch_bounds__(256) void hist3_kernel(const int* __restrict__ edst,
                                                    const int* __restrict__ etype,
                                                    int* __restrict__ deg3, int E) {
    int e = blockIdx.x * 256 + threadIdx.x;
    if (e < E) atomicAdd(&deg3[edst[e] * 3 + etype[e]], 1);
}

__global__ __launch_bounds__(256) void degtot_kernel(const int* __restrict__ deg3,
                                                     int* __restrict__ degtot, int N) {
    int n = blockIdx.x * 256 + threadIdx.x;
    if (n < N) degtot[n] = deg3[n * 3] + deg3[n * 3 + 1] + deg3[n * 3 + 2];
}

__global__ __launch_bounds__(256) void scan_block(const int* __restrict__ in,
                                                  int* __restrict__ out,
                                                  int* __restrict__ sums, int n) {
    __shared__ int s[256];
    int g = blockIdx.x * 256 + threadIdx.x;
    int v = (g < n) ? in[g] : 0;
    s[threadIdx.x] = v;
    __syncthreads();
    int acc = v;
    for (int off = 1; off < 256; off <<= 1) {
        int t = (threadIdx.x >= off) ? s[threadIdx.x - off] : 0;
        __syncthreads();
        acc += t;
        s[threadIdx.x] = acc;
        __syncthreads();
    }
    if (g < n) out[g] = acc - v;
    if (threadIdx.x == 255 && sums) sums[blockIdx.x] = acc;
}

__global__ __launch_bounds__(256) void scan_add(int* __restrict__ out,
                                                const int* __restrict__ topex,
                                                int n, int total) {
    int g = blockIdx.x * 256 + threadIdx.x;
    if (g < n) out[g] += topex[blockIdx.x];
    if (g == 0) out[n] = total;
}

__global__ __launch_bounds__(256) void ranges_kernel(
    const int* __restrict__ rowptr, const int* __restrict__ deg3,
    int4* __restrict__ ranges, int* __restrict__ cursor3, int N) {
    int n = blockIdx.x * 256 + threadIdx.x;
    if (n >= N) return;
    int b = rowptr[n];
    int d0 = deg3[n * 3], d1 = deg3[n * 3 + 1];
    int4 r;
    r.x = b; r.y = b + d0; r.z = b + d0 + d1; r.w = rowptr[n + 1];
    ranges[n] = r;
    cursor3[n * 3] = r.x; cursor3[n * 3 + 1] = r.y; cursor3[n * 3 + 2] = r.z;
}

__global__ __launch_bounds__(256) void fill3_kernel(
    const int* __restrict__ esrc, const int* __restrict__ edst,
    const int* __restrict__ etype, int* __restrict__ cursor3,
    int* __restrict__ colidx, int E) {
    int e = blockIdx.x * 256 + threadIdx.x;
    if (e >= E) return;
    int pos = atomicAdd(&cursor3[edst[e] * 3 + etype[e]], 1);
    colidx[pos] = esrc[e];
}

// ===================== fused add-gather: S_r = A_r x -> planes =============
__device__ __forceinline__ float4 gather_sum(const float4* __restrict__ X4,
                                             const int* __restrict__ colidx,
                                             int beg, int end, int l) {
    float4 a = make_float4(0.f, 0.f, 0.f, 0.f);
    int e = beg;
    for (; e + 4 <= end; e += 4) {
        int s0 = colidx[e], s1 = colidx[e + 1];
        int s2 = colidx[e + 2], s3 = colidx[e + 3];
        float4 v0 = X4[(size_t)s0 * 32 + l];
        float4 v1 = X4[(size_t)s1 * 32 + l];
        float4 v2 = X4[(size_t)s2 * 32 + l];
        float4 v3 = X4[(size_t)s3 * 32 + l];
        a.x += (v0.x + v1.x) + (v2.x + v3.x);
        a.y += (v0.y + v1.y) + (v2.y + v3.y);
        a.z += (v0.z + v1.z) + (v2.z + v3.z);
        a.w += (v0.w + v1.w) + (v2.w + v3.w);
    }
    for (; e < end; ++e) {
        float4 v = X4[(size_t)colidx[e] * 32 + l];
        a.x += v.x; a.y += v.y; a.z += v.z; a.w += v.w;
    }
    return a;
}

__device__ __forceinline__ void store_plane4(char* rowbase, int l, float4 a) {
    uint2 h, lo;
    split4(a, h, lo);
    *(uint2*)(rowbase + 8 * l) = h;
    *(uint2*)(rowbase + 256 + 8 * l) = lo;
}

__global__ __launch_bounds__(256) void agg3_add(
    const float* __restrict__ x, const int4* __restrict__ ranges,
    const int* __restrict__ colidx, char* __restrict__ S0,
    char* __restrict__ S1, char* __restrict__ S2, int N) {
    int node = blockIdx.x * 8 + (threadIdx.x >> 5);
    int l = threadIdx.x & 31;
    if (node >= N) return;
    int4 rg = ranges[node];
    const float4* X4 = (const float4*)x;
    float4 a0 = gather_sum(X4, colidx, rg.x, rg.y, l);
    float4 a1 = gather_sum(X4, colidx, rg.y, rg.z, l);
    float4 a2 = gather_sum(X4, colidx, rg.z, rg.w, l);
    store_plane4(S0 + (size_t)node * 512, l, a0);
    store_plane4(S1 + (size_t)node * 512, l, a1);
    store_plane4(S2 + (size_t)node * 512, l, a2);
}

// ===================== max-gather RMW: acc += max_r(H[src])  ===============
__global__ __launch_bounds__(256) void maxagg(
    const float* __restrict__ H, const int4* __restrict__ ranges,
    const int* __restrict__ colidx, int rel, float* __restrict__ acc, int N) {
    int node = blockIdx.x * 8 + (threadIdx.x >> 5);
    int l = threadIdx.x & 31;
    if (node >= N) return;
    int4 rg = ranges[node];
    int beg = (rel == 0) ? rg.x : ((rel == 1) ? rg.y : rg.z);
    int end = (rel == 0) ? rg.y : ((rel == 1) ? rg.z : rg.w);
    if (beg >= end) return;
    const float4* H4 = (const float4*)H;
    float4 m = make_float4(-INFINITY, -INFINITY, -INFINITY, -INFINITY);
    int e = beg;
    for (; e + 4 <= end; e += 4) {
        int s0 = colidx[e], s1 = colidx[e + 1];
        int s2 = colidx[e + 2], s3 = colidx[e + 3];
        float4 v0 = H4[(size_t)s0 * 32 + l];
        float4 v1 = H4[(size_t)s1 * 32 + l];
        float4 v2 = H4[(size_t)s2 * 32 + l];
        float4 v3 = H4[(size_t)s3 * 32 + l];
        m.x = fmaxf(m.x, fmaxf(fmaxf(v0.x, v1.x), fmaxf(v2.x, v3.x)));
        m.y = fmaxf(m.y, fmaxf(fmaxf(v0.y, v1.y), fmaxf(v2.y, v3.y)));
        m.z = fmaxf(m.z, fmaxf(fmaxf(v0.z, v1.z), fmaxf(v2.z, v3.z)));
        m.w = fmaxf(m.w, fmaxf(fmaxf(v0.w, v1.w), fmaxf(v2.w, v3.w)));
    }
    for (; e < end; ++e) {
        float4 v = H4[(size_t)colidx[e] * 32 + l];
        m.x = fmaxf(m.x, v.x); m.y = fmaxf(m.y, v.y);
        m.z = fmaxf(m.z, v.z); m.w = fmaxf(m.w, v.w);
    }
    float4* ap = (float4*)acc + (size_t)node * 32 + l;
    float4 c = *ap;
    c.x += m.x; c.y += m.y; c.z += m.z; c.w += m.w;
    *ap = c;
}

// ===================== LayerNorm (standalone, conv2 only) ==================
// MODE: 1=relu+0.2*resid(planes); OUT: 1=plane rows
template <int D, int MODE, int OUT>
__global__ __launch_bounds__(256) void ln_kernel(const float* __restrict__ in,
                                                 const float* __restrict__ g,
                                                 const float* __restrict__ b,
                                                 const char* __restrict__ residP,
                                                 void* __restrict__ outv, int M) {
    int row = blockIdx.x * 4 + (threadIdx.x >> 6);
    int lane = threadIdx.x & 63;
    if (row >= M) return;
    constexpr int EPL = D / 64;
    float v[EPL];
    const float* ip = in + (size_t)row * D;
#pragma unroll
    for (int j = 0; j < EPL; ++j) v[j] = ip[lane * EPL + j];
    float s = 0.f, sq = 0.f;
#pragma unroll
    for (int j = 0; j < EPL; ++j) { s += v[j]; sq += v[j] * v[j]; }
#pragma unroll
    for (int off = 32; off; off >>= 1) {
        s += __shfl_xor(s, off, 64);
        sq += __shfl_xor(sq, off, 64);
    }
    float mu = s * (1.f / D);
    float var = sq * (1.f / D) - mu * mu;
    float rs = rsqrtf(var + 1e-5f);
    float y[EPL];
#pragma unroll
    for (int j = 0; j < EPL; ++j) {
        int c = lane * EPL + j;
        float t = (v[j] - mu) * rs * g[c] + b[c];
        if (MODE == 1) {
            const char* rb = residP + (size_t)row * 512;
            float rf = bf2f(*(const ushort_t*)(rb + 2 * c)) +
                       bf2f(*(const ushort_t*)(rb + 256 + 2 * c));
            t = fmaxf(t, 0.f) + 0.2f * rf;
        } else {
            t = fmaxf(t, 0.f);
        }
        y[j] = t;
    }
    if (OUT == 0) {
        float* out = (float*)outv;
#pragma unroll
        for (int j = 0; j < EPL; ++j) out[(size_t)row * D + lane * EPL + j] = y[j];
    } else {
        char* ob = (char*)outv + (size_t)row * 512;
        ushort_t h0, l0, h1, l1;
        split_bf16(y[0], h0, l0);
        split_bf16(y[1], h1, l1);
        *(unsigned*)(ob + 4 * lane) = (unsigned)h0 | ((unsigned)h1 << 16);
        *(unsigned*)(ob + 256 + 4 * lane) = (unsigned)l0 | ((unsigned)l1 << 16);
    }
}

// =================== f32 GEMM  M x 64 @ 64 x 40  (classifier out) ==========
__global__ __launch_bounds__(256) void gemm_40(const float* __restrict__ X,
                                               const float* __restrict__ W,
                                               const float* __restrict__ bias,
                                               float* __restrict__ Y, int M) {
    __shared__ float Xs[64][65];
    __shared__ float Ws[64 * 40];
    const int tid = threadIdx.x;
    const int row0 = blockIdx.x * 64;
    for (int i = tid; i < 64 * 40; i += 256) Ws[i] = W[i];
#pragma unroll
    for (int i = 0; i < 4; ++i) {
        int slot = tid + i * 256;
        int r = slot >> 4, c4 = slot & 15;
        float4 v = make_float4(0.f, 0.f, 0.f, 0.f);
        if (row0 + r < M) v = *(const float4*)(X + (size_t)(row0 + r) * 64 + c4 * 4);
        Xs[r][c4 * 4 + 0] = v.x; Xs[r][c4 * 4 + 1] = v.y;
        Xs[r][c4 * 4 + 2] = v.z; Xs[r][c4 * 4 + 3] = v.w;
    }
    __syncthreads();
    const int row = tid >> 2, cg = (tid & 3) * 10;
    float acc[10];
#pragma unroll
    for (int j = 0; j < 10; ++j) acc[j] = 0.f;
#pragma unroll 8
    for (int k = 0; k < 64; ++k) {
        float xv = Xs[row][k];
#pragma unroll
        for (int j = 0; j < 10; ++j) acc[j] = fmaf(xv, Ws[k * 40 + cg + j], acc[j]);
    }
    int grow = row0 + row;
    if (grow < M) {
#pragma unroll
        for (int j = 0; j < 10; ++j)
            Y[(size_t)grow * 40 + cg + j] = acc[j] + bias[cg + j];
    }
}

// ============================ log_softmax (rows of 40) =====================
__global__ __launch_bounds__(256) void lsm_kernel(const float* __restrict__ in,
                                                  float* __restrict__ out, int M) {
    int row = blockIdx.x * 4 + (threadIdx.x >> 6);
    int lane = threadIdx.x & 63;
    if (row >= M) return;
    float v = (lane < 40) ? in[(size_t)row * 40 + lane] : -INFINITY;
    float mx = v;
#pragma unroll
    for (int off = 32; off; off >>= 1) mx = fmaxf(mx, __shfl_xor(mx, off, 64));
    float e = (lane < 40) ? __expf(v - mx) : 0.f;
    float sum = e;
#pragma unroll
    for (int off = 32; off; off >>= 1) sum += __shfl_xor(sum, off, 64);
    float ls = logf(sum);
    if (lane < 40) out[(size_t)row * 40 + lane] = v - mx - ls;
}

// ===========================================================================
extern "C" void kernel_launch(void* const* d_in, const int* in_sizes, int n_in,
                              void* d_out, int out_size, void* d_ws, size_t ws_size,
                              hipStream_t stream) {
    const float* x       = (const float*)d_in[0];
    const int*   eidx    = (const int*)d_in[1];
    const int*   etype   = (const int*)d_in[2];
    const float* w1_rel  = (const float*)d_in[3];
    const float* w1_root = (const float*)d_in[4];
    const float* b1      = (const float*)d_in[5];
    const float* ln1_g   = (const float*)d_in[6];
    const float* ln1_b   = (const float*)d_in[7];
    const float* w2_rel  = (const float*)d_in[8];
    const float* w2_root = (const float*)d_in[9];
    const float* b2      = (const float*)d_in[10];
    const float* ln2_g   = (const float*)d_in[11];
    const float* ln2_b   = (const float*)d_in[12];
    const float* cw1     = (const float*)d_in[13];
    const float* cb1     = (const float*)d_in[14];
    const float* cln1_g  = (const float*)d_in[15];
    const float* cln1_b  = (const float*)d_in[16];
    const float* cw2     = (const float*)d_in[17];
    const float* cb2     = (const float*)d_in[18];
    const float* cln2_g  = (const float*)d_in[19];
    const float* cln2_b  = (const float*)d_in[20];
    const float* cw3     = (const float*)d_in[21];
    const float* cb3     = (const float*)d_in[22];

    const int N = in_sizes[0] / 128;   // 50000
    const int E = in_sizes[1] / 2;     // 600000
    const int* esrc = eidx;
    const int* edst = eidx + E;

    const size_t NFB = (size_t)N * 512;     // one [N,128]-f32-equivalent, bytes
    char* B0 = (char*)d_ws;
    char* B1 = B0 + NFB;
    char* B2 = B1 + NFB;
    char* B3 = B2 + NFB;   // META: CSR + wfrag

    int* rowptr  = (int*)B3;                      // N+1
    int* degtot  = rowptr + (N + 1);              // N
    int* deg3    = degtot + N;                    // 3N
    int* cursor3 = deg3 + 3 * N;                  // 3N
    int* bsums   = cursor3 + 3 * N;               // 256
    int* btop    = bsums + 256;                   // 256
    int4* ranges = (int4*)(((uintptr_t)(btop + 256) + 15) & ~(uintptr_t)15);
    int* colidx  = (int*)(ranges + N);            // E
    ushort_t* wfb = (ushort_t*)(((uintptr_t)(colidx + E) + 255) & ~(uintptr_t)255);
    // 10 slots x 32768 ushorts: 0=w1_root 1-3=w1_rel 4=w2_root 5-7=w2_rel
    // 8=cw1 9=cw2(64col)
    auto WSLOT = [&](int i) { return wfb + (size_t)i * 32768; };

    const dim3 blk(256);
    const int gGemm = (N + 63) / 64;
    const int gAgg  = (N + 7) / 8;
    const int gRow  = (N + 3) / 4;
    const int gEdge = (E + 255) / 256;
    const int gNode = (N + 255) / 256;
    const int nScanB = (N + 255) / 256;

    // ---------------- CSR build ----------------
    hipMemsetAsync(deg3, 0, (size_t)3 * N * sizeof(int), stream);
    hist3_kernel<<<gEdge, blk, 0, stream>>>(edst, etype, deg3, E);
    degtot_kernel<<<gNode, blk, 0, stream>>>(deg3, degtot, N);
    scan_block<<<nScanB, blk, 0, stream>>>(degtot, rowptr, bsums, N);
    scan_block<<<1, blk, 0, stream>>>(bsums, btop, nullptr, nScanB);
    scan_add<<<nScanB, blk, 0, stream>>>(rowptr, btop, N, E);
    ranges_kernel<<<gNode, blk, 0, stream>>>(rowptr, deg3, ranges, cursor3, N);
    fill3_kernel<<<gEdge, blk, 0, stream>>>(esrc, edst, etype, cursor3, colidx, E);

    // ---------------- convert weights to fragment order ----------------
    convert_wfrag<128><<<8, blk, 0, stream>>>(w1_root, WSLOT(0));
    for (int r = 0; r < 3; ++r)
        convert_wfrag<128><<<8, blk, 0, stream>>>(w1_rel + (size_t)r * 16384, WSLOT(1 + r));
    convert_wfrag<128><<<8, blk, 0, stream>>>(w2_root, WSLOT(4));
    for (int r = 0; r < 3; ++r)
        convert_wfrag<128><<<8, blk, 0, stream>>>(w2_rel + (size_t)r * 16384, WSLOT(5 + r));
    convert_wfrag<128><<<8, blk, 0, stream>>>(cw1, WSLOT(8));
    convert_wfrag<64><<<4, blk, 0, stream>>>(cw2, WSLOT(9));

    // ---------------- conv1 (add): aggregate-then-transform ----------------
    // S planes -> B0,B1,B2; fused K=512 gemm + LN1 + relu -> x1 planes in B0
    // (in-place over S0 is safe: each block touches only its own 64 rows)
    agg3_add<<<gAgg, blk, 0, stream>>>(x, ranges, colidx, B0, B1, B2, N);
    gemm_planes<128, 4, true, 1><<<gGemm, blk, 0, stream>>>(
        (const char*)x, B0, B1, B2, WSLOT(0), b1, ln1_g, ln1_b, B0, N);

    // ---------------- conv2 (max) ----------------
    gemm_planes<128, 1, false, 0><<<gGemm, blk, 0, stream>>>(
        B0, B0, B0, B0, WSLOT(4), b2, nullptr, nullptr, B1, N);   // acc f32 -> B1
    for (int r = 0; r < 3; ++r) {
        gemm_planes<128, 1, false, 0><<<gGemm, blk, 0, stream>>>(
            B0, B0, B0, B0, WSLOT(5 + r), nullptr, nullptr, nullptr, B2, N);
        maxagg<<<gAgg, blk, 0, stream>>>((float*)B2, ranges, colidx, r,
                                         (float*)B1, N);
    }
    // h2 = relu(LN(B1)) + 0.2*x1(B0 planes) -> planes B2
    ln_kernel<128, 1, 1><<<gRow, blk, 0, stream>>>((float*)B1, ln2_g, ln2_b,
                                                   B0, B2, N);

    // ---------------- classifier ----------------
    gemm_planes<128, 1, false, 2><<<gGemm, blk, 0, stream>>>(
        B2, B2, B2, B2, WSLOT(8), cb1, cln1_g, cln1_b, B1, N);    // planes -> B1
    gemm_planes<64, 1, false, 3><<<gGemm, blk, 0, stream>>>(
        B1, B1, B1, B1, WSLOT(9), cb2, cln2_g, cln2_b, B0, N);    // f32[N,64] -> B0
    gemm_40<<<gGemm, blk, 0, stream>>>((float*)B0, cw3, cb3, (float*)B2, N);
    lsm_kernel<<<gRow, blk, 0, stream>>>((float*)B2, (float*)d_out, N);
}

// Round 7
// 391.168 us; speedup vs baseline: 5.8599x; 1.0383x over previous
//
#include <hip/hip_runtime.h>
#include <hip/hip_bf16.h>
#include <math.h>

// ---------------------------------------------------------------------------
// RGCN forward. Activations as bf16 hi/lo "plane rows" (512B/row).
// GEMM: split-bf16 triple MFMA, swapped operands; W pre-converted to
// fragment order in global; X via double-buffered LDS; ALL epilogue output
// goes through LDS and leaves as contiguous full-row uint4 stores
// (64B-line complete per instruction -> no L2 write-allocate).
// conv1 (add): aggregate-then-transform (one K=512 GEMM, fused LN1+relu).
// conv2 (max): transform-then-gather, f32 H + RMW max.
// ---------------------------------------------------------------------------

typedef __attribute__((ext_vector_type(8))) short bf16x8;
typedef __attribute__((ext_vector_type(4))) float f32x4;
typedef unsigned short ushort_t;

__device__ __forceinline__ void split_bf16(float v, ushort_t& h, ushort_t& l) {
    unsigned uv = __float_as_uint(v);
    unsigned rh = uv + 0x7FFFu + ((uv >> 16) & 1u);   // RNE to bf16
    ushort_t hu = (ushort_t)(rh >> 16);
    float hf = __uint_as_float((unsigned)hu << 16);
    float lo = v - hf;                                // exact
    unsigned ul = __float_as_uint(lo);
    unsigned rl = ul + 0x7FFFu + ((ul >> 16) & 1u);
    h = hu;
    l = (ushort_t)(rl >> 16);
}

__device__ __forceinline__ void split4(float4 v, uint2& h, uint2& l) {
    ushort_t h0, h1, h2, h3, l0, l1, l2, l3;
    split_bf16(v.x, h0, l0); split_bf16(v.y, h1, l1);
    split_bf16(v.z, h2, l2); split_bf16(v.w, h3, l3);
    h.x = (unsigned)h0 | ((unsigned)h1 << 16);
    h.y = (unsigned)h2 | ((unsigned)h3 << 16);
    l.x = (unsigned)l0 | ((unsigned)l1 << 16);
    l.y = (unsigned)l2 | ((unsigned)l3 << 16);
}

__device__ __forceinline__ float bf2f(ushort_t u) {
    return __uint_as_float((unsigned)u << 16);
}

// ============ W[128][NCOL] f32 -> fragment-ordered bf16 hi/lo ==============
// layout (ushort): [plane][ks 0..3][cf 0..NCF-1][lane 0..63][8]
template <int NCOL>
__global__ __launch_bounds__(256) void convert_wfrag(const float* __restrict__ W,
                                                     ushort_t* __restrict__ out) {
    constexpr int NCF = NCOL / 16;
    constexpr int CSH = (NCF == 8) ? 3 : 2;
    constexpr size_t PST = (size_t)4 * NCF * 512;   // plane stride (ushorts)
    int idx = blockIdx.x * 256 + threadIdx.x;
    if (idx >= 4 * NCF * 64) return;
    int l = idx & 63;
    int cf = (idx >> 6) & (NCF - 1);
    int ks = idx >> (6 + CSH);
    int col = cf * 16 + (l & 15);
    int k0 = ks * 32 + (l >> 4) * 8;
    size_t base = (((size_t)ks * NCF + cf) * 64 + l) * 8;
#pragma unroll
    for (int j = 0; j < 8; ++j) {
        ushort_t h, lo_;
        split_bf16(W[(size_t)(k0 + j) * NCOL + col], h, lo_);
        out[base + j] = h;
        out[PST + base + j] = lo_;
    }
}

// ================= GEMM  Y[M,NCOL] = sum_s A_s[M,128] @ W_s + bias =========
// 256 thr / 4 waves (2 rowgrp x 2 colgrp), 64 rows/block.
// FUSE: 0 = bias only, f32 rows out
//       1 = bias + LN + relu -> plane rows out
//       2 = bias + LN + gelu -> plane rows out
//       3 = bias + LN + gelu -> f32 rows out
template <int NCOL, int NSEG, bool SPLIT0, int FUSE>
__global__ __launch_bounds__(256, 3) void gemm_planes(
    const char* __restrict__ A0, const char* __restrict__ A1,
    const char* __restrict__ A2, const char* __restrict__ A3,
    const ushort_t* __restrict__ wfrag, const float* __restrict__ bias,
    const float* __restrict__ lng, const float* __restrict__ lnb,
    void* __restrict__ Yv, int M) {
    constexpr int NCF = NCOL / 16;
    constexpr int WF = NCOL / 32;               // n-frags per wave
    constexpr int PST = 4 * NCF * 512;          // plane stride in wfrag
    constexpr int WSEG = 2 * PST;               // per-segment stride
    constexpr int RS = NCOL * 4 + 16;           // epilogue LDS row stride
    constexpr int EPB = 64 * RS;
    constexpr int SMEM_BYTES = (EPB > 32768) ? EPB : 32768;
    __shared__ __align__(16) char smem[SMEM_BYTES];
    char (*lds)[16384] = (char(*)[16384])smem;

    const int tid = threadIdx.x;
    const int wv = tid >> 6, lane = tid & 63, l15 = lane & 15, lg = lane >> 4;
    const int rowgrp = wv >> 1, colgrp = wv & 1;
    const int row0 = blockIdx.x * 64;
    const char* As[4] = {A0, A1, A2, A3};

    f32x4 acc[2][WF];
#pragma unroll
    for (int xf = 0; xf < 2; ++xf)
#pragma unroll
        for (int wf = 0; wf < WF; ++wf) acc[xf][wf] = (f32x4){0.f, 0.f, 0.f, 0.f};

    uint4 regs[4];

    auto LOADSTAGE = [&](int ch) {
        int seg = ch >> 1, kc = (ch & 1) * 64;
        const char* __restrict__ A = As[seg];
        if (SPLIT0 && seg == 0) {
#pragma unroll
            for (int i = 0; i < 4; ++i) {
                int s = tid + i * 256;             // 1024: 64r x 16 c4
                int r = s >> 4, c4 = s & 15;
                int gr = row0 + r;
                float4 v = make_float4(0.f, 0.f, 0.f, 0.f);
                if (gr < M) v = *(const float4*)(A + (size_t)gr * 512 + kc * 4 + c4 * 16);
                regs[i] = *(uint4*)&v;
            }
        } else {
#pragma unroll
            for (int i = 0; i < 4; ++i) {
                int s = tid + i * 256;             // 1024: 2p x 64r x 8 c16
                int p = s >> 9, r = (s >> 3) & 63, c16 = s & 7;
                int gr = row0 + r;
                uint4 v = make_uint4(0u, 0u, 0u, 0u);
                if (gr < M)
                    v = *(const uint4*)(A + (size_t)gr * 512 + p * 256 + kc * 2 + c16 * 16);
                regs[i] = v;
            }
        }
    };

    auto WRITESTAGE = [&](int ch, int buf) {
        char* L = lds[buf];
        if (SPLIT0 && (ch >> 1) == 0) {
#pragma unroll
            for (int i = 0; i < 4; ++i) {
                int s = tid + i * 256;
                int r = s >> 4, c4 = s & 15;
                uint2 hh, ll;
                float4 v = *(float4*)&regs[i];
                split4(v, hh, ll);
                int byte = (r * 128 + c4 * 8) ^ ((r & 7) << 4);
                *(uint2*)(L + byte) = hh;
                *(uint2*)(L + 8192 + byte) = ll;
            }
        } else {
#pragma unroll
            for (int i = 0; i < 4; ++i) {
                int s = tid + i * 256;
                int p = s >> 9, r = (s >> 3) & 63, c16 = s & 7;
                int byte = p * 8192 + ((r * 128 + c16 * 16) ^ ((r & 7) << 4));
                *(uint4*)(L + byte) = regs[i];
            }
        }
    };

    auto COMPUTE = [&](int ch, int buf) {
        int seg = ch >> 1, half = ch & 1;
        const ushort_t* __restrict__ ws = wfrag + (size_t)seg * WSEG;
        const char* L = lds[buf];
#pragma unroll
        for (int kk = 0; kk < 2; ++kk) {
            int ks = half * 2 + kk;
            bf16x8 xh[2], xl[2];
#pragma unroll
            for (int xf = 0; xf < 2; ++xf) {
                int r = rowgrp * 32 + xf * 16 + l15;
                int byte = (r * 128 + kk * 64 + lg * 16) ^ ((r & 7) << 4);
                xh[xf] = *(const bf16x8*)(L + byte);
                xl[xf] = *(const bf16x8*)(L + 8192 + byte);
            }
            bf16x8 wh[WF], wl[WF];
#pragma unroll
            for (int wf = 0; wf < WF; ++wf) {
                size_t off = (((size_t)ks * NCF + colgrp * WF + wf) * 64 + lane) * 8;
                wh[wf] = *(const bf16x8*)(ws + off);
                wl[wf] = *(const bf16x8*)(ws + PST + off);
            }
#pragma unroll
            for (int xf = 0; xf < 2; ++xf)
#pragma unroll
                for (int wf = 0; wf < WF; ++wf) {
                    acc[xf][wf] = __builtin_amdgcn_mfma_f32_16x16x32_bf16(
                        wh[wf], xh[xf], acc[xf][wf], 0, 0, 0);
                    acc[xf][wf] = __builtin_amdgcn_mfma_f32_16x16x32_bf16(
                        wl[wf], xh[xf], acc[xf][wf], 0, 0, 0);
                    acc[xf][wf] = __builtin_amdgcn_mfma_f32_16x16x32_bf16(
                        wh[wf], xl[xf], acc[xf][wf], 0, 0, 0);
                }
        }
    };

    constexpr int CH = 2 * NSEG;
    LOADSTAGE(0);
    WRITESTAGE(0, 0);
    __syncthreads();
    for (int ch = 0; ch < CH; ++ch) {
        if (ch + 1 < CH) LOADSTAGE(ch + 1);
        COMPUTE(ch, ch & 1);
        __syncthreads();
        if (ch + 1 < CH) WRITESTAGE(ch + 1, (ch + 1) & 1);
        __syncthreads();
    }
    // staging LDS dead -> reuse as epilogue tile

    // ---- stage acc tile (+bias) into LDS as full f32 rows ----
    {
        float4 bv[WF];
#pragma unroll
        for (int wf = 0; wf < WF; ++wf) {
            int col = colgrp * (NCOL / 2) + wf * 16 + lg * 4;
            bv[wf] = bias ? *(const float4*)(bias + col)
                          : make_float4(0.f, 0.f, 0.f, 0.f);
        }
#pragma unroll
        for (int xf = 0; xf < 2; ++xf) {
            int r = rowgrp * 32 + xf * 16 + l15;
#pragma unroll
            for (int wf = 0; wf < WF; ++wf) {
                int col = colgrp * (NCOL / 2) + wf * 16 + lg * 4;
                float4 o;
                o.x = acc[xf][wf][0] + bv[wf].x;
                o.y = acc[xf][wf][1] + bv[wf].y;
                o.z = acc[xf][wf][2] + bv[wf].z;
                o.w = acc[xf][wf][3] + bv[wf].w;
                *(float4*)(smem + r * RS + col * 4) = o;
            }
        }
    }
    __syncthreads();

    if (FUSE != 0) {
        // LN across the row (4 threads/row), activation, write BACK to LDS
        constexpr int CPT = NCOL / 4;          // cols per thread
        int r = tid >> 2, seg = tid & 3;
        char* rp = smem + r * RS + seg * CPT * 4;
        float s = 0.f, sq = 0.f;
        float4 vv[CPT / 4];
#pragma unroll
        for (int j = 0; j < CPT / 4; ++j) {
            float4 v = *(const float4*)(rp + j * 16);
            vv[j] = v;
            s += (v.x + v.y) + (v.z + v.w);
            sq += (v.x * v.x + v.y * v.y) + (v.z * v.z + v.w * v.w);
        }
        s += __shfl_xor(s, 1, 64); sq += __shfl_xor(sq, 1, 64);
        s += __shfl_xor(s, 2, 64); sq += __shfl_xor(sq, 2, 64);
        float mu = s * (1.f / NCOL);
        float var = sq * (1.f / NCOL) - mu * mu;
        float rstd = rsqrtf(var + 1e-5f);
#pragma unroll
        for (int j = 0; j < CPT / 4; ++j) {
            int c0 = seg * CPT + j * 4;
            float4 v = vv[j];
            float4 gg = *(const float4*)(lng + c0);
            float4 bb = *(const float4*)(lnb + c0);
            float y0 = (v.x - mu) * rstd * gg.x + bb.x;
            float y1 = (v.y - mu) * rstd * gg.y + bb.y;
            float y2 = (v.z - mu) * rstd * gg.z + bb.z;
            float y3 = (v.w - mu) * rstd * gg.w + bb.w;
            if (FUSE == 1) {
                y0 = fmaxf(y0, 0.f); y1 = fmaxf(y1, 0.f);
                y2 = fmaxf(y2, 0.f); y3 = fmaxf(y3, 0.f);
            } else {
                y0 = 0.5f * y0 * (1.f + erff(y0 * 0.70710678118654752f));
                y1 = 0.5f * y1 * (1.f + erff(y1 * 0.70710678118654752f));
                y2 = 0.5f * y2 * (1.f + erff(y2 * 0.70710678118654752f));
                y3 = 0.5f * y3 * (1.f + erff(y3 * 0.70710678118654752f));
            }
            vv[j] = make_float4(y0, y1, y2, y3);
        }
        __syncthreads();   // all reads of the f32 tile done before overwrite
        if (FUSE == 3) {
#pragma unroll
            for (int j = 0; j < CPT / 4; ++j) *(float4*)(rp + j * 16) = vv[j];
        } else {
            // plane layout within row: [hi 256B][lo 256B] at base r*RS
#pragma unroll
            for (int j = 0; j < CPT / 4; ++j) {
                int c0 = seg * CPT + j * 4;
                uint2 hw, lw;
                split4(vv[j], hw, lw);
                *(uint2*)(smem + r * RS + 2 * c0) = hw;
                *(uint2*)(smem + r * RS + 256 + 2 * c0) = lw;
            }
        }
        __syncthreads();
    }

    // ---- contiguous copy-out: full rows, line-complete per instruction ----
    {
        constexpr int OUTB = (FUSE == 0) ? NCOL * 4
                           : (FUSE == 3) ? NCOL * 4 : 512;   // bytes per row
        constexpr int RP = OUTB / 16;                        // uint4 per row
        constexpr int SL = 64 * RP;
#pragma unroll
        for (int i = 0; i < SL / 256; ++i) {
            int slot = tid + i * 256;
            int rr = slot / RP, c16 = slot % RP;
            int gr = row0 + rr;
            if (gr < M)
                *(uint4*)((char*)Yv + (size_t)gr * OUTB + c16 * 16) =
                    *(const uint4*)(smem + rr * RS + c16 * 16);
        }
    }
}

// ============================== CSR build ((dst,rel)-sorted) ===============
__global__ __launch_bounds__(256) void hist3_kernel(const int* __restrict__ edst,
                                                    const int* __restrict__ etype,
                                                    int* __restrict__ deg3, int E) {
    int e = blockIdx.x * 256 + threadIdx.x;
    if (e < E) atomicAdd(&deg3[edst[e] * 3 + etype[e]], 1);
}

__global__ __launch_bounds__(256) void degtot_kernel(const int* __restrict__ deg3,
                                                     int* __restrict__ degtot, int N) {
    int n = blockIdx.x * 256 + threadIdx.x;
    if (n < N) degtot[n] = deg3[n * 3] + deg3[n * 3 + 1] + deg3[n * 3 + 2];
}

__global__ __launch_bounds__(256) void scan_block(const int* __restrict__ in,
                                                  int* __restrict__ out,
                                                  int* __restrict__ sums, int n) {
    __shared__ int s[256];
    int g = blockIdx.x * 256 + threadIdx.x;
    int v = (g < n) ? in[g] : 0;
    s[threadIdx.x] = v;
    __syncthreads();
    int acc = v;
    for (int off = 1; off < 256; off <<= 1) {
        int t = (threadIdx.x >= off) ? s[threadIdx.x - off] : 0;
        __syncthreads();
        acc += t;
        s[threadIdx.x] = acc;
        __syncthreads();
    }
    if (g < n) out[g] = acc - v;
    if (threadIdx.x == 255 && sums) sums[blockIdx.x] = acc;
}

__global__ __launch_bounds__(256) void scan_add(int* __restrict__ out,
                                                const int* __restrict__ topex,
                                                int n, int total) {
    int g = blockIdx.x * 256 + threadIdx.x;
    if (g < n) out[g] += topex[blockIdx.x];
    if (g == 0) out[n] = total;
}

__global__ __launch_bounds__(256) void ranges_kernel(
    const int* __restrict__ rowptr, const int* __restrict__ deg3,
    int4* __restrict__ ranges, int* __restrict__ cursor3, int N) {
    int n = blockIdx.x * 256 + threadIdx.x;
    if (n >= N) return;
    int b = rowptr[n];
    int d0 = deg3[n * 3], d1 = deg3[n * 3 + 1];
    int4 r;
    r.x = b; r.y = b + d0; r.z = b + d0 + d1; r.w = rowptr[n + 1];
    ranges[n] = r;
    cursor3[n * 3] = r.x; cursor3[n * 3 + 1] = r.y; cursor3[n * 3 + 2] = r.z;
}

__global__ __launch_bounds__(256) void fill3_kernel(
    const int* __restrict__ esrc, const int* __restrict__ edst,
    const int* __restrict__ etype, int* __restrict__ cursor3,
    int* __restrict__ colidx, int E) {
    int e = blockIdx.x * 256 + threadIdx.x;
    if (e >= E) return;
    int pos = atomicAdd(&cursor3[edst[e] * 3 + etype[e]], 1);
    colidx[pos] = esrc[e];
}

// ===================== fused add-gather: S_r = A_r x -> planes =============
__device__ __forceinline__ float4 gather_sum(const float4* __restrict__ X4,
                                             const int* __restrict__ colidx,
                                             int beg, int end, int l) {
    float4 a = make_float4(0.f, 0.f, 0.f, 0.f);
    int e = beg;
    for (; e + 4 <= end; e += 4) {
        int s0 = colidx[e], s1 = colidx[e + 1];
        int s2 = colidx[e + 2], s3 = colidx[e + 3];
        float4 v0 = X4[(size_t)s0 * 32 + l];
        float4 v1 = X4[(size_t)s1 * 32 + l];
        float4 v2 = X4[(size_t)s2 * 32 + l];
        float4 v3 = X4[(size_t)s3 * 32 + l];
        a.x += (v0.x + v1.x) + (v2.x + v3.x);
        a.y += (v0.y + v1.y) + (v2.y + v3.y);
        a.z += (v0.z + v1.z) + (v2.z + v3.z);
        a.w += (v0.w + v1.w) + (v2.w + v3.w);
    }
    for (; e < end; ++e) {
        float4 v = X4[(size_t)colidx[e] * 32 + l];
        a.x += v.x; a.y += v.y; a.z += v.z; a.w += v.w;
    }
    return a;
}

__device__ __forceinline__ void store_plane4(char* rowbase, int l, float4 a) {
    uint2 h, lo;
    split4(a, h, lo);
    *(uint2*)(rowbase + 8 * l) = h;
    *(uint2*)(rowbase + 256 + 8 * l) = lo;
}

__global__ __launch_bounds__(256) void agg3_add(
    const float* __restrict__ x, const int4* __restrict__ ranges,
    const int* __restrict__ colidx, char* __restrict__ S0,
    char* __restrict__ S1, char* __restrict__ S2, int N) {
    int node = blockIdx.x * 8 + (threadIdx.x >> 5);
    int l = threadIdx.x & 31;
    if (node >= N) return;
    int4 rg = ranges[node];
    const float4* X4 = (const float4*)x;
    float4 a0 = gather_sum(X4, colidx, rg.x, rg.y, l);
    float4 a1 = gather_sum(X4, colidx, rg.y, rg.z, l);
    float4 a2 = gather_sum(X4, colidx, rg.z, rg.w, l);
    store_plane4(S0 + (size_t)node * 512, l, a0);
    store_plane4(S1 + (size_t)node * 512, l, a1);
    store_plane4(S2 + (size_t)node * 512, l, a2);
}

// ===================== max-gather RMW: acc += max_r(H[src])  ===============
__global__ __launch_bounds__(256) void maxagg(
    const float* __restrict__ H, const int4* __restrict__ ranges,
    const int* __restrict__ colidx, int rel, float* __restrict__ acc, int N) {
    int node = blockIdx.x * 8 + (threadIdx.x >> 5);
    int l = threadIdx.x & 31;
    if (node >= N) return;
    int4 rg = ranges[node];
    int beg = (rel == 0) ? rg.x : ((rel == 1) ? rg.y : rg.z);
    int end = (rel == 0) ? rg.y : ((rel == 1) ? rg.z : rg.w);
    if (beg >= end) return;
    const float4* H4 = (const float4*)H;
    float4 m = make_float4(-INFINITY, -INFINITY, -INFINITY, -INFINITY);
    int e = beg;
    for (; e + 4 <= end; e += 4) {
        int s0 = colidx[e], s1 = colidx[e + 1];
        int s2 = colidx[e + 2], s3 = colidx[e + 3];
        float4 v0 = H4[(size_t)s0 * 32 + l];
        float4 v1 = H4[(size_t)s1 * 32 + l];
        float4 v2 = H4[(size_t)s2 * 32 + l];
        float4 v3 = H4[(size_t)s3 * 32 + l];
        m.x = fmaxf(m.x, fmaxf(fmaxf(v0.x, v1.x), fmaxf(v2.x, v3.x)));
        m.y = fmaxf(m.y, fmaxf(fmaxf(v0.y, v1.y), fmaxf(v2.y, v3.y)));
        m.z = fmaxf(m.z, fmaxf(fmaxf(v0.z, v1.z), fmaxf(v2.z, v3.z)));
        m.w = fmaxf(m.w, fmaxf(fmaxf(v0.w, v1.w), fmaxf(v2.w, v3.w)));
    }
    for (; e < end; ++e) {
        float4 v = H4[(size_t)colidx[e] * 32 + l];
        m.x = fmaxf(m.x, v.x); m.y = fmaxf(m.y, v.y);
        m.z = fmaxf(m.z, v.z); m.w = fmaxf(m.w, v.w);
    }
    float4* ap = (float4*)acc + (size_t)node * 32 + l;
    float4 c = *ap;
    c.x += m.x; c.y += m.y; c.z += m.z; c.w += m.w;
    *ap = c;
}

// ===================== LayerNorm (standalone, conv2 post only) =============
template <int D, int MODE, int OUT>
__global__ __launch_bounds__(256) void ln_kernel(const float* __restrict__ in,
                                                 const float* __restrict__ g,
                                                 const float* __restrict__ b,
                                                 const char* __restrict__ residP,
                                                 void* __restrict__ outv, int M) {
    int row = blockIdx.x * 4 + (threadIdx.x >> 6);
    int lane = threadIdx.x & 63;
    if (row >= M) return;
    constexpr int EPL = D / 64;
    float v[EPL];
    const float* ip = in + (size_t)row * D;
#pragma unroll
    for (int j = 0; j < EPL; ++j) v[j] = ip[lane * EPL + j];
    float s = 0.f, sq = 0.f;
#pragma unroll
    for (int j = 0; j < EPL; ++j) { s += v[j]; sq += v[j] * v[j]; }
#pragma unroll
    for (int off = 32; off; off >>= 1) {
        s += __shfl_xor(s, off, 64);
        sq += __shfl_xor(sq, off, 64);
    }
    float mu = s * (1.f / D);
    float var = sq * (1.f / D) - mu * mu;
    float rs = rsqrtf(var + 1e-5f);
    float y[EPL];
#pragma unroll
    for (int j = 0; j < EPL; ++j) {
        int c = lane * EPL + j;
        float t = (v[j] - mu) * rs * g[c] + b[c];
        if (MODE == 1) {
            const char* rb = residP + (size_t)row * 512;
            float rf = bf2f(*(const ushort_t*)(rb + 2 * c)) +
                       bf2f(*(const ushort_t*)(rb + 256 + 2 * c));
            t = fmaxf(t, 0.f) + 0.2f * rf;
        } else {
            t = fmaxf(t, 0.f);
        }
        y[j] = t;
    }
    if (OUT == 0) {
        float* out = (float*)outv;
#pragma unroll
        for (int j = 0; j < EPL; ++j) out[(size_t)row * D + lane * EPL + j] = y[j];
    } else {
        char* ob = (char*)outv + (size_t)row * 512;
        ushort_t h0, l0, h1, l1;
        split_bf16(y[0], h0, l0);
        split_bf16(y[1], h1, l1);
        *(unsigned*)(ob + 4 * lane) = (unsigned)h0 | ((unsigned)h1 << 16);
        *(unsigned*)(ob + 256 + 4 * lane) = (unsigned)l0 | ((unsigned)l1 << 16);
    }
}

// =================== f32 GEMM  M x 64 @ 64 x 40  (classifier out) ==========
__global__ __launch_bounds__(256) void gemm_40(const float* __restrict__ X,
                                               const float* __restrict__ W,
                                               const float* __restrict__ bias,
                                               float* __restrict__ Y, int M) {
    __shared__ float Xs[64][65];
    __shared__ float Ws[64 * 40];
    __shared__ float Ys[64][41];
    const int tid = threadIdx.x;
    const int row0 = blockIdx.x * 64;
    for (int i = tid; i < 64 * 40; i += 256) Ws[i] = W[i];
#pragma unroll
    for (int i = 0; i < 4; ++i) {
        int slot = tid + i * 256;
        int r = slot >> 4, c4 = slot & 15;
        float4 v = make_float4(0.f, 0.f, 0.f, 0.f);
        if (row0 + r < M) v = *(const float4*)(X + (size_t)(row0 + r) * 64 + c4 * 4);
        Xs[r][c4 * 4 + 0] = v.x; Xs[r][c4 * 4 + 1] = v.y;
        Xs[r][c4 * 4 + 2] = v.z; Xs[r][c4 * 4 + 3] = v.w;
    }
    __syncthreads();
    const int row = tid >> 2, cg = (tid & 3) * 10;
    float acc[10];
#pragma unroll
    for (int j = 0; j < 10; ++j) acc[j] = 0.f;
#pragma unroll 8
    for (int k = 0; k < 64; ++k) {
        float xv = Xs[row][k];
#pragma unroll
        for (int j = 0; j < 10; ++j) acc[j] = fmaf(xv, Ws[k * 40 + cg + j], acc[j]);
    }
#pragma unroll
    for (int j = 0; j < 10; ++j) Ys[row][cg + j] = acc[j] + bias[cg + j];
    __syncthreads();
    // contiguous copy-out: 64 rows x 160B
#pragma unroll
    for (int i = 0; i < 10; ++i) {
        int slot = tid + i * 256;
        int r = slot / 40, c = slot % 40;
        int gr = row0 + r;
        if (gr < M) Y[(size_t)gr * 40 + c] = Ys[r][c];
    }
}

// ============================ log_softmax (rows of 40) =====================
__global__ __launch_bounds__(256) void lsm_kernel(const float* __restrict__ in,
                                                  float* __restrict__ out, int M) {
    int row = blockIdx.x * 4 + (threadIdx.x >> 6);
    int lane = threadIdx.x & 63;
    if (row >= M) return;
    float v = (lane < 40) ? in[(size_t)row * 40 + lane] : -INFINITY;
    float mx = v;
#pragma unroll
    for (int off = 32; off; off >>= 1) mx = fmaxf(mx, __shfl_xor(mx, off, 64));
    float e = (lane < 40) ? __expf(v - mx) : 0.f;
    float sum = e;
#pragma unroll
    for (int off = 32; off; off >>= 1) sum += __shfl_xor(sum, off, 64);
    float ls = logf(sum);
    if (lane < 40) out[(size_t)row * 40 + lane] = v - mx - ls;
}

// ===========================================================================
extern "C" void kernel_launch(void* const* d_in, const int* in_sizes, int n_in,
                              void* d_out, int out_size, void* d_ws, size_t ws_size,
                              hipStream_t stream) {
    const float* x       = (const float*)d_in[0];
    const int*   eidx    = (const int*)d_in[1];
    const int*   etype   = (const int*)d_in[2];
    const float* w1_rel  = (const float*)d_in[3];
    const float* w1_root = (const float*)d_in[4];
    const float* b1      = (const float*)d_in[5];
    const float* ln1_g   = (const float*)d_in[6];
    const float* ln1_b   = (const float*)d_in[7];
    const float* w2_rel  = (const float*)d_in[8];
    const float* w2_root = (const float*)d_in[9];
    const float* b2      = (const float*)d_in[10];
    const float* ln2_g   = (const float*)d_in[11];
    const float* ln2_b   = (const float*)d_in[12];
    const float* cw1     = (const float*)d_in[13];
    const float* cb1     = (const float*)d_in[14];
    const float* cln1_g  = (const float*)d_in[15];
    const float* cln1_b  = (const float*)d_in[16];
    const float* cw2     = (const float*)d_in[17];
    const float* cb2     = (const float*)d_in[18];
    const float* cln2_g  = (const float*)d_in[19];
    const float* cln2_b  = (const float*)d_in[20];
    const float* cw3     = (const float*)d_in[21];
    const float* cb3     = (const float*)d_in[22];

    const int N = in_sizes[0] / 128;   // 50000
    const int E = in_sizes[1] / 2;     // 600000
    const int* esrc = eidx;
    const int* edst = eidx + E;

    const size_t NFB = (size_t)N * 512;     // one [N,128]-f32-equivalent, bytes
    char* B0 = (char*)d_ws;
    char* B1 = B0 + NFB;
    char* B2 = B1 + NFB;
    char* B3 = B2 + NFB;   // META: CSR + wfrag

    int* rowptr  = (int*)B3;                      // N+1
    int* degtot  = rowptr + (N + 1);              // N
    int* deg3    = degtot + N;                    // 3N
    int* cursor3 = deg3 + 3 * N;                  // 3N
    int* bsums   = cursor3 + 3 * N;               // 256
    int* btop    = bsums + 256;                   // 256
    int4* ranges = (int4*)(((uintptr_t)(btop + 256) + 15) & ~(uintptr_t)15);
    int* colidx  = (int*)(ranges + N);            // E
    ushort_t* wfb = (ushort_t*)(((uintptr_t)(colidx + E) + 255) & ~(uintptr_t)255);
    // 10 slots x 32768 ushorts: 0=w1_root 1-3=w1_rel 4=w2_root 5-7=w2_rel
    // 8=cw1 9=cw2(64col)
    auto WSLOT = [&](int i) { return wfb + (size_t)i * 32768; };

    const dim3 blk(256);
    const int gGemm = (N + 63) / 64;
    const int gAgg  = (N + 7) / 8;
    const int gRow  = (N + 3) / 4;
    const int gEdge = (E + 255) / 256;
    const int gNode = (N + 255) / 256;
    const int nScanB = (N + 255) / 256;

    // ---------------- CSR build ----------------
    hipMemsetAsync(deg3, 0, (size_t)3 * N * sizeof(int), stream);
    hist3_kernel<<<gEdge, blk, 0, stream>>>(edst, etype, deg3, E);
    degtot_kernel<<<gNode, blk, 0, stream>>>(deg3, degtot, N);
    scan_block<<<nScanB, blk, 0, stream>>>(degtot, rowptr, bsums, N);
    scan_block<<<1, blk, 0, stream>>>(bsums, btop, nullptr, nScanB);
    scan_add<<<nScanB, blk, 0, stream>>>(rowptr, btop, N, E);
    ranges_kernel<<<gNode, blk, 0, stream>>>(rowptr, deg3, ranges, cursor3, N);
    fill3_kernel<<<gEdge, blk, 0, stream>>>(esrc, edst, etype, cursor3, colidx, E);

    // ---------------- convert weights to fragment order ----------------
    convert_wfrag<128><<<8, blk, 0, stream>>>(w1_root, WSLOT(0));
    for (int r = 0; r < 3; ++r)
        convert_wfrag<128><<<8, blk, 0, stream>>>(w1_rel + (size_t)r * 16384, WSLOT(1 + r));
    convert_wfrag<128><<<8, blk, 0, stream>>>(w2_root, WSLOT(4));
    for (int r = 0; r < 3; ++r)
        convert_wfrag<128><<<8, blk, 0, stream>>>(w2_rel + (size_t)r * 16384, WSLOT(5 + r));
    convert_wfrag<128><<<8, blk, 0, stream>>>(cw1, WSLOT(8));
    convert_wfrag<64><<<4, blk, 0, stream>>>(cw2, WSLOT(9));

    // ---------------- conv1 (add): aggregate-then-transform ----------------
    // S planes -> B0,B1,B2; fused K=512 gemm + LN1 + relu -> x1 planes in B0
    agg3_add<<<gAgg, blk, 0, stream>>>(x, ranges, colidx, B0, B1, B2, N);
    gemm_planes<128, 4, true, 1><<<gGemm, blk, 0, stream>>>(
        (const char*)x, B0, B1, B2, WSLOT(0), b1, ln1_g, ln1_b, B0, N);

    // ---------------- conv2 (max) ----------------
    gemm_planes<128, 1, false, 0><<<gGemm, blk, 0, stream>>>(
        B0, B0, B0, B0, WSLOT(4), b2, nullptr, nullptr, B1, N);   // acc f32 -> B1
    for (int r = 0; r < 3; ++r) {
        gemm_planes<128, 1, false, 0><<<gGemm, blk, 0, stream>>>(
            B0, B0, B0, B0, WSLOT(5 + r), nullptr, nullptr, nullptr, B2, N);
        maxagg<<<gAgg, blk, 0, stream>>>((float*)B2, ranges, colidx, r,
                                         (float*)B1, N);
    }
    // h2 = relu(LN(B1)) + 0.2*x1(B0 planes) -> planes B2
    ln_kernel<128, 1, 1><<<gRow, blk, 0, stream>>>((float*)B1, ln2_g, ln2_b,
                                                   B0, B2, N);

    // ---------------- classifier ----------------
    gemm_planes<128, 1, false, 2><<<gGemm, blk, 0, stream>>>(
        B2, B2, B2, B2, WSLOT(8), cb1, cln1_g, cln1_b, B1, N);    // planes -> B1
    gemm_planes<64, 1, false, 3><<<gGemm, blk, 0, stream>>>(
        B1, B1, B1, B1, WSLOT(9), cb2, cln2_g, cln2_b, B0, N);    // f32[N,64] -> B0
    gemm_40<<<gGemm, blk, 0, stream>>>((float*)B0, cw3, cb3, (float*)B2, N);
    lsm_kernel<<<gRow, blk, 0, stream>>>((float*)B2, (float*)d_out, N);
}

// Round 8
// 311.805 us; speedup vs baseline: 7.3514x; 1.2545x over previous
//
#include <hip/hip_runtime.h>
#include <hip/hip_bf16.h>
#include <math.h>

// ---------------------------------------------------------------------------
// RGCN forward. Activations as bf16 hi/lo "plane rows" (512B/row); gather
// paths use bf16-only rows (256B). Split-bf16 triple-MFMA GEMMs with
// LDS-staged contiguous epilogues (optionally fused LN+activation).
// conv1: x->bf16 copy, fused add-gather (bf16), K=512 GEMM + LN1 + relu.
// conv2: root gemm f32 acc; 3 rel gemms -> bf16 H; ONE fused
//        maxagg+LN2+relu+resid pass. Classifier fused; gemm40+logsoftmax.
// ---------------------------------------------------------------------------

typedef __attribute__((ext_vector_type(8))) short bf16x8;
typedef __attribute__((ext_vector_type(4))) float f32x4;
typedef unsigned short ushort_t;

__device__ __forceinline__ ushort_t bf16rne(float v) {
    unsigned u = __float_as_uint(v);
    return (ushort_t)((u + 0x7FFFu + ((u >> 16) & 1u)) >> 16);
}

__device__ __forceinline__ void split_bf16(float v, ushort_t& h, ushort_t& l) {
    ushort_t hu = bf16rne(v);
    float hf = __uint_as_float((unsigned)hu << 16);
    float lo = v - hf;                                // exact
    h = hu;
    l = bf16rne(lo);
}

__device__ __forceinline__ void split4(float4 v, uint2& h, uint2& l) {
    ushort_t h0, h1, h2, h3, l0, l1, l2, l3;
    split_bf16(v.x, h0, l0); split_bf16(v.y, h1, l1);
    split_bf16(v.z, h2, l2); split_bf16(v.w, h3, l3);
    h.x = (unsigned)h0 | ((unsigned)h1 << 16);
    h.y = (unsigned)h2 | ((unsigned)h3 << 16);
    l.x = (unsigned)l0 | ((unsigned)l1 << 16);
    l.y = (unsigned)l2 | ((unsigned)l3 << 16);
}

__device__ __forceinline__ float bf2f(unsigned u16) {
    return __uint_as_float(u16 << 16);
}

__device__ __forceinline__ float4 unpack_bf4(uint2 u) {
    return make_float4(bf2f(u.x & 0xFFFFu), bf2f(u.x >> 16),
                       bf2f(u.y & 0xFFFFu), bf2f(u.y >> 16));
}

// ================= convert ALL weights to fragment order (1 launch) ========
// frag layout (ushort): [plane][ks 0..3][cf][lane 0..63][8], slot=32768 ush.
__device__ __forceinline__ void conv_body128(const float* __restrict__ W,
                                             ushort_t* __restrict__ out,
                                             int idx) {
    constexpr int NCF = 8;
    constexpr size_t PST = (size_t)4 * NCF * 512;
    int l = idx & 63;
    int cf = (idx >> 6) & 7;
    int ks = idx >> 9;
    int col = cf * 16 + (l & 15);
    int k0 = ks * 32 + (l >> 4) * 8;
    size_t base = (((size_t)ks * NCF + cf) * 64 + l) * 8;
#pragma unroll
    for (int j = 0; j < 8; ++j) {
        ushort_t h, lo_;
        split_bf16(W[(size_t)(k0 + j) * 128 + col], h, lo_);
        out[base + j] = h;
        out[PST + base + j] = lo_;
    }
}

__global__ __launch_bounds__(256) void convert_all(
    const float* __restrict__ w1_root, const float* __restrict__ w1_rel,
    const float* __restrict__ w2_root, const float* __restrict__ w2_rel,
    const float* __restrict__ cw1, const float* __restrict__ cw2,
    ushort_t* __restrict__ wfb) {
    int b = blockIdx.x;
    if (b < 72) {
        const float* src;
        int slot;
        if (b < 8)       { slot = 0;               src = w1_root; }
        else if (b < 32) { int r = (b - 8) >> 3;   slot = 1 + r; src = w1_rel + (size_t)r * 16384; }
        else if (b < 40) { slot = 4;               src = w2_root; }
        else if (b < 64) { int r = (b - 40) >> 3;  slot = 5 + r; src = w2_rel + (size_t)r * 16384; }
        else             { slot = 8;               src = cw1; }
        int lb = (b < 8) ? b : (b < 32) ? ((b - 8) & 7) : (b < 40) ? (b - 32)
               : (b < 64) ? ((b - 40) & 7) : (b - 64);
        conv_body128(src, wfb + (size_t)slot * 32768, lb * 256 + threadIdx.x);
    } else {
        // slot 9: cw2 [64][... wait: cw2 is [HID=128? no: 128x64] K=128,NCOL=64
        constexpr int NCF = 4;
        constexpr size_t PST = (size_t)4 * NCF * 512;
        int idx = (b - 72) * 256 + threadIdx.x;   // 4096 items
        ushort_t* out = wfb + (size_t)9 * 32768;
        int l = idx & 63;
        int cf = (idx >> 6) & 3;
        int ks = idx >> 8;
        int col = cf * 16 + (l & 15);
        int k0 = ks * 32 + (l >> 4) * 8;
        size_t base = (((size_t)ks * NCF + cf) * 64 + l) * 8;
#pragma unroll
        for (int j = 0; j < 8; ++j) {
            ushort_t h, lo_;
            split_bf16(cw2[(size_t)(k0 + j) * 64 + col], h, lo_);
            out[base + j] = h;
            out[PST + base + j] = lo_;
        }
    }
}

// ===================== x (f32) -> compact bf16 copy ========================
__global__ __launch_bounds__(256) void x2bf(const float* __restrict__ x,
                                            ushort_t* __restrict__ xh, int n4) {
    int g = blockIdx.x * 256 + threadIdx.x;
    if (g >= n4) return;
    float4 v = ((const float4*)x)[g];
    uint2 o;
    o.x = (unsigned)bf16rne(v.x) | ((unsigned)bf16rne(v.y) << 16);
    o.y = (unsigned)bf16rne(v.z) | ((unsigned)bf16rne(v.w) << 16);
    ((uint2*)xh)[g] = o;
}

// ================= GEMM  Y[M,NCOL] = sum_s A_s[M,128] @ W_s + bias =========
// 256 thr / 4 waves (2 rowgrp x 2 colgrp), 64 rows/block.
// FUSE: 0 = bias only, f32 rows out
//       1 = bias + LN + relu -> plane rows out
//       2 = bias + LN + gelu -> plane rows out
//       3 = bias + LN + gelu -> f32 rows out
//       4 = bias only -> bf16 rows out (256B/row)
template <int NCOL, int NSEG, bool SPLIT0, int FUSE>
__global__ __launch_bounds__(256, 3) void gemm_planes(
    const char* __restrict__ A0, const char* __restrict__ A1,
    const char* __restrict__ A2, const char* __restrict__ A3,
    const ushort_t* __restrict__ wfrag, const float* __restrict__ bias,
    const float* __restrict__ lng, const float* __restrict__ lnb,
    void* __restrict__ Yv, int M) {
    constexpr int NCF = NCOL / 16;
    constexpr int WF = NCOL / 32;               // n-frags per wave
    constexpr int PST = 4 * NCF * 512;          // plane stride in wfrag
    constexpr int WSEG = 2 * PST;               // per-segment stride
    constexpr int RS = NCOL * 4 + 16;           // epilogue LDS row stride
    constexpr int EPB = 64 * RS;
    constexpr int SMEM_BYTES = (EPB > 32768) ? EPB : 32768;
    __shared__ __align__(16) char smem[SMEM_BYTES];
    char (*lds)[16384] = (char(*)[16384])smem;

    const int tid = threadIdx.x;
    const int wv = tid >> 6, lane = tid & 63, l15 = lane & 15, lg = lane >> 4;
    const int rowgrp = wv >> 1, colgrp = wv & 1;
    const int row0 = blockIdx.x * 64;
    const char* As[4] = {A0, A1, A2, A3};

    f32x4 acc[2][WF];
#pragma unroll
    for (int xf = 0; xf < 2; ++xf)
#pragma unroll
        for (int wf = 0; wf < WF; ++wf) acc[xf][wf] = (f32x4){0.f, 0.f, 0.f, 0.f};

    uint4 regs[4];

    auto LOADSTAGE = [&](int ch) {
        int seg = ch >> 1, kc = (ch & 1) * 64;
        const char* __restrict__ A = As[seg];
        if (SPLIT0 && seg == 0) {
#pragma unroll
            for (int i = 0; i < 4; ++i) {
                int s = tid + i * 256;             // 1024: 64r x 16 c4
                int r = s >> 4, c4 = s & 15;
                int gr = row0 + r;
                float4 v = make_float4(0.f, 0.f, 0.f, 0.f);
                if (gr < M) v = *(const float4*)(A + (size_t)gr * 512 + kc * 4 + c4 * 16);
                regs[i] = *(uint4*)&v;
            }
        } else {
#pragma unroll
            for (int i = 0; i < 4; ++i) {
                int s = tid + i * 256;             // 1024: 2p x 64r x 8 c16
                int p = s >> 9, r = (s >> 3) & 63, c16 = s & 7;
                int gr = row0 + r;
                uint4 v = make_uint4(0u, 0u, 0u, 0u);
                if (gr < M)
                    v = *(const uint4*)(A + (size_t)gr * 512 + p * 256 + kc * 2 + c16 * 16);
                regs[i] = v;
            }
        }
    };

    auto WRITESTAGE = [&](int ch, int buf) {
        char* L = lds[buf];
        if (SPLIT0 && (ch >> 1) == 0) {
#pragma unroll
            for (int i = 0; i < 4; ++i) {
                int s = tid + i * 256;
                int r = s >> 4, c4 = s & 15;
                uint2 hh, ll;
                float4 v = *(float4*)&regs[i];
                split4(v, hh, ll);
                int byte = (r * 128 + c4 * 8) ^ ((r & 7) << 4);
                *(uint2*)(L + byte) = hh;
                *(uint2*)(L + 8192 + byte) = ll;
            }
        } else {
#pragma unroll
            for (int i = 0; i < 4; ++i) {
                int s = tid + i * 256;
                int p = s >> 9, r = (s >> 3) & 63, c16 = s & 7;
                int byte = p * 8192 + ((r * 128 + c16 * 16) ^ ((r & 7) << 4));
                *(uint4*)(L + byte) = regs[i];
            }
        }
    };

    auto COMPUTE = [&](int ch, int buf) {
        int seg = ch >> 1, half = ch & 1;
        const ushort_t* __restrict__ ws = wfrag + (size_t)seg * WSEG;
        const char* L = lds[buf];
#pragma unroll
        for (int kk = 0; kk < 2; ++kk) {
            int ks = half * 2 + kk;
            bf16x8 xh[2], xl[2];
#pragma unroll
            for (int xf = 0; xf < 2; ++xf) {
                int r = rowgrp * 32 + xf * 16 + l15;
                int byte = (r * 128 + kk * 64 + lg * 16) ^ ((r & 7) << 4);
                xh[xf] = *(const bf16x8*)(L + byte);
                xl[xf] = *(const bf16x8*)(L + 8192 + byte);
            }
            bf16x8 wh[WF], wl[WF];
#pragma unroll
            for (int wf = 0; wf < WF; ++wf) {
                size_t off = (((size_t)ks * NCF + colgrp * WF + wf) * 64 + lane) * 8;
                wh[wf] = *(const bf16x8*)(ws + off);
                wl[wf] = *(const bf16x8*)(ws + PST + off);
            }
#pragma unroll
            for (int xf = 0; xf < 2; ++xf)
#pragma unroll
                for (int wf = 0; wf < WF; ++wf) {
                    acc[xf][wf] = __builtin_amdgcn_mfma_f32_16x16x32_bf16(
                        wh[wf], xh[xf], acc[xf][wf], 0, 0, 0);
                    acc[xf][wf] = __builtin_amdgcn_mfma_f32_16x16x32_bf16(
                        wl[wf], xh[xf], acc[xf][wf], 0, 0, 0);
                    acc[xf][wf] = __builtin_amdgcn_mfma_f32_16x16x32_bf16(
                        wh[wf], xl[xf], acc[xf][wf], 0, 0, 0);
                }
        }
    };

    constexpr int CH = 2 * NSEG;
    LOADSTAGE(0);
    WRITESTAGE(0, 0);
    __syncthreads();
    for (int ch = 0; ch < CH; ++ch) {
        if (ch + 1 < CH) LOADSTAGE(ch + 1);
        COMPUTE(ch, ch & 1);
        __syncthreads();
        if (ch + 1 < CH) WRITESTAGE(ch + 1, (ch + 1) & 1);
        __syncthreads();
    }
    // staging LDS dead -> reuse as epilogue tile

    // ---- stage acc tile (+bias) into LDS as full f32 rows ----
    {
        float4 bv[WF];
#pragma unroll
        for (int wf = 0; wf < WF; ++wf) {
            int col = colgrp * (NCOL / 2) + wf * 16 + lg * 4;
            bv[wf] = bias ? *(const float4*)(bias + col)
                          : make_float4(0.f, 0.f, 0.f, 0.f);
        }
#pragma unroll
        for (int xf = 0; xf < 2; ++xf) {
            int r = rowgrp * 32 + xf * 16 + l15;
#pragma unroll
            for (int wf = 0; wf < WF; ++wf) {
                int col = colgrp * (NCOL / 2) + wf * 16 + lg * 4;
                float4 o;
                o.x = acc[xf][wf][0] + bv[wf].x;
                o.y = acc[xf][wf][1] + bv[wf].y;
                o.z = acc[xf][wf][2] + bv[wf].z;
                o.w = acc[xf][wf][3] + bv[wf].w;
                *(float4*)(smem + r * RS + col * 4) = o;
            }
        }
    }
    __syncthreads();

    if (FUSE >= 1 && FUSE <= 3) {
        // LN across the row (4 threads/row), activation, write BACK to LDS
        constexpr int CPT = NCOL / 4;          // cols per thread
        int r = tid >> 2, seg = tid & 3;
        char* rp = smem + r * RS + seg * CPT * 4;
        float s = 0.f, sq = 0.f;
        float4 vv[CPT / 4];
#pragma unroll
        for (int j = 0; j < CPT / 4; ++j) {
            float4 v = *(const float4*)(rp + j * 16);
            vv[j] = v;
            s += (v.x + v.y) + (v.z + v.w);
            sq += (v.x * v.x + v.y * v.y) + (v.z * v.z + v.w * v.w);
        }
        s += __shfl_xor(s, 1, 64); sq += __shfl_xor(sq, 1, 64);
        s += __shfl_xor(s, 2, 64); sq += __shfl_xor(sq, 2, 64);
        float mu = s * (1.f / NCOL);
        float var = sq * (1.f / NCOL) - mu * mu;
        float rstd = rsqrtf(var + 1e-5f);
#pragma unroll
        for (int j = 0; j < CPT / 4; ++j) {
            int c0 = seg * CPT + j * 4;
            float4 v = vv[j];
            float4 gg = *(const float4*)(lng + c0);
            float4 bb = *(const float4*)(lnb + c0);
            float y0 = (v.x - mu) * rstd * gg.x + bb.x;
            float y1 = (v.y - mu) * rstd * gg.y + bb.y;
            float y2 = (v.z - mu) * rstd * gg.z + bb.z;
            float y3 = (v.w - mu) * rstd * gg.w + bb.w;
            if (FUSE == 1) {
                y0 = fmaxf(y0, 0.f); y1 = fmaxf(y1, 0.f);
                y2 = fmaxf(y2, 0.f); y3 = fmaxf(y3, 0.f);
            } else {
                y0 = 0.5f * y0 * (1.f + erff(y0 * 0.70710678118654752f));
                y1 = 0.5f * y1 * (1.f + erff(y1 * 0.70710678118654752f));
                y2 = 0.5f * y2 * (1.f + erff(y2 * 0.70710678118654752f));
                y3 = 0.5f * y3 * (1.f + erff(y3 * 0.70710678118654752f));
            }
            vv[j] = make_float4(y0, y1, y2, y3);
        }
        __syncthreads();   // all reads of the f32 tile done before overwrite
        if (FUSE == 3) {
#pragma unroll
            for (int j = 0; j < CPT / 4; ++j) *(float4*)(rp + j * 16) = vv[j];
        } else {
            // plane layout within row: [hi 256B][lo 256B] at base r*RS
#pragma unroll
            for (int j = 0; j < CPT / 4; ++j) {
                int c0 = seg * CPT + j * 4;
                uint2 hw, lw;
                split4(vv[j], hw, lw);
                *(uint2*)(smem + r * RS + 2 * c0) = hw;
                *(uint2*)(smem + r * RS + 256 + 2 * c0) = lw;
            }
        }
        __syncthreads();
    }

    // ---- contiguous copy-out: full rows, line-complete per instruction ----
    if (FUSE == 4) {
        // f32 tile -> bf16 rows (256B), NCOL must be 128
        constexpr int SL = 64 * 16;            // uint4 slots
#pragma unroll
        for (int i = 0; i < SL / 256; ++i) {
            int slot = tid + i * 256;
            int rr = slot >> 4, c16 = slot & 15;
            int gr = row0 + rr;
            if (gr < M) {
                float4 a = *(const float4*)(smem + rr * RS + c16 * 32);
                float4 b = *(const float4*)(smem + rr * RS + c16 * 32 + 16);
                uint4 o;
                o.x = (unsigned)bf16rne(a.x) | ((unsigned)bf16rne(a.y) << 16);
                o.y = (unsigned)bf16rne(a.z) | ((unsigned)bf16rne(a.w) << 16);
                o.z = (unsigned)bf16rne(b.x) | ((unsigned)bf16rne(b.y) << 16);
                o.w = (unsigned)bf16rne(b.z) | ((unsigned)bf16rne(b.w) << 16);
                *(uint4*)((char*)Yv + (size_t)gr * 256 + c16 * 16) = o;
            }
        }
    } else {
        constexpr int OUTB = (FUSE == 0 || FUSE == 3) ? NCOL * 4 : 512;
        constexpr int RP = OUTB / 16;                        // uint4 per row
        constexpr int SL = 64 * RP;
#pragma unroll
        for (int i = 0; i < SL / 256; ++i) {
            int slot = tid + i * 256;
            int rr = slot / RP, c16 = slot % RP;
            int gr = row0 + rr;
            if (gr < M)
                *(uint4*)((char*)Yv + (size_t)gr * OUTB + c16 * 16) =
                    *(const uint4*)(smem + rr * RS + c16 * 16);
        }
    }
}

// ============================== CSR build ((dst,rel)-sorted) ===============
__global__ __launch_bounds__(256) void hist3_kernel(const int* __restrict__ edst,
                                                    const int* __restrict__ etype,
                                                    int* __restrict__ deg3, int E) {
    int e = blockIdx.x * 256 + threadIdx.x;
    if (e < E) atomicAdd(&deg3[edst[e] * 3 + etype[e]], 1);
}

__global__ __launch_bounds__(256) void degtot_kernel(const int* __restrict__ deg3,
                                                     int* __restrict__ degtot, int N) {
    int n = blockIdx.x * 256 + threadIdx.x;
    if (n < N) degtot[n] = deg3[n * 3] + deg3[n * 3 + 1] + deg3[n * 3 + 2];
}

__global__ __launch_bounds__(256) void scan_block(const int* __restrict__ in,
                                                  int* __restrict__ out,
                                                  int* __restrict__ sums, int n) {
    __shared__ int s[256];
    int g = blockIdx.x * 256 + threadIdx.x;
    int v = (g < n) ? in[g] : 0;
    s[threadIdx.x] = v;
    __syncthreads();
    int acc = v;
    for (int off = 1; off < 256; off <<= 1) {
        int t = (threadIdx.x >= off) ? s[threadIdx.x - off] : 0;
        __syncthreads();
        acc += t;
        s[threadIdx.x] = acc;
        __syncthreads();
    }
    if (g < n) out[g] = acc - v;
    if (threadIdx.x == 255 && sums) sums[blockIdx.x] = acc;
}

__global__ __launch_bounds__(256) void scan_add(int* __restrict__ out,
                                                const int* __restrict__ topex,
                                                int n, int total) {
    int g = blockIdx.x * 256 + threadIdx.x;
    if (g < n) out[g] += topex[blockIdx.x];
    if (g == 0) out[n] = total;
}

__global__ __launch_bounds__(256) void ranges_kernel(
    const int* __restrict__ rowptr, const int* __restrict__ deg3,
    int4* __restrict__ ranges, int* __restrict__ cursor3, int N) {
    int n = blockIdx.x * 256 + threadIdx.x;
    if (n >= N) return;
    int b = rowptr[n];
    int d0 = deg3[n * 3], d1 = deg3[n * 3 + 1];
    int4 r;
    r.x = b; r.y = b + d0; r.z = b + d0 + d1; r.w = rowptr[n + 1];
    ranges[n] = r;
    cursor3[n * 3] = r.x; cursor3[n * 3 + 1] = r.y; cursor3[n * 3 + 2] = r.z;
}

__global__ __launch_bounds__(256) void fill3_kernel(
    const int* __restrict__ esrc, const int* __restrict__ edst,
    const int* __restrict__ etype, int* __restrict__ cursor3,
    int* __restrict__ colidx, int E) {
    int e = blockIdx.x * 256 + threadIdx.x;
    if (e >= E) return;
    int pos = atomicAdd(&cursor3[edst[e] * 3 + etype[e]], 1);
    colidx[pos] = esrc[e];
}

// ========== fused add-gather from bf16 x: S_r = A_r x -> planes ============
__device__ __forceinline__ float4 gather_sum_bf(const ushort_t* __restrict__ XH,
                                                const int* __restrict__ colidx,
                                                int beg, int end, int l) {
    float4 a = make_float4(0.f, 0.f, 0.f, 0.f);
    int e = beg;
    for (; e + 4 <= end; e += 4) {
        int s0 = colidx[e], s1 = colidx[e + 1];
        int s2 = colidx[e + 2], s3 = colidx[e + 3];
        uint2 u0 = *(const uint2*)(XH + (size_t)s0 * 128 + l * 4);
        uint2 u1 = *(const uint2*)(XH + (size_t)s1 * 128 + l * 4);
        uint2 u2 = *(const uint2*)(XH + (size_t)s2 * 128 + l * 4);
        uint2 u3 = *(const uint2*)(XH + (size_t)s3 * 128 + l * 4);
        float4 v0 = unpack_bf4(u0), v1 = unpack_bf4(u1);
        float4 v2 = unpack_bf4(u2), v3 = unpack_bf4(u3);
        a.x += (v0.x + v1.x) + (v2.x + v3.x);
        a.y += (v0.y + v1.y) + (v2.y + v3.y);
        a.z += (v0.z + v1.z) + (v2.z + v3.z);
        a.w += (v0.w + v1.w) + (v2.w + v3.w);
    }
    for (; e < end; ++e) {
        float4 v = unpack_bf4(*(const uint2*)(XH + (size_t)colidx[e] * 128 + l * 4));
        a.x += v.x; a.y += v.y; a.z += v.z; a.w += v.w;
    }
    return a;
}

__device__ __forceinline__ void store_plane4(char* rowbase, int l, float4 a) {
    uint2 h, lo;
    split4(a, h, lo);
    *(uint2*)(rowbase + 8 * l) = h;
    *(uint2*)(rowbase + 256 + 8 * l) = lo;
}

__global__ __launch_bounds__(256) void agg3_add(
    const ushort_t* __restrict__ xh, const int4* __restrict__ ranges,
    const int* __restrict__ colidx, char* __restrict__ S0,
    char* __restrict__ S1, char* __restrict__ S2, int N) {
    int node = blockIdx.x * 8 + (threadIdx.x >> 5);
    int l = threadIdx.x & 31;
    if (node >= N) return;
    int4 rg = ranges[node];
    float4 a0 = gather_sum_bf(xh, colidx, rg.x, rg.y, l);
    float4 a1 = gather_sum_bf(xh, colidx, rg.y, rg.z, l);
    float4 a2 = gather_sum_bf(xh, colidx, rg.z, rg.w, l);
    store_plane4(S0 + (size_t)node * 512, l, a0);
    store_plane4(S1 + (size_t)node * 512, l, a1);
    store_plane4(S2 + (size_t)node * 512, l, a2);
}

// ======= fused: acc + sum_r max-gather(H_r bf16) -> LN -> relu+resid =======
__device__ __forceinline__ float4 gather_max_bf(const ushort_t* __restrict__ H,
                                                const int* __restrict__ colidx,
                                                int beg, int end, int l) {
    float4 m = make_float4(-INFINITY, -INFINITY, -INFINITY, -INFINITY);
    int e = beg;
    for (; e + 4 <= end; e += 4) {
        int s0 = colidx[e], s1 = colidx[e + 1];
        int s2 = colidx[e + 2], s3 = colidx[e + 3];
        float4 v0 = unpack_bf4(*(const uint2*)(H + (size_t)s0 * 128 + l * 4));
        float4 v1 = unpack_bf4(*(const uint2*)(H + (size_t)s1 * 128 + l * 4));
        float4 v2 = unpack_bf4(*(const uint2*)(H + (size_t)s2 * 128 + l * 4));
        float4 v3 = unpack_bf4(*(const uint2*)(H + (size_t)s3 * 128 + l * 4));
        m.x = fmaxf(m.x, fmaxf(fmaxf(v0.x, v1.x), fmaxf(v2.x, v3.x)));
        m.y = fmaxf(m.y, fmaxf(fmaxf(v0.y, v1.y), fmaxf(v2.y, v3.y)));
        m.z = fmaxf(m.z, fmaxf(fmaxf(v0.z, v1.z), fmaxf(v2.z, v3.z)));
        m.w = fmaxf(m.w, fmaxf(fmaxf(v0.w, v1.w), fmaxf(v2.w, v3.w)));
    }
    for (; e < end; ++e) {
        float4 v = unpack_bf4(*(const uint2*)(H + (size_t)colidx[e] * 128 + l * 4));
        m.x = fmaxf(m.x, v.x); m.y = fmaxf(m.y, v.y);
        m.z = fmaxf(m.z, v.z); m.w = fmaxf(m.w, v.w);
    }
    // empty/none -> 0 contribution
    m.x = (m.x > -3e38f) ? m.x : 0.f;
    m.y = (m.y > -3e38f) ? m.y : 0.f;
    m.z = (m.z > -3e38f) ? m.z : 0.f;
    m.w = (m.w > -3e38f) ? m.w : 0.f;
    return m;
}

__global__ __launch_bounds__(256) void maxagg_ln(
    const ushort_t* __restrict__ H0, const ushort_t* __restrict__ H1,
    const ushort_t* __restrict__ H2, const int4* __restrict__ ranges,
    const int* __restrict__ colidx, const float* __restrict__ acc,
    const char* __restrict__ residP, const float* __restrict__ g,
    const float* __restrict__ b, char* __restrict__ outP, int N) {
    int node = blockIdx.x * 8 + (threadIdx.x >> 5);
    int l = threadIdx.x & 31;
    if (node >= N) return;
    int4 rg = ranges[node];
    float4 m0 = gather_max_bf(H0, colidx, rg.x, rg.y, l);
    float4 m1 = gather_max_bf(H1, colidx, rg.y, rg.z, l);
    float4 m2 = gather_max_bf(H2, colidx, rg.z, rg.w, l);
    float4 a = *(const float4*)(acc + (size_t)node * 128 + l * 4);
    a.x += m0.x + m1.x + m2.x;
    a.y += m0.y + m1.y + m2.y;
    a.z += m0.z + m1.z + m2.z;
    a.w += m0.w + m1.w + m2.w;
    // LN across 32 lanes
    float s = (a.x + a.y) + (a.z + a.w);
    float sq = (a.x * a.x + a.y * a.y) + (a.z * a.z + a.w * a.w);
#pragma unroll
    for (int off = 16; off; off >>= 1) {
        s += __shfl_xor(s, off, 64);
        sq += __shfl_xor(sq, off, 64);
    }
    float mu = s * (1.f / 128.f);
    float var = sq * (1.f / 128.f) - mu * mu;
    float rstd = rsqrtf(var + 1e-5f);
    float4 gg = *(const float4*)(g + l * 4);
    float4 bb = *(const float4*)(b + l * 4);
    float y0 = fmaxf((a.x - mu) * rstd * gg.x + bb.x, 0.f);
    float y1 = fmaxf((a.y - mu) * rstd * gg.y + bb.y, 0.f);
    float y2 = fmaxf((a.z - mu) * rstd * gg.z + bb.z, 0.f);
    float y3 = fmaxf((a.w - mu) * rstd * gg.w + bb.w, 0.f);
    const char* rb = residP + (size_t)node * 512;
    uint2 rh = *(const uint2*)(rb + 8 * l);
    uint2 rl = *(const uint2*)(rb + 256 + 8 * l);
    float4 rhi = unpack_bf4(rh), rlo = unpack_bf4(rl);
    y0 += 0.2f * (rhi.x + rlo.x);
    y1 += 0.2f * (rhi.y + rlo.y);
    y2 += 0.2f * (rhi.z + rlo.z);
    y3 += 0.2f * (rhi.w + rlo.w);
    store_plane4((char*)outP + (size_t)node * 512, l, make_float4(y0, y1, y2, y3));
}

// ====== f32 GEMM  M x 64 @ 64 x 40 + bias + log_softmax -> out =============
__global__ __launch_bounds__(256) void gemm40_lsm(const float* __restrict__ X,
                                                  const float* __restrict__ W,
                                                  const float* __restrict__ bias,
                                                  float* __restrict__ Y, int M) {
    __shared__ float Xs[64][65];
    __shared__ float Ws[64 * 40];
    __shared__ float Ys[64][41];
    __shared__ float mx_[64], ls_[64];
    const int tid = threadIdx.x;
    const int row0 = blockIdx.x * 64;
    for (int i = tid; i < 64 * 40; i += 256) Ws[i] = W[i];
#pragma unroll
    for (int i = 0; i < 4; ++i) {
        int slot = tid + i * 256;
        int r = slot >> 4, c4 = slot & 15;
        float4 v = make_float4(0.f, 0.f, 0.f, 0.f);
        if (row0 + r < M) v = *(const float4*)(X + (size_t)(row0 + r) * 64 + c4 * 4);
        Xs[r][c4 * 4 + 0] = v.x; Xs[r][c4 * 4 + 1] = v.y;
        Xs[r][c4 * 4 + 2] = v.z; Xs[r][c4 * 4 + 3] = v.w;
    }
    __syncthreads();
    const int row = tid >> 2, cg = (tid & 3) * 10;
    float acc[10];
#pragma unroll
    for (int j = 0; j < 10; ++j) acc[j] = 0.f;
#pragma unroll 8
    for (int k = 0; k < 64; ++k) {
        float xv = Xs[row][k];
#pragma unroll
        for (int j = 0; j < 10; ++j) acc[j] = fmaf(xv, Ws[k * 40 + cg + j], acc[j]);
    }
#pragma unroll
    for (int j = 0; j < 10; ++j) Ys[row][cg + j] = acc[j] + bias[cg + j];
    __syncthreads();
    if (tid < 64) {
        float mx = -INFINITY;
#pragma unroll 8
        for (int c = 0; c < 40; ++c) mx = fmaxf(mx, Ys[tid][c]);
        float sum = 0.f;
#pragma unroll 8
        for (int c = 0; c < 40; ++c) sum += __expf(Ys[tid][c] - mx);
        mx_[tid] = mx;
        ls_[tid] = logf(sum);
    }
    __syncthreads();
#pragma unroll
    for (int i = 0; i < 10; ++i) {
        int slot = tid + i * 256;
        int r = slot / 40, c = slot % 40;
        int gr = row0 + r;
        if (gr < M) Y[(size_t)gr * 40 + c] = Ys[r][c] - mx_[r] - ls_[r];
    }
}

// ===========================================================================
extern "C" void kernel_launch(void* const* d_in, const int* in_sizes, int n_in,
                              void* d_out, int out_size, void* d_ws, size_t ws_size,
                              hipStream_t stream) {
    const float* x       = (const float*)d_in[0];
    const int*   eidx    = (const int*)d_in[1];
    const int*   etype   = (const int*)d_in[2];
    const float* w1_rel  = (const float*)d_in[3];
    const float* w1_root = (const float*)d_in[4];
    const float* b1      = (const float*)d_in[5];
    const float* ln1_g   = (const float*)d_in[6];
    const float* ln1_b   = (const float*)d_in[7];
    const float* w2_rel  = (const float*)d_in[8];
    const float* w2_root = (const float*)d_in[9];
    const float* b2      = (const float*)d_in[10];
    const float* ln2_g   = (const float*)d_in[11];
    const float* ln2_b   = (const float*)d_in[12];
    const float* cw1     = (const float*)d_in[13];
    const float* cb1     = (const float*)d_in[14];
    const float* cln1_g  = (const float*)d_in[15];
    const float* cln1_b  = (const float*)d_in[16];
    const float* cw2     = (const float*)d_in[17];
    const float* cb2     = (const float*)d_in[18];
    const float* cln2_g  = (const float*)d_in[19];
    const float* cln2_b  = (const float*)d_in[20];
    const float* cw3     = (const float*)d_in[21];
    const float* cb3     = (const float*)d_in[22];

    const int N = in_sizes[0] / 128;   // 50000
    const int E = in_sizes[1] / 2;     // 600000
    const int* esrc = eidx;
    const int* edst = eidx + E;

    const size_t NFB = (size_t)N * 512;     // one [N,128]-f32-equiv, bytes
    char* B0 = (char*)d_ws;
    char* B1 = B0 + NFB;
    char* B2 = B1 + NFB;
    char* B3 = B2 + NFB;   // META: CSR + wfrag + xh/H2

    int* rowptr  = (int*)B3;                      // N+1
    int* degtot  = rowptr + (N + 1);              // N
    int* deg3    = degtot + N;                    // 3N
    int* cursor3 = deg3 + 3 * N;                  // 3N
    int* bsums   = cursor3 + 3 * N;               // 256
    int* btop    = bsums + 256;                   // 256
    int4* ranges = (int4*)(((uintptr_t)(btop + 256) + 15) & ~(uintptr_t)15);
    int* colidx  = (int*)(ranges + N);            // E
    ushort_t* wfb = (ushort_t*)(((uintptr_t)(colidx + E) + 255) & ~(uintptr_t)255);
    // 10 slots x 32768 ushorts
    auto WSLOT = [&](int i) { return wfb + (size_t)i * 32768; };
    // xh: bf16 [N,128], reused later as H2
    ushort_t* xh = (ushort_t*)(((uintptr_t)(wfb + 10 * 32768) + 255) & ~(uintptr_t)255);
    ushort_t* H0 = (ushort_t*)B2;
    ushort_t* H1 = (ushort_t*)(B2 + (size_t)N * 256);
    ushort_t* H2 = xh;

    const dim3 blk(256);
    const int gGemm = (N + 63) / 64;
    const int gAgg  = (N + 7) / 8;
    const int gEdge = (E + 255) / 256;
    const int gNode = (N + 255) / 256;
    const int nScanB = (N + 255) / 256;
    const int gX2  = (N * 32 + 255) / 256;

    // ---------------- CSR build ----------------
    hipMemsetAsync(deg3, 0, (size_t)3 * N * sizeof(int), stream);
    hist3_kernel<<<gEdge, blk, 0, stream>>>(edst, etype, deg3, E);
    degtot_kernel<<<gNode, blk, 0, stream>>>(deg3, degtot, N);
    scan_block<<<nScanB, blk, 0, stream>>>(degtot, rowptr, bsums, N);
    scan_block<<<1, blk, 0, stream>>>(bsums, btop, nullptr, nScanB);
    scan_add<<<nScanB, blk, 0, stream>>>(rowptr, btop, N, E);
    ranges_kernel<<<gNode, blk, 0, stream>>>(rowptr, deg3, ranges, cursor3, N);
    fill3_kernel<<<gEdge, blk, 0, stream>>>(esrc, edst, etype, cursor3, colidx, E);

    // ---------------- weights + x conversion ----------------
    convert_all<<<76, blk, 0, stream>>>(w1_root, w1_rel, w2_root, w2_rel,
                                        cw1, cw2, wfb);
    x2bf<<<gX2, blk, 0, stream>>>(x, xh, N * 32);

    // ---------------- conv1 (add): aggregate-then-transform ----------------
    agg3_add<<<gAgg, blk, 0, stream>>>(xh, ranges, colidx, B0, B1, B2, N);
    gemm_planes<128, 4, true, 1><<<gGemm, blk, 0, stream>>>(
        (const char*)x, B0, B1, B2, WSLOT(0), b1, ln1_g, ln1_b, B0, N);
    // x1 planes now in B0

    // ---------------- conv2 (max) ----------------
    gemm_planes<128, 1, false, 0><<<gGemm, blk, 0, stream>>>(
        B0, B0, B0, B0, WSLOT(4), b2, nullptr, nullptr, B1, N);   // acc f32 -> B1
    gemm_planes<128, 1, false, 4><<<gGemm, blk, 0, stream>>>(
        B0, B0, B0, B0, WSLOT(5), nullptr, nullptr, nullptr, H0, N);
    gemm_planes<128, 1, false, 4><<<gGemm, blk, 0, stream>>>(
        B0, B0, B0, B0, WSLOT(6), nullptr, nullptr, nullptr, H1, N);
    gemm_planes<128, 1, false, 4><<<gGemm, blk, 0, stream>>>(
        B0, B0, B0, B0, WSLOT(7), nullptr, nullptr, nullptr, H2, N);
    // h2 = relu(LN(acc + sum_r max_r)) + 0.2*x1 -> planes into B1 (in-place)
    maxagg_ln<<<gAgg, blk, 0, stream>>>(H0, H1, H2, ranges, colidx, (float*)B1,
                                        B0, ln2_g, ln2_b, B1, N);

    // ---------------- classifier ----------------
    gemm_planes<128, 1, false, 2><<<gGemm, blk, 0, stream>>>(
        B1, B1, B1, B1, WSLOT(8), cb1, cln1_g, cln1_b, B0, N);    // planes -> B0
    gemm_planes<64, 1, false, 3><<<gGemm, blk, 0, stream>>>(
        B0, B0, B0, B0, WSLOT(9), cb2, cln2_g, cln2_b, B2, N);    // f32[N,64] -> B2
    gemm40_lsm<<<gGemm, blk, 0, stream>>>((float*)B2, cw3, cb3, (float*)d_out, N);
}

// Round 9
// 274.515 us; speedup vs baseline: 8.3500x; 1.1358x over previous
//
#include <hip/hip_runtime.h>
#include <hip/hip_bf16.h>
#include <math.h>

// ---------------------------------------------------------------------------
// RGCN forward. ALL activations as single-plane bf16 rows (256B/row);
// weights split-bf16 (hi/lo) in MFMA fragment order -> 2 MFMA per frag.
// conv1: x->bf16, fused add-gather, one K=512 GEMM + LN1 + relu.
// conv2: ONE multi-head GEMM (x1 staged once -> acc f32 + 3 bf16 H),
//        then ONE fused maxagg+LN2+relu+resid pass.
// classifier: gemm+LN+gelu x2, gemm40+log_softmax fused.
// All global stores are full-line contiguous (LDS-staged epilogues).
// ---------------------------------------------------------------------------

typedef __attribute__((ext_vector_type(8))) short bf16x8;
typedef __attribute__((ext_vector_type(4))) float f32x4;
typedef unsigned short ushort_t;

__device__ __forceinline__ ushort_t bf16rne(float v) {
    unsigned u = __float_as_uint(v);
    return (ushort_t)((u + 0x7FFFu + ((u >> 16) & 1u)) >> 16);
}

__device__ __forceinline__ void split_bf16(float v, ushort_t& h, ushort_t& l) {
    ushort_t hu = bf16rne(v);
    float hf = __uint_as_float((unsigned)hu << 16);
    h = hu;
    l = bf16rne(v - hf);
}

__device__ __forceinline__ float bf2f(unsigned u16) {
    return __uint_as_float(u16 << 16);
}

__device__ __forceinline__ float4 unpack_bf4(uint2 u) {
    return make_float4(bf2f(u.x & 0xFFFFu), bf2f(u.x >> 16),
                       bf2f(u.y & 0xFFFFu), bf2f(u.y >> 16));
}

__device__ __forceinline__ uint2 pack_bf4(float4 v) {
    uint2 o;
    o.x = (unsigned)bf16rne(v.x) | ((unsigned)bf16rne(v.y) << 16);
    o.y = (unsigned)bf16rne(v.z) | ((unsigned)bf16rne(v.w) << 16);
    return o;
}

// ================= convert ALL weights to fragment order (1 launch) ========
// frag layout (ushort): [plane][ks 0..3][cf][lane 0..63][8], slot=32768 ush.
__device__ __forceinline__ void conv_body128(const float* __restrict__ W,
                                             ushort_t* __restrict__ out,
                                             int idx) {
    constexpr int NCF = 8;
    constexpr size_t PST = (size_t)4 * NCF * 512;
    int l = idx & 63;
    int cf = (idx >> 6) & 7;
    int ks = idx >> 9;
    int col = cf * 16 + (l & 15);
    int k0 = ks * 32 + (l >> 4) * 8;
    size_t base = (((size_t)ks * NCF + cf) * 64 + l) * 8;
#pragma unroll
    for (int j = 0; j < 8; ++j) {
        ushort_t h, lo_;
        split_bf16(W[(size_t)(k0 + j) * 128 + col], h, lo_);
        out[base + j] = h;
        out[PST + base + j] = lo_;
    }
}

__global__ __launch_bounds__(256) void convert_all(
    const float* __restrict__ w1_root, const float* __restrict__ w1_rel,
    const float* __restrict__ w2_root, const float* __restrict__ w2_rel,
    const float* __restrict__ cw1, const float* __restrict__ cw2,
    ushort_t* __restrict__ wfb) {
    int b = blockIdx.x;
    if (b < 72) {
        const float* src;
        int slot;
        if (b < 8)       { slot = 0;              src = w1_root; }
        else if (b < 32) { int r = (b - 8) >> 3;  slot = 1 + r; src = w1_rel + (size_t)r * 16384; }
        else if (b < 40) { slot = 4;              src = w2_root; }
        else if (b < 64) { int r = (b - 40) >> 3; slot = 5 + r; src = w2_rel + (size_t)r * 16384; }
        else             { slot = 8;              src = cw1; }
        int lb = (b < 8) ? b : (b < 32) ? ((b - 8) & 7) : (b < 40) ? (b - 32)
               : (b < 64) ? ((b - 40) & 7) : (b - 64);
        conv_body128(src, wfb + (size_t)slot * 32768, lb * 256 + threadIdx.x);
    } else {
        // slot 9: cw2 K=128 x NCOL=64
        constexpr int NCF = 4;
        constexpr size_t PST = (size_t)4 * NCF * 512;
        int idx = (b - 72) * 256 + threadIdx.x;   // 4096 items
        ushort_t* out = wfb + (size_t)9 * 32768;
        int l = idx & 63;
        int cf = (idx >> 6) & 3;
        int ks = idx >> 8;
        int col = cf * 16 + (l & 15);
        int k0 = ks * 32 + (l >> 4) * 8;
        size_t base = (((size_t)ks * NCF + cf) * 64 + l) * 8;
#pragma unroll
        for (int j = 0; j < 8; ++j) {
            ushort_t h, lo_;
            split_bf16(cw2[(size_t)(k0 + j) * 64 + col], h, lo_);
            out[base + j] = h;
            out[PST + base + j] = lo_;
        }
    }
}

// ===================== x (f32) -> compact bf16 copy ========================
__global__ __launch_bounds__(256) void x2bf(const float* __restrict__ x,
                                            ushort_t* __restrict__ xh, int n4) {
    int g = blockIdx.x * 256 + threadIdx.x;
    if (g >= n4) return;
    float4 v = ((const float4*)x)[g];
    ((uint2*)xh)[g] = pack_bf4(v);
}

// ============= GEMM  Y[M,NCOL] = sum_s A_s[M,128] @ W_s + bias =============
// A_s: bf16 rows 256B. 256 thr / 4 waves (2x2), 64 rows/block.
// FUSE: 0 = bias, f32 out   1 = LN+relu, bf16 out   2 = LN+gelu, bf16 out
//       3 = LN+gelu, f32 out   4 = bias, bf16 out
template <int NCOL, int NSEG, int FUSE>
__global__ __launch_bounds__(256, 3) void gemm_bf(
    const ushort_t* __restrict__ A0, const ushort_t* __restrict__ A1,
    const ushort_t* __restrict__ A2, const ushort_t* __restrict__ A3,
    const ushort_t* __restrict__ wfrag, const float* __restrict__ bias,
    const float* __restrict__ lng, const float* __restrict__ lnb,
    void* __restrict__ Yv, int M) {
    constexpr int NCF = NCOL / 16;
    constexpr int WF = NCOL / 32;
    constexpr int PST = 4 * NCF * 512;
    constexpr int WSEG = 2 * PST;
    constexpr int RS = NCOL * 4 + 16;
    constexpr int EPB = 64 * RS;
    constexpr int SMEM_BYTES = (EPB > 16384) ? EPB : 16384;
    __shared__ __align__(16) char smem[SMEM_BYTES];
    char (*lds)[8192] = (char(*)[8192])smem;

    const int tid = threadIdx.x;
    const int wv = tid >> 6, lane = tid & 63, l15 = lane & 15, lg = lane >> 4;
    const int rowgrp = wv >> 1, colgrp = wv & 1;
    const int row0 = blockIdx.x * 64;
    const ushort_t* As[4] = {A0, A1, A2, A3};

    f32x4 acc[2][WF];
#pragma unroll
    for (int xf = 0; xf < 2; ++xf)
#pragma unroll
        for (int wf = 0; wf < WF; ++wf) acc[xf][wf] = (f32x4){0.f, 0.f, 0.f, 0.f};

    uint4 regs[2];

    auto LOADSTAGE = [&](int ch) {
        const ushort_t* __restrict__ A = As[ch >> 1];
        int kcb = (ch & 1) * 128;            // byte offset of k-chunk in row
#pragma unroll
        for (int i = 0; i < 2; ++i) {
            int s = tid + i * 256;           // 512 slots: 64r x 8 c16
            int r = s >> 3, c16 = s & 7;
            int gr = row0 + r;
            uint4 v = make_uint4(0u, 0u, 0u, 0u);
            if (gr < M)
                v = *(const uint4*)((const char*)A + (size_t)gr * 256 + kcb + c16 * 16);
            regs[i] = v;
        }
    };

    auto WRITESTAGE = [&](int buf) {
        char* L = lds[buf];
#pragma unroll
        for (int i = 0; i < 2; ++i) {
            int s = tid + i * 256;
            int r = s >> 3, c16 = s & 7;
            int byte = (r * 128 + c16 * 16) ^ ((r & 7) << 4);
            *(uint4*)(L + byte) = regs[i];
        }
    };

    auto COMPUTE = [&](int ch, int buf) {
        int seg = ch >> 1, half = ch & 1;
        const ushort_t* __restrict__ ws = wfrag + (size_t)seg * WSEG;
        const char* L = lds[buf];
#pragma unroll
        for (int kk = 0; kk < 2; ++kk) {
            int ks = half * 2 + kk;
            bf16x8 xh[2];
#pragma unroll
            for (int xf = 0; xf < 2; ++xf) {
                int r = rowgrp * 32 + xf * 16 + l15;
                int byte = (r * 128 + kk * 64 + lg * 16) ^ ((r & 7) << 4);
                xh[xf] = *(const bf16x8*)(L + byte);
            }
            bf16x8 wh[WF], wl[WF];
#pragma unroll
            for (int wf = 0; wf < WF; ++wf) {
                size_t off = (((size_t)ks * NCF + colgrp * WF + wf) * 64 + lane) * 8;
                wh[wf] = *(const bf16x8*)(ws + off);
                wl[wf] = *(const bf16x8*)(ws + PST + off);
            }
#pragma unroll
            for (int xf = 0; xf < 2; ++xf)
#pragma unroll
                for (int wf = 0; wf < WF; ++wf) {
                    acc[xf][wf] = __builtin_amdgcn_mfma_f32_16x16x32_bf16(
                        wh[wf], xh[xf], acc[xf][wf], 0, 0, 0);
                    acc[xf][wf] = __builtin_amdgcn_mfma_f32_16x16x32_bf16(
                        wl[wf], xh[xf], acc[xf][wf], 0, 0, 0);
                }
        }
    };

    constexpr int CH = 2 * NSEG;
    LOADSTAGE(0);
    WRITESTAGE(0);
    __syncthreads();
    for (int ch = 0; ch < CH; ++ch) {
        if (ch + 1 < CH) LOADSTAGE(ch + 1);
        COMPUTE(ch, ch & 1);
        __syncthreads();
        if (ch + 1 < CH) WRITESTAGE((ch + 1) & 1);
        __syncthreads();
    }

    // ---- stage acc tile (+bias) into LDS as full f32 rows ----
    {
        float4 bv[WF];
#pragma unroll
        for (int wf = 0; wf < WF; ++wf) {
            int col = colgrp * (NCOL / 2) + wf * 16 + lg * 4;
            bv[wf] = bias ? *(const float4*)(bias + col)
                          : make_float4(0.f, 0.f, 0.f, 0.f);
        }
#pragma unroll
        for (int xf = 0; xf < 2; ++xf) {
            int r = rowgrp * 32 + xf * 16 + l15;
#pragma unroll
            for (int wf = 0; wf < WF; ++wf) {
                int col = colgrp * (NCOL / 2) + wf * 16 + lg * 4;
                float4 o;
                o.x = acc[xf][wf][0] + bv[wf].x;
                o.y = acc[xf][wf][1] + bv[wf].y;
                o.z = acc[xf][wf][2] + bv[wf].z;
                o.w = acc[xf][wf][3] + bv[wf].w;
                *(float4*)(smem + r * RS + col * 4) = o;
            }
        }
    }
    __syncthreads();

    if (FUSE >= 1 && FUSE <= 3) {
        constexpr int CPT = NCOL / 4;
        int r = tid >> 2, seg = tid & 3;
        char* rp = smem + r * RS + seg * CPT * 4;
        float s = 0.f, sq = 0.f;
        float4 vv[CPT / 4];
#pragma unroll
        for (int j = 0; j < CPT / 4; ++j) {
            float4 v = *(const float4*)(rp + j * 16);
            vv[j] = v;
            s += (v.x + v.y) + (v.z + v.w);
            sq += (v.x * v.x + v.y * v.y) + (v.z * v.z + v.w * v.w);
        }
        s += __shfl_xor(s, 1, 64); sq += __shfl_xor(sq, 1, 64);
        s += __shfl_xor(s, 2, 64); sq += __shfl_xor(sq, 2, 64);
        float mu = s * (1.f / NCOL);
        float var = sq * (1.f / NCOL) - mu * mu;
        float rstd = rsqrtf(var + 1e-5f);
#pragma unroll
        for (int j = 0; j < CPT / 4; ++j) {
            int c0 = seg * CPT + j * 4;
            float4 v = vv[j];
            float4 gg = *(const float4*)(lng + c0);
            float4 bb = *(const float4*)(lnb + c0);
            float y0 = (v.x - mu) * rstd * gg.x + bb.x;
            float y1 = (v.y - mu) * rstd * gg.y + bb.y;
            float y2 = (v.z - mu) * rstd * gg.z + bb.z;
            float y3 = (v.w - mu) * rstd * gg.w + bb.w;
            if (FUSE == 1) {
                y0 = fmaxf(y0, 0.f); y1 = fmaxf(y1, 0.f);
                y2 = fmaxf(y2, 0.f); y3 = fmaxf(y3, 0.f);
            } else {
                y0 = 0.5f * y0 * (1.f + erff(y0 * 0.70710678118654752f));
                y1 = 0.5f * y1 * (1.f + erff(y1 * 0.70710678118654752f));
                y2 = 0.5f * y2 * (1.f + erff(y2 * 0.70710678118654752f));
                y3 = 0.5f * y3 * (1.f + erff(y3 * 0.70710678118654752f));
            }
            vv[j] = make_float4(y0, y1, y2, y3);
        }
        __syncthreads();
        if (FUSE == 3) {
#pragma unroll
            for (int j = 0; j < CPT / 4; ++j) *(float4*)(rp + j * 16) = vv[j];
        } else {
            // bf16 row region: first NCOL*2 bytes at base r*RS
#pragma unroll
            for (int j = 0; j < CPT / 4; ++j) {
                int c0 = seg * CPT + j * 4;
                *(uint2*)(smem + r * RS + 2 * c0) = pack_bf4(vv[j]);
            }
        }
        __syncthreads();
    }

    // ---- contiguous copy-out ----
    if (FUSE == 4) {
        constexpr int SL = 64 * (NCOL / 8);    // uint4 slots (bf16 rows)
#pragma unroll
        for (int i = 0; i < SL / 256; ++i) {
            int slot = tid + i * 256;
            int rr = slot / (NCOL / 8), c16 = slot % (NCOL / 8);
            int gr = row0 + rr;
            if (gr < M) {
                float4 a = *(const float4*)(smem + rr * RS + c16 * 32);
                float4 b = *(const float4*)(smem + rr * RS + c16 * 32 + 16);
                uint4 o;
                uint2 pa = pack_bf4(a), pb = pack_bf4(b);
                o.x = pa.x; o.y = pa.y; o.z = pb.x; o.w = pb.y;
                *(uint4*)((char*)Yv + (size_t)gr * (NCOL * 2) + c16 * 16) = o;
            }
        }
    } else {
        constexpr int OUTB = (FUSE == 0 || FUSE == 3) ? NCOL * 4 : NCOL * 2;
        constexpr int RP = OUTB / 16;
        constexpr int SL = 64 * RP;
#pragma unroll
        for (int i = 0; i < SL / 256; ++i) {
            int slot = tid + i * 256;
            int rr = slot / RP, c16 = slot % RP;
            int gr = row0 + rr;
            if (gr < M)
                *(uint4*)((char*)Yv + (size_t)gr * OUTB + c16 * 16) =
                    *(const uint4*)(smem + rr * RS + c16 * 16);
        }
    }
}

// ======== conv2 multi-head GEMM: stage x1 once, 4 weight sets ==============
// set 0 -> acc f32 (+b2); sets 1-3 -> H_r bf16 rows.
__global__ __launch_bounds__(256, 3) void gemm_conv2(
    const ushort_t* __restrict__ X, const ushort_t* __restrict__ wfb,
    const float* __restrict__ b2, float* __restrict__ accOut,
    ushort_t* __restrict__ H0, ushort_t* __restrict__ H1,
    ushort_t* __restrict__ H2, int M) {
    constexpr int NCF = 8, WF = 4;
    constexpr int PST = 4 * NCF * 512;
    constexpr int RS = 128 * 4 + 16;
    __shared__ __align__(16) char smem[16384 + 64 * RS];
    char* Xs = smem;
    char* ep = smem + 16384;

    const int tid = threadIdx.x;
    const int wv = tid >> 6, lane = tid & 63, l15 = lane & 15, lg = lane >> 4;
    const int rowgrp = wv >> 1, colgrp = wv & 1;
    const int row0 = blockIdx.x * 64;

    // stage full X tile [64r][128k] bf16, swizzled
#pragma unroll
    for (int i = 0; i < 4; ++i) {
        int s = tid + i * 256;               // 1024 slots
        int r = s >> 4, c16 = s & 15;
        int gr = row0 + r;
        uint4 v = make_uint4(0u, 0u, 0u, 0u);
        if (gr < M) v = *(const uint4*)((const char*)X + (size_t)gr * 256 + c16 * 16);
        int byte = (r * 256 + c16 * 16) ^ ((r & 7) << 4);
        *(uint4*)(Xs + byte) = v;
    }
    __syncthreads();

    ushort_t* Hs[3] = {H0, H1, H2};
    for (int set = 0; set < 4; ++set) {
        const ushort_t* __restrict__ ws = wfb + (size_t)(4 + set) * 32768;
        f32x4 acc[2][WF];
#pragma unroll
        for (int xf = 0; xf < 2; ++xf)
#pragma unroll
            for (int wf = 0; wf < WF; ++wf) acc[xf][wf] = (f32x4){0.f, 0.f, 0.f, 0.f};
#pragma unroll
        for (int ks = 0; ks < 4; ++ks) {
            bf16x8 xh[2];
#pragma unroll
            for (int xf = 0; xf < 2; ++xf) {
                int r = rowgrp * 32 + xf * 16 + l15;
                int byte = (r * 256 + ks * 64 + lg * 16) ^ ((r & 7) << 4);
                xh[xf] = *(const bf16x8*)(Xs + byte);
            }
            bf16x8 wh[WF], wl[WF];
#pragma unroll
            for (int wf = 0; wf < WF; ++wf) {
                size_t off = (((size_t)ks * NCF + colgrp * WF + wf) * 64 + lane) * 8;
                wh[wf] = *(const bf16x8*)(ws + off);
                wl[wf] = *(const bf16x8*)(ws + PST + off);
            }
#pragma unroll
            for (int xf = 0; xf < 2; ++xf)
#pragma unroll
                for (int wf = 0; wf < WF; ++wf) {
                    acc[xf][wf] = __builtin_amdgcn_mfma_f32_16x16x32_bf16(
                        wh[wf], xh[xf], acc[xf][wf], 0, 0, 0);
                    acc[xf][wf] = __builtin_amdgcn_mfma_f32_16x16x32_bf16(
                        wl[wf], xh[xf], acc[xf][wf], 0, 0, 0);
                }
        }
        __syncthreads();   // previous set's copy-out of ep done
        // stage f32 tile (+bias for set 0)
        {
            float4 bv[WF];
#pragma unroll
            for (int wf = 0; wf < WF; ++wf) {
                int col = colgrp * 64 + wf * 16 + lg * 4;
                bv[wf] = (set == 0) ? *(const float4*)(b2 + col)
                                    : make_float4(0.f, 0.f, 0.f, 0.f);
            }
#pragma unroll
            for (int xf = 0; xf < 2; ++xf) {
                int r = rowgrp * 32 + xf * 16 + l15;
#pragma unroll
                for (int wf = 0; wf < WF; ++wf) {
                    int col = colgrp * 64 + wf * 16 + lg * 4;
                    float4 o;
                    o.x = acc[xf][wf][0] + bv[wf].x;
                    o.y = acc[xf][wf][1] + bv[wf].y;
                    o.z = acc[xf][wf][2] + bv[wf].z;
                    o.w = acc[xf][wf][3] + bv[wf].w;
                    *(float4*)(ep + r * RS + col * 4) = o;
                }
            }
        }
        __syncthreads();
        if (set == 0) {
            // f32 rows 512B
#pragma unroll
            for (int i = 0; i < 8; ++i) {
                int slot = tid + i * 256;
                int rr = slot >> 5, c16 = slot & 31;
                int gr = row0 + rr;
                if (gr < M)
                    *(uint4*)((char*)accOut + (size_t)gr * 512 + c16 * 16) =
                        *(const uint4*)(ep + rr * RS + c16 * 16);
            }
        } else {
            ushort_t* H = Hs[set - 1];
#pragma unroll
            for (int i = 0; i < 4; ++i) {
                int slot = tid + i * 256;
                int rr = slot >> 4, c16 = slot & 15;
                int gr = row0 + rr;
                if (gr < M) {
                    float4 a = *(const float4*)(ep + rr * RS + c16 * 32);
                    float4 b = *(const float4*)(ep + rr * RS + c16 * 32 + 16);
                    uint2 pa = pack_bf4(a), pb = pack_bf4(b);
                    uint4 o; o.x = pa.x; o.y = pa.y; o.z = pb.x; o.w = pb.y;
                    *(uint4*)((char*)H + (size_t)gr * 256 + c16 * 16) = o;
                }
            }
        }
        // next set's ep staging waits on the barrier at loop top
    }
}

// ============================== CSR build ((dst,rel)-sorted) ===============
__global__ __launch_bounds__(256) void hist3_kernel(const int* __restrict__ edst,
                                                    const int* __restrict__ etype,
                                                    int* __restrict__ deg3, int E) {
    int e = blockIdx.x * 256 + threadIdx.x;
    if (e < E) atomicAdd(&deg3[edst[e] * 3 + etype[e]], 1);
}

__global__ __launch_bounds__(256) void degtot_kernel(const int* __restrict__ deg3,
                                                     int* __restrict__ degtot, int N) {
    int n = blockIdx.x * 256 + threadIdx.x;
    if (n < N) degtot[n] = deg3[n * 3] + deg3[n * 3 + 1] + deg3[n * 3 + 2];
}

__global__ __launch_bounds__(256) void scan_block(const int* __restrict__ in,
                                                  int* __restrict__ out,
                                                  int* __restrict__ sums, int n) {
    __shared__ int s[256];
    int g = blockIdx.x * 256 + threadIdx.x;
    int v = (g < n) ? in[g] : 0;
    s[threadIdx.x] = v;
    __syncthreads();
    int acc = v;
    for (int off = 1; off < 256; off <<= 1) {
        int t = (threadIdx.x >= off) ? s[threadIdx.x - off] : 0;
        __syncthreads();
        acc += t;
        s[threadIdx.x] = acc;
        __syncthreads();
    }
    if (g < n) out[g] = acc - v;
    if (threadIdx.x == 255 && sums) sums[blockIdx.x] = acc;
}

__global__ __launch_bounds__(256) void scan_add(int* __restrict__ out,
                                                const int* __restrict__ topex,
                                                int n, int total) {
    int g = blockIdx.x * 256 + threadIdx.x;
    if (g < n) out[g] += topex[blockIdx.x];
    if (g == 0) out[n] = total;
}

__global__ __launch_bounds__(256) void ranges_kernel(
    const int* __restrict__ rowptr, const int* __restrict__ deg3,
    int4* __restrict__ ranges, int* __restrict__ cursor3, int N) {
    int n = blockIdx.x * 256 + threadIdx.x;
    if (n >= N) return;
    int b = rowptr[n];
    int d0 = deg3[n * 3], d1 = deg3[n * 3 + 1];
    int4 r;
    r.x = b; r.y = b + d0; r.z = b + d0 + d1; r.w = rowptr[n + 1];
    ranges[n] = r;
    cursor3[n * 3] = r.x; cursor3[n * 3 + 1] = r.y; cursor3[n * 3 + 2] = r.z;
}

__global__ __launch_bounds__(256) void fill3_kernel(
    const int* __restrict__ esrc, const int* __restrict__ edst,
    const int* __restrict__ etype, int* __restrict__ cursor3,
    int* __restrict__ colidx, int E) {
    int e = blockIdx.x * 256 + threadIdx.x;
    if (e >= E) return;
    int pos = atomicAdd(&cursor3[edst[e] * 3 + etype[e]], 1);
    colidx[pos] = esrc[e];
}

// ========== fused add-gather from bf16 x -> bf16 S rows ====================
__device__ __forceinline__ float4 gather_sum_bf(const ushort_t* __restrict__ XH,
                                                const int* __restrict__ colidx,
                                                int beg, int end, int l) {
    float4 a = make_float4(0.f, 0.f, 0.f, 0.f);
    int e = beg;
    for (; e + 4 <= end; e += 4) {
        int s0 = colidx[e], s1 = colidx[e + 1];
        int s2 = colidx[e + 2], s3 = colidx[e + 3];
        float4 v0 = unpack_bf4(*(const uint2*)(XH + (size_t)s0 * 128 + l * 4));
        float4 v1 = unpack_bf4(*(const uint2*)(XH + (size_t)s1 * 128 + l * 4));
        float4 v2 = unpack_bf4(*(const uint2*)(XH + (size_t)s2 * 128 + l * 4));
        float4 v3 = unpack_bf4(*(const uint2*)(XH + (size_t)s3 * 128 + l * 4));
        a.x += (v0.x + v1.x) + (v2.x + v3.x);
        a.y += (v0.y + v1.y) + (v2.y + v3.y);
        a.z += (v0.z + v1.z) + (v2.z + v3.z);
        a.w += (v0.w + v1.w) + (v2.w + v3.w);
    }
    for (; e < end; ++e) {
        float4 v = unpack_bf4(*(const uint2*)(XH + (size_t)colidx[e] * 128 + l * 4));
        a.x += v.x; a.y += v.y; a.z += v.z; a.w += v.w;
    }
    return a;
}

__global__ __launch_bounds__(256) void agg3_add(
    const ushort_t* __restrict__ xh, const int4* __restrict__ ranges,
    const int* __restrict__ colidx, ushort_t* __restrict__ S0,
    ushort_t* __restrict__ S1, ushort_t* __restrict__ S2, int N) {
    int node = blockIdx.x * 8 + (threadIdx.x >> 5);
    int l = threadIdx.x & 31;
    if (node >= N) return;
    int4 rg = ranges[node];
    float4 a0 = gather_sum_bf(xh, colidx, rg.x, rg.y, l);
    float4 a1 = gather_sum_bf(xh, colidx, rg.y, rg.z, l);
    float4 a2 = gather_sum_bf(xh, colidx, rg.z, rg.w, l);
    *(uint2*)(S0 + (size_t)node * 128 + l * 4) = pack_bf4(a0);
    *(uint2*)(S1 + (size_t)node * 128 + l * 4) = pack_bf4(a1);
    *(uint2*)(S2 + (size_t)node * 128 + l * 4) = pack_bf4(a2);
}

// ======= fused: acc + sum_r max-gather(H_r bf16) -> LN -> relu+resid =======
__device__ __forceinline__ float4 gather_max_bf(const ushort_t* __restrict__ H,
                                                const int* __restrict__ colidx,
                                                int beg, int end, int l) {
    float4 m = make_float4(-INFINITY, -INFINITY, -INFINITY, -INFINITY);
    int e = beg;
    for (; e + 4 <= end; e += 4) {
        int s0 = colidx[e], s1 = colidx[e + 1];
        int s2 = colidx[e + 2], s3 = colidx[e + 3];
        float4 v0 = unpack_bf4(*(const uint2*)(H + (size_t)s0 * 128 + l * 4));
        float4 v1 = unpack_bf4(*(const uint2*)(H + (size_t)s1 * 128 + l * 4));
        float4 v2 = unpack_bf4(*(const uint2*)(H + (size_t)s2 * 128 + l * 4));
        float4 v3 = unpack_bf4(*(const uint2*)(H + (size_t)s3 * 128 + l * 4));
        m.x = fmaxf(m.x, fmaxf(fmaxf(v0.x, v1.x), fmaxf(v2.x, v3.x)));
        m.y = fmaxf(m.y, fmaxf(fmaxf(v0.y, v1.y), fmaxf(v2.y, v3.y)));
        m.z = fmaxf(m.z, fmaxf(fmaxf(v0.z, v1.z), fmaxf(v2.z, v3.z)));
        m.w = fmaxf(m.w, fmaxf(fmaxf(v0.w, v1.w), fmaxf(v2.w, v3.w)));
    }
    for (; e < end; ++e) {
        float4 v = unpack_bf4(*(const uint2*)(H + (size_t)colidx[e] * 128 + l * 4));
        m.x = fmaxf(m.x, v.x); m.y = fmaxf(m.y, v.y);
        m.z = fmaxf(m.z, v.z); m.w = fmaxf(m.w, v.w);
    }
    m.x = (m.x > -3e38f) ? m.x : 0.f;
    m.y = (m.y > -3e38f) ? m.y : 0.f;
    m.z = (m.z > -3e38f) ? m.z : 0.f;
    m.w = (m.w > -3e38f) ? m.w : 0.f;
    return m;
}

__global__ __launch_bounds__(256) void maxagg_ln(
    const ushort_t* __restrict__ H0, const ushort_t* __restrict__ H1,
    const ushort_t* __restrict__ H2, const int4* __restrict__ ranges,
    const int* __restrict__ colidx, const float* __restrict__ acc,
    const ushort_t* __restrict__ resid, const float* __restrict__ g,
    const float* __restrict__ b, ushort_t* __restrict__ outH, int N) {
    int node = blockIdx.x * 8 + (threadIdx.x >> 5);
    int l = threadIdx.x & 31;
    if (node >= N) return;
    int4 rg = ranges[node];
    float4 m0 = gather_max_bf(H0, colidx, rg.x, rg.y, l);
    float4 m1 = gather_max_bf(H1, colidx, rg.y, rg.z, l);
    float4 m2 = gather_max_bf(H2, colidx, rg.z, rg.w, l);
    float4 a = *(const float4*)(acc + (size_t)node * 128 + l * 4);
    a.x += m0.x + m1.x + m2.x;
    a.y += m0.y + m1.y + m2.y;
    a.z += m0.z + m1.z + m2.z;
    a.w += m0.w + m1.w + m2.w;
    float s = (a.x + a.y) + (a.z + a.w);
    float sq = (a.x * a.x + a.y * a.y) + (a.z * a.z + a.w * a.w);
#pragma unroll
    for (int off = 16; off; off >>= 1) {
        s += __shfl_xor(s, off, 64);
        sq += __shfl_xor(sq, off, 64);
    }
    float mu = s * (1.f / 128.f);
    float var = sq * (1.f / 128.f) - mu * mu;
    float rstd = rsqrtf(var + 1e-5f);
    float4 gg = *(const float4*)(g + l * 4);
    float4 bb = *(const float4*)(b + l * 4);
    float4 rv = unpack_bf4(*(const uint2*)(resid + (size_t)node * 128 + l * 4));
    float4 y;
    y.x = fmaxf((a.x - mu) * rstd * gg.x + bb.x, 0.f) + 0.2f * rv.x;
    y.y = fmaxf((a.y - mu) * rstd * gg.y + bb.y, 0.f) + 0.2f * rv.y;
    y.z = fmaxf((a.z - mu) * rstd * gg.z + bb.z, 0.f) + 0.2f * rv.z;
    y.w = fmaxf((a.w - mu) * rstd * gg.w + bb.w, 0.f) + 0.2f * rv.w;
    *(uint2*)(outH + (size_t)node * 128 + l * 4) = pack_bf4(y);
}

// ====== f32 GEMM  M x 64 @ 64 x 40 + bias + log_softmax -> out =============
__global__ __launch_bounds__(256) void gemm40_lsm(const float* __restrict__ X,
                                                  const float* __restrict__ W,
                                                  const float* __restrict__ bias,
                                                  float* __restrict__ Y, int M) {
    __shared__ float Xs[64][65];
    __shared__ float Ws[64 * 40];
    __shared__ float Ys[64][41];
    __shared__ float mx_[64], ls_[64];
    const int tid = threadIdx.x;
    const int row0 = blockIdx.x * 64;
    for (int i = tid; i < 64 * 40; i += 256) Ws[i] = W[i];
#pragma unroll
    for (int i = 0; i < 4; ++i) {
        int slot = tid + i * 256;
        int r = slot >> 4, c4 = slot & 15;
        float4 v = make_float4(0.f, 0.f, 0.f, 0.f);
        if (row0 + r < M) v = *(const float4*)(X + (size_t)(row0 + r) * 64 + c4 * 4);
        Xs[r][c4 * 4 + 0] = v.x; Xs[r][c4 * 4 + 1] = v.y;
        Xs[r][c4 * 4 + 2] = v.z; Xs[r][c4 * 4 + 3] = v.w;
    }
    __syncthreads();
    const int row = tid >> 2, cg = (tid & 3) * 10;
    float acc[10];
#pragma unroll
    for (int j = 0; j < 10; ++j) acc[j] = 0.f;
#pragma unroll 8
    for (int k = 0; k < 64; ++k) {
        float xv = Xs[row][k];
#pragma unroll
        for (int j = 0; j < 10; ++j) acc[j] = fmaf(xv, Ws[k * 40 + cg + j], acc[j]);
    }
#pragma unroll
    for (int j = 0; j < 10; ++j) Ys[row][cg + j] = acc[j] + bias[cg + j];
    __syncthreads();
    if (tid < 64) {
        float mx = -INFINITY;
#pragma unroll 8
        for (int c = 0; c < 40; ++c) mx = fmaxf(mx, Ys[tid][c]);
        float sum = 0.f;
#pragma unroll 8
        for (int c = 0; c < 40; ++c) sum += __expf(Ys[tid][c] - mx);
        mx_[tid] = mx;
        ls_[tid] = logf(sum);
    }
    __syncthreads();
#pragma unroll
    for (int i = 0; i < 10; ++i) {
        int slot = tid + i * 256;
        int r = slot / 40, c = slot % 40;
        int gr = row0 + r;
        if (gr < M) Y[(size_t)gr * 40 + c] = Ys[r][c] - mx_[r] - ls_[r];
    }
}

// ===========================================================================
extern "C" void kernel_launch(void* const* d_in, const int* in_sizes, int n_in,
                              void* d_out, int out_size, void* d_ws, size_t ws_size,
                              hipStream_t stream) {
    const float* x       = (const float*)d_in[0];
    const int*   eidx    = (const int*)d_in[1];
    const int*   etype   = (const int*)d_in[2];
    const float* w1_rel  = (const float*)d_in[3];
    const float* w1_root = (const float*)d_in[4];
    const float* b1      = (const float*)d_in[5];
    const float* ln1_g   = (const float*)d_in[6];
    const float* ln1_b   = (const float*)d_in[7];
    const float* w2_rel  = (const float*)d_in[8];
    const float* w2_root = (const float*)d_in[9];
    const float* b2      = (const float*)d_in[10];
    const float* ln2_g   = (const float*)d_in[11];
    const float* ln2_b   = (const float*)d_in[12];
    const float* cw1     = (const float*)d_in[13];
    const float* cb1     = (const float*)d_in[14];
    const float* cln1_g  = (const float*)d_in[15];
    const float* cln1_b  = (const float*)d_in[16];
    const float* cw2     = (const float*)d_in[17];
    const float* cb2     = (const float*)d_in[18];
    const float* cln2_g  = (const float*)d_in[19];
    const float* cln2_b  = (const float*)d_in[20];
    const float* cw3     = (const float*)d_in[21];
    const float* cb3     = (const float*)d_in[22];

    const int N = in_sizes[0] / 128;   // 50000
    const int E = in_sizes[1] / 2;     // 600000
    const int* esrc = eidx;
    const int* edst = eidx + E;

    const size_t HB = (size_t)N * 256;      // one bf16 [N,128] buffer, bytes
    char* base = (char*)d_ws;
    ushort_t* S0 = (ushort_t*)(base + 0 * HB);       // -> H0
    ushort_t* S1 = (ushort_t*)(base + 1 * HB);       // -> H1
    ushort_t* S2 = (ushort_t*)(base + 2 * HB);       // -> H2
    ushort_t* X1 = (ushort_t*)(base + 3 * HB);       // x1 bf16
    float*    AC = (float*)   (base + 4 * HB);       // acc2 f32 (2 HB)
    char*     B3 = base + 6 * HB;                    // META

    int* rowptr  = (int*)B3;                      // N+1
    int* degtot  = rowptr + (N + 1);              // N
    int* deg3    = degtot + N;                    // 3N
    int* cursor3 = deg3 + 3 * N;                  // 3N
    int* bsums   = cursor3 + 3 * N;               // 256
    int* btop    = bsums + 256;                   // 256
    int4* ranges = (int4*)(((uintptr_t)(btop + 256) + 15) & ~(uintptr_t)15);
    int* colidx  = (int*)(ranges + N);            // E
    ushort_t* wfb = (ushort_t*)(((uintptr_t)(colidx + E) + 255) & ~(uintptr_t)255);
    auto WSLOT = [&](int i) { return wfb + (size_t)i * 32768; };
    ushort_t* xh = (ushort_t*)(((uintptr_t)(wfb + 10 * 32768) + 255) & ~(uintptr_t)255);
    ushort_t* h2 = xh;                            // xh dead after conv1 gemm
    ushort_t* C1 = S0;                            // classifier temps reuse
    float*    C2 = (float*)S1;                    // [N,64] f32

    const dim3 blk(256);
    const int gGemm = (N + 63) / 64;
    const int gAgg  = (N + 7) / 8;
    const int gEdge = (E + 255) / 256;
    const int gNode = (N + 255) / 256;
    const int nScanB = (N + 255) / 256;
    const int gX2  = (N * 32 + 255) / 256;

    // ---------------- CSR build ----------------
    hipMemsetAsync(deg3, 0, (size_t)3 * N * sizeof(int), stream);
    hist3_kernel<<<gEdge, blk, 0, stream>>>(edst, etype, deg3, E);
    degtot_kernel<<<gNode, blk, 0, stream>>>(deg3, degtot, N);
    scan_block<<<nScanB, blk, 0, stream>>>(degtot, rowptr, bsums, N);
    scan_block<<<1, blk, 0, stream>>>(bsums, btop, nullptr, nScanB);
    scan_add<<<nScanB, blk, 0, stream>>>(rowptr, btop, N, E);
    ranges_kernel<<<gNode, blk, 0, stream>>>(rowptr, deg3, ranges, cursor3, N);
    fill3_kernel<<<gEdge, blk, 0, stream>>>(esrc, edst, etype, cursor3, colidx, E);

    // ---------------- weights + x conversion ----------------
    convert_all<<<76, blk, 0, stream>>>(w1_root, w1_rel, w2_root, w2_rel,
                                        cw1, cw2, wfb);
    x2bf<<<gX2, blk, 0, stream>>>(x, xh, N * 32);

    // ---------------- conv1 (add) ----------------
    agg3_add<<<gAgg, blk, 0, stream>>>(xh, ranges, colidx, S0, S1, S2, N);
    gemm_bf<128, 4, 1><<<gGemm, blk, 0, stream>>>(
        xh, S0, S1, S2, WSLOT(0), b1, ln1_g, ln1_b, X1, N);   // x1 bf16

    // ---------------- conv2 (max) ----------------
    gemm_conv2<<<gGemm, blk, 0, stream>>>(X1, wfb, b2, AC, S0, S1, S2, N);
    maxagg_ln<<<gAgg, blk, 0, stream>>>(S0, S1, S2, ranges, colidx, AC,
                                        X1, ln2_g, ln2_b, h2, N);

    // ---------------- classifier ----------------
    gemm_bf<128, 1, 2><<<gGemm, blk, 0, stream>>>(
        h2, h2, h2, h2, WSLOT(8), cb1, cln1_g, cln1_b, C1, N);   // bf16
    gemm_bf<64, 1, 3><<<gGemm, blk, 0, stream>>>(
        C1, C1, C1, C1, WSLOT(9), cb2, cln2_g, cln2_b, C2, N);   // f32 [N,64]
    gemm40_lsm<<<gGemm, blk, 0, stream>>>(C2, cw3, cb3, (float*)d_out, N);
}